// Round 4
// baseline (2913.245 us; speedup 1.0000x reference)
//
#include <hip/hip_runtime.h>
#include <hip/hip_bf16.h>

#define BS 8
#define V0 2048
#define V1N 512
#define V2N 128

// ---------------------------------------------------------------------------
// Threefry2x32 cipher (JAX-compatible), PARTITIONABLE split/random_bits
// (jax_threefry_partitionable defaults True since jax 0.4.36)
// ---------------------------------------------------------------------------
__device__ __forceinline__ void tf2x32(unsigned k0, unsigned k1,
                                       unsigned x0, unsigned x1,
                                       unsigned &o0, unsigned &o1) {
  unsigned ks2 = k0 ^ k1 ^ 0x1BD11BDAu;
  x0 += k0; x1 += k1;
#define RR(r) { x0 += x1; x1 = (x1 << (r)) | (x1 >> (32 - (r))); x1 ^= x0; }
  RR(13) RR(15) RR(26) RR(6)   x0 += k1;  x1 += ks2 + 1u;
  RR(17) RR(29) RR(16) RR(24)  x0 += ks2; x1 += k0 + 2u;
  RR(13) RR(15) RR(26) RR(6)   x0 += k0;  x1 += k1 + 3u;
  RR(17) RR(29) RR(16) RR(24)  x0 += k1;  x1 += ks2 + 4u;
  RR(13) RR(15) RR(26) RR(6)   x0 += ks2; x1 += k0 + 5u;
#undef RR
  o0 = x0; o1 = x1;
}

__device__ void do_perm(unsigned long long* skey, int* sval, int n, int nrounds,
                        unsigned k0, unsigned k1, int m, int* out,
                        int tid, int nthr) {
  for (int i = tid; i < n; i += nthr) sval[i] = i;
  __syncthreads();
  for (int r = 0; r < nrounds; ++r) {
    // partitionable split: newkey = cipher(key,(0,0)), subkey = cipher(key,(0,1))
    unsigned nk0, nk1, sk0, sk1;
    tf2x32(k0, k1, 0u, 0u, nk0, nk1);
    tf2x32(k0, k1, 0u, 1u, sk0, sk1);
    k0 = nk0; k1 = nk1;
    // partitionable random_bits(32): counter (hi=0, lo=i), bits = o0 ^ o1
    for (int t = tid; t < n; t += nthr) {
      unsigned o0, o1;
      tf2x32(sk0, sk1, 0u, (unsigned)t, o0, o1);
      skey[t] = (((unsigned long long)(o0 ^ o1)) << 32) | (unsigned)t;
    }
    __syncthreads();
    // bitonic sort ascending on (bits, position) — composite keys distinct →
    // equivalent to stable sort on bits (lax.sort_key_val is_stable=True)
    for (int kk = 2; kk <= n; kk <<= 1) {
      for (int j = kk >> 1; j > 0; j >>= 1) {
        for (int i = tid; i < n; i += nthr) {
          int ixj = i ^ j;
          if (ixj > i) {
            bool up = ((i & kk) == 0);
            unsigned long long ki = skey[i], kj = skey[ixj];
            if ((ki > kj) == up) {
              skey[i] = kj; skey[ixj] = ki;
              int v = sval[i]; sval[i] = sval[ixj]; sval[ixj] = v;
            }
          }
        }
        __syncthreads();
      }
    }
  }
  for (int i = tid; i < m; i += nthr) out[i] = sval[i];
  __syncthreads();
}

__global__ void perm_kernel(int* perm1, int* perm2) {
  __shared__ unsigned long long skey[2048];
  __shared__ int sval[2048];
  int tid = threadIdx.x, nthr = blockDim.x;
  unsigned k0, k1;
  // fold_in(key(42), d) = threefry_2x32(key, [0, d])  (mode-independent)
  tf2x32(0u, 42u, 0u, 1u, k0, k1);   // fold_in(key(42), 1)
  do_perm(skey, sval, 2048, 2, k0, k1, 512, perm1, tid, nthr);
  tf2x32(0u, 42u, 0u, 2u, k0, k1);   // fold_in(key(42), 2)
  do_perm(skey, sval, 512, 1, k0, k1, 128, perm2, tid, nthr);
}

// ---------------------------------------------------------------------------
// f32 squared distance, bit-exact vs numpy/jax f32: no FMA, ((dx²+dy²)+dz²)
// ---------------------------------------------------------------------------
__device__ __forceinline__ float sqdist_f32(float cx, float cy, float cz,
                                            const float* p) {
  float dx = __fsub_rn(cx, p[0]);
  float dy = __fsub_rn(cy, p[1]);
  float dz = __fsub_rn(cz, p[2]);
  return __fadd_rn(__fadd_rn(__fmul_rn(dx, dx), __fmul_rn(dy, dy)),
                   __fmul_rn(dz, dz));
}

// ---------------------------------------------------------------------------
// query_ball_point: first `nsample` in-radius indices (ascending j), pad first
// ---------------------------------------------------------------------------
__global__ void qbp_kernel(const float* __restrict__ pts, int Nv, int nsample,
                           float rr, int* __restrict__ out) {
  int wid = blockIdx.x * (blockDim.x >> 6) + (threadIdx.x >> 6);
  int lane = threadIdx.x & 63;
  if (wid >= BS * Nv) return;
  int b = wid / Nv, i = wid - b * Nv;
  const float* base = pts + (size_t)b * Nv * 3;
  float cx = base[i * 3], cy = base[i * 3 + 1], cz = base[i * 3 + 2];
  int cnt = 0, idx0 = 0;
  for (int j0 = 0; j0 < Nv; j0 += 64) {
    int j = j0 + lane;
    float d2 = sqdist_f32(cx, cy, cz, base + (size_t)j * 3);
    bool in = (d2 <= rr);
    unsigned long long mask = __ballot(in);
    if (cnt == 0 && mask) idx0 = j0 + __builtin_ctzll(mask);
    if (in) {
      int rank = cnt + __popcll(mask & ((1ull << lane) - 1ull));
      if (rank < nsample) out[(size_t)wid * nsample + rank] = j;
    }
    cnt += __popcll(mask);
    if (cnt >= nsample) break;
  }
  for (int s = cnt + lane; s < nsample; s += 64)
    out[(size_t)wid * nsample + s] = idx0;
}

// ---------------------------------------------------------------------------
// inline dir-norm helpers (continuous math, f32)
// ---------------------------------------------------------------------------
__device__ __forceinline__ void dirn(const float* base, int v, int nb,
                                     float& ox, float& oy, float& oz) {
  float dx = __fsub_rn(base[nb * 3 + 0], base[v * 3 + 0]);
  float dy = __fsub_rn(base[nb * 3 + 1], base[v * 3 + 1]);
  float dz = __fsub_rn(base[nb * 3 + 2], base[v * 3 + 2]);
  float s2 = __fadd_rn(__fadd_rn(__fmul_rn(dx, dx), __fmul_rn(dy, dy)),
                       __fmul_rn(dz, dz));
  float nrm = fmaxf(__fsqrt_rn(s2), 1e-12f);
  ox = __fdiv_rn(dx, nrm); oy = __fdiv_rn(dy, nrm); oz = __fdiv_rn(dz, nrm);
}

__device__ __forceinline__ void norm_col(const float* d, int k,
                                         float& ox, float& oy, float& oz) {
  float x = d[k], y = d[32 + k], z = d[64 + k];
  float s2 = __fadd_rn(__fadd_rn(__fmul_rn(x, x), __fmul_rn(y, y)),
                       __fmul_rn(z, z));
  float nrm = fmaxf(__fsqrt_rn(s2), 1e-12f);
  ox = __fdiv_rn(x, nrm); oy = __fdiv_rn(y, nrm); oz = __fdiv_rn(z, nrm);
}

// ---------------------------------------------------------------------------
// conv_surface: fm0[bv,k] = max_n relu(dn·dirn_k); block = 8 v x 32 k
// ---------------------------------------------------------------------------
__global__ void conv_surface_kernel(const float* __restrict__ pts,
                                    const int* __restrict__ ni,
                                    const float* __restrict__ d0,
                                    float* __restrict__ out, int Nv,
                                    int ldout) {
  __shared__ float sdir[3][32];
  __shared__ float sdn[8][32][3];
  int tid = threadIdx.x;
  if (tid < 32) {
    float x, y, z; norm_col(d0, tid, x, y, z);
    sdir[0][tid] = x; sdir[1][tid] = y; sdir[2][tid] = z;
  }
  int vloc = tid >> 5, k = tid & 31;
  size_t bvg = (size_t)blockIdx.x * 8 + vloc;
  int b = (int)(bvg / Nv), v = (int)(bvg % Nv);
  const float* base = pts + (size_t)b * Nv * 3;
  int nb = ni[bvg * 32 + k];
  float x, y, z; dirn(base, v, nb, x, y, z);
  sdn[vloc][k][0] = x; sdn[vloc][k][1] = y; sdn[vloc][k][2] = z;
  __syncthreads();
  float m = 0.f;
  for (int n = 0; n < 32; ++n) {
    float d = sdn[vloc][n][0] * sdir[0][k] + sdn[vloc][n][1] * sdir[1][k] +
              sdn[vloc][n][2] * sdir[2][k];
    m = fmaxf(m, fmaxf(d, 0.f));
  }
  out[bvg * ldout + k] = m;
}

// ---------------------------------------------------------------------------
// f = fm @ w + b  (out width fixed 64)
// ---------------------------------------------------------------------------
__global__ void linear64_kernel(const float* __restrict__ fm, int ld, int Cin,
                                const float* __restrict__ w,
                                const float* __restrict__ bias,
                                float* __restrict__ f, int rows) {
  int t = blockIdx.x * blockDim.x + threadIdx.x;
  int o = t & 63, bv = t >> 6;
  if (bv >= rows) return;
  const float* a = fm + (size_t)bv * ld;
  float acc = bias[o];
  for (int c = 0; c < Cin; ++c) acc += a[c] * w[c * 64 + o];
  f[(size_t)bv * 64 + o] = acc;
}

// ---------------------------------------------------------------------------
// conv act: out[bv,k] = relu(f[bv,k] + max_n(relu(dn·ddn_k) * f[nbr,32+k]))
// ---------------------------------------------------------------------------
__global__ void conv_act_kernel(const float* __restrict__ pts,
                                const float* __restrict__ dd,
                                const int* __restrict__ ni,
                                const float* __restrict__ f,
                                float* __restrict__ out, int Nv, int ldout,
                                int colofs) {
  __shared__ float sdir[3][32];
  __shared__ float sdn[8][32][3];
  __shared__ int sidx[8][32];
  int tid = threadIdx.x;
  if (tid < 32) {
    float x, y, z; norm_col(dd, tid, x, y, z);
    sdir[0][tid] = x; sdir[1][tid] = y; sdir[2][tid] = z;
  }
  int vloc = tid >> 5, k = tid & 31;
  size_t bvg = (size_t)blockIdx.x * 8 + vloc;
  int b = (int)(bvg / Nv), v = (int)(bvg % Nv);
  const float* base = pts + (size_t)b * Nv * 3;
  int nb = ni[bvg * 32 + k];
  float x, y, z; dirn(base, v, nb, x, y, z);
  sdn[vloc][k][0] = x; sdn[vloc][k][1] = y; sdn[vloc][k][2] = z;
  sidx[vloc][k] = nb;
  __syncthreads();
  float m = -INFINITY;
  size_t fb = (size_t)b * Nv * 64;
  for (int n = 0; n < 32; ++n) {
    float th = fmaxf(sdn[vloc][n][0] * sdir[0][k] + sdn[vloc][n][1] * sdir[1][k] +
                     sdn[vloc][n][2] * sdir[2][k], 0.f);
    float sup = f[fb + (size_t)sidx[vloc][n] * 64 + 32 + k];
    m = fmaxf(m, th * sup);
  }
  float center = f[bvg * 64 + k];
  out[bvg * ldout + colofs + k] = fmaxf(center + m, 0.f);
}

// ---------------------------------------------------------------------------
// pool: per selected vertex (perm), first-4 ball neighbors, max-pool features
// ---------------------------------------------------------------------------
__global__ void pool_kernel(const float* __restrict__ pts_in,
                            const float* __restrict__ fm_in, int ld_in, int C,
                            int Nv_in, const int* __restrict__ perm, int Nv_out,
                            float rr, float* __restrict__ pts_out,
                            float* __restrict__ fm_out, int ld_out) {
  int wid = blockIdx.x * (blockDim.x >> 6) + (threadIdx.x >> 6);
  int lane = threadIdx.x & 63;
  if (wid >= BS * Nv_out) return;
  int b = wid / Nv_out, pp = wid - b * Nv_out;
  int v = perm[pp];
  const float* base = pts_in + (size_t)b * Nv_in * 3;
  float cx = base[v * 3], cy = base[v * 3 + 1], cz = base[v * 3 + 2];
  int nb[4]; int cnt = 0;
  for (int j0 = 0; j0 < Nv_in && cnt < 4; j0 += 64) {
    int j = j0 + lane;
    float d2 = sqdist_f32(cx, cy, cz, base + (size_t)j * 3);
    unsigned long long mask = __ballot(d2 <= rr);
    while (mask && cnt < 4) {
      int bp = __builtin_ctzll(mask);
      mask &= mask - 1;
      nb[cnt++] = j0 + bp;
    }
  }
  for (int q = cnt; q < 4; ++q) nb[q] = nb[0];
  if (lane < 3) pts_out[((size_t)b * Nv_out + pp) * 3 + lane] = base[v * 3 + lane];
  size_t inrow = (size_t)b * Nv_in;
  size_t outrow = ((size_t)b * Nv_out + pp) * ld_out;
  for (int c = lane; c < C; c += 64) {
    float m = fm_in[(inrow + nb[0]) * ld_in + c];
    m = fmaxf(m, fm_in[(inrow + nb[1]) * ld_in + c]);
    m = fmaxf(m, fm_in[(inrow + nb[2]) * ld_in + c]);
    m = fmaxf(m, fm_in[(inrow + nb[3]) * ld_in + c]);
    fm_out[outrow + c] = m;
  }
}

// ---------------------------------------------------------------------------
// nearest source index (argmin, first occurrence), f32 exact semantics
// ---------------------------------------------------------------------------
__global__ void nearest_kernel(const float* __restrict__ tgt,
                               const float* __restrict__ src, int Ns,
                               int* __restrict__ out) {
  int t = blockIdx.x * blockDim.x + threadIdx.x;
  if (t >= BS * V0) return;
  int b = t / V0;
  const float* tb = tgt + (size_t)t * 3;
  float cx = tb[0], cy = tb[1], cz = tb[2];
  const float* sb = src + (size_t)b * Ns * 3;
  float best = INFINITY; int bi = 0;
  for (int j = 0; j < Ns; ++j) {
    float d2 = sqdist_f32(cx, cy, cz, sb + (size_t)j * 3);
    if (d2 < best) { best = d2; bi = j; }
  }
  out[t] = bi;
}

// ---------------------------------------------------------------------------
// global max over 128 vertices of fm7 (256 ch)
// ---------------------------------------------------------------------------
__global__ void gmax_kernel(const float* __restrict__ fm,
                            float* __restrict__ out) {
  int t = blockIdx.x * blockDim.x + threadIdx.x;
  if (t >= BS * 256) return;
  int b = t >> 8, c = t & 255;
  float m = -INFINITY;
  for (int v = 0; v < V2N; ++v)
    m = fmaxf(m, fm[((size_t)b * V2N + v) * 256 + c]);
  out[t] = m;
}

// ---------------------------------------------------------------------------
// fuse channel gather (virtual A row for gemm1)
// ---------------------------------------------------------------------------
__device__ __forceinline__ float fuse_val(const float* r2, const float* r5,
                                          const float* r7, const float* rg,
                                          const float* roh, int c) {
  if (c < 192) {
    int cc = (c < 32) ? c : (c < 96 ? c - 32 : c - 96);
    return r2[cc];
  } else if (c < 672) {
    int cc = (c < 320) ? c - 192 : (c < 480 ? c - 320 : c - 480);
    return r5[cc];
  } else if (c < 1152) {
    int cc = (c < 896) ? c - 672 : c - 896;
    return r7[cc];
  } else if (c < 1408) {
    return rg[c - 1152];
  }
  return roh[c - 1408];
}

// ---------------------------------------------------------------------------
// GEMM (f32, 128x128 tile, 8x8/thread). gemm1 variant gathers A on the fly.
// ---------------------------------------------------------------------------
#define TM 128
#define TN 128
#define TK 8
__global__ __launch_bounds__(256) void gemm1_fuse_kernel(
    const float* __restrict__ fm2, const float* __restrict__ fm5,
    const float* __restrict__ fm7, const float* __restrict__ fglob,
    const float* __restrict__ onehot, const int* __restrict__ n1,
    const int* __restrict__ n2, const float* __restrict__ B,
    const float* __restrict__ bias, float* __restrict__ C, int row0) {
  __shared__ float As[TK][TM + 4];
  __shared__ float Bs[TK][TN + 4];
  const int N = 1024, Kd = 1424;
  int tid = threadIdx.x;
  int bm = blockIdx.y * TM, bn = blockIdx.x * TN;
  int lr = tid >> 1;
  int lk = (tid & 1) * 4;
  int tx = tid & 15, ty = tid >> 4;
  int gr = row0 + bm + lr;             // global fused row
  int b = gr >> 11;                    // / V0
  const float* r2 = fm2 + (size_t)gr * 96;
  const float* r5 = fm5 + ((size_t)b * V1N + n1[gr]) * 192;
  const float* r7 = fm7 + ((size_t)b * V2N + n2[gr]) * 256;
  const float* rg = fglob + b * 256;
  const float* roh = onehot + b * 16;
  float acc[8][8];
#pragma unroll
  for (int i = 0; i < 8; ++i)
#pragma unroll
    for (int j = 0; j < 8; ++j) acc[i][j] = 0.f;
  for (int k0 = 0; k0 < Kd; k0 += TK) {
    int c = k0 + lk;
    As[lk + 0][lr] = fuse_val(r2, r5, r7, rg, roh, c + 0);
    As[lk + 1][lr] = fuse_val(r2, r5, r7, rg, roh, c + 1);
    As[lk + 2][lr] = fuse_val(r2, r5, r7, rg, roh, c + 2);
    As[lk + 3][lr] = fuse_val(r2, r5, r7, rg, roh, c + 3);
    float4 b4 = *(const float4*)(B + (size_t)(bn + lr) * Kd + c);
    Bs[lk + 0][lr] = b4.x; Bs[lk + 1][lr] = b4.y;
    Bs[lk + 2][lr] = b4.z; Bs[lk + 3][lr] = b4.w;
    __syncthreads();
#pragma unroll
    for (int kk = 0; kk < TK; ++kk) {
      float av[8], bw[8];
#pragma unroll
      for (int i = 0; i < 8; ++i) av[i] = As[kk][ty * 8 + i];
#pragma unroll
      for (int j = 0; j < 8; ++j) bw[j] = Bs[kk][tx * 8 + j];
#pragma unroll
      for (int i = 0; i < 8; ++i)
#pragma unroll
        for (int j = 0; j < 8; ++j) acc[i][j] += av[i] * bw[j];
    }
    __syncthreads();
  }
#pragma unroll
  for (int i = 0; i < 8; ++i) {
    int m = bm + ty * 8 + i;
#pragma unroll
    for (int j = 0; j < 8; ++j) {
      int n = bn + tx * 8 + j;
      float v = acc[i][j] + bias[n];
      C[(size_t)m * N + n] = fmaxf(v, 0.f);
    }
  }
}

__global__ __launch_bounds__(256) void gemm_nt_kernel(
    const float* __restrict__ A, const float* __restrict__ B,
    const float* __restrict__ bias, float* __restrict__ C, int M, int N,
    int Kd, int dorelu) {
  __shared__ float As[TK][TM + 4];
  __shared__ float Bs[TK][TN + 4];
  int tid = threadIdx.x;
  int bm = blockIdx.y * TM, bn = blockIdx.x * TN;
  int lr = tid >> 1;
  int lk = (tid & 1) * 4;
  int tx = tid & 15, ty = tid >> 4;
  float acc[8][8];
#pragma unroll
  for (int i = 0; i < 8; ++i)
#pragma unroll
    for (int j = 0; j < 8; ++j) acc[i][j] = 0.f;
  for (int k0 = 0; k0 < Kd; k0 += TK) {
    float4 a4 = *(const float4*)(A + (size_t)(bm + lr) * Kd + (k0 + lk));
    int nr = bn + lr;
    float4 b4 = make_float4(0.f, 0.f, 0.f, 0.f);
    if (nr < N) b4 = *(const float4*)(B + (size_t)nr * Kd + (k0 + lk));
    As[lk + 0][lr] = a4.x; As[lk + 1][lr] = a4.y;
    As[lk + 2][lr] = a4.z; As[lk + 3][lr] = a4.w;
    Bs[lk + 0][lr] = b4.x; Bs[lk + 1][lr] = b4.y;
    Bs[lk + 2][lr] = b4.z; Bs[lk + 3][lr] = b4.w;
    __syncthreads();
#pragma unroll
    for (int kk = 0; kk < TK; ++kk) {
      float av[8], bw[8];
#pragma unroll
      for (int i = 0; i < 8; ++i) av[i] = As[kk][ty * 8 + i];
#pragma unroll
      for (int j = 0; j < 8; ++j) bw[j] = Bs[kk][tx * 8 + j];
#pragma unroll
      for (int i = 0; i < 8; ++i)
#pragma unroll
        for (int j = 0; j < 8; ++j) acc[i][j] += av[i] * bw[j];
    }
    __syncthreads();
  }
#pragma unroll
  for (int i = 0; i < 8; ++i) {
    int m = bm + ty * 8 + i;
#pragma unroll
    for (int j = 0; j < 8; ++j) {
      int n = bn + tx * 8 + j;
      if (n < N) {
        float v = acc[i][j] + bias[n];
        if (dorelu) v = fmaxf(v, 0.f);
        C[(size_t)m * N + n] = v;
      }
    }
  }
}

// ---------------------------------------------------------------------------
extern "C" void kernel_launch(void* const* d_in, const int* in_sizes, int n_in,
                              void* d_out, int out_size, void* d_ws,
                              size_t ws_size, hipStream_t stream) {
  const float* vertices = (const float*)d_in[0];
  const float* onehot = (const float*)d_in[1];
  const float* d0 = (const float*)d_in[2];
  const float *w[8], *bb[8], *dd[8];
  for (int i = 1; i <= 7; ++i) {
    w[i] = (const float*)d_in[3 * i];
    bb[i] = (const float*)d_in[3 * i + 1];
    dd[i] = (const float*)d_in[3 * i + 2];
  }
  const float* cw1 = (const float*)d_in[24];
  const float* cb1 = (const float*)d_in[25];
  const float* cw2 = (const float*)d_in[26];
  const float* cb2 = (const float*)d_in[27];
  const float* cw3 = (const float*)d_in[28];
  const float* cb3 = (const float*)d_in[29];
  float* out = (float*)d_out;

  char* wsp = (char*)d_ws;
  size_t off = 0;
  auto alloc = [&](size_t bytes) -> void* {
    void* p = wsp + off;
    off += (bytes + 255) & ~(size_t)255;
    return p;
  };
  int* perm1 = (int*)alloc(512 * 4);
  int* perm2 = (int*)alloc(128 * 4);
  int* ni1 = (int*)alloc((size_t)BS * V0 * 32 * 4);
  int* ni2 = (int*)alloc((size_t)BS * V1N * 32 * 4);
  int* ni3 = (int*)alloc((size_t)BS * V2N * 32 * 4);
  float* fm2buf = (float*)alloc((size_t)BS * V0 * 96 * 4);
  float* fm5buf = (float*)alloc((size_t)BS * V1N * 192 * 4);
  float* fm7buf = (float*)alloc((size_t)BS * V2N * 256 * 4);
  float* fbuf = (float*)alloc((size_t)BS * V0 * 64 * 4);
  float* v1 = (float*)alloc((size_t)BS * V1N * 3 * 4);
  float* v2 = (float*)alloc((size_t)BS * V2N * 3 * 4);
  int* n1 = (int*)alloc((size_t)BS * V0 * 4);
  int* n2 = (int*)alloc((size_t)BS * V0 * 4);
  float* fglob = (float*)alloc((size_t)BS * 256 * 4);
  const int CH = 4096;  // head row-chunk
  float* h1c = (float*)alloc((size_t)CH * 1024 * 4);
  float* h2c = (float*)alloc((size_t)CH * 512 * 4);
  // peak ≈ 41 MB

  perm_kernel<<<1, 1024, 0, stream>>>(perm1, perm2);

  float rr1 = 0.0625f;
  float rr2 = (float)(0.39 * 0.39);
  float rr3 = (float)(0.63 * 0.63);

  // level 1 (V=2048)
  qbp_kernel<<<BS * V0 / 4, 256, 0, stream>>>(vertices, V0, 32, rr1, ni1);
  conv_surface_kernel<<<BS * V0 / 8, 256, 0, stream>>>(vertices, ni1, d0, fm2buf, V0, 96);
  linear64_kernel<<<BS * V0 * 64 / 256, 256, 0, stream>>>(fm2buf, 96, 32, w[1], bb[1], fbuf, BS * V0);
  conv_act_kernel<<<BS * V0 / 8, 256, 0, stream>>>(vertices, dd[1], ni1, fbuf, fm2buf, V0, 96, 32);
  linear64_kernel<<<BS * V0 * 64 / 256, 256, 0, stream>>>(fm2buf, 96, 64, w[2], bb[2], fbuf, BS * V0);
  conv_act_kernel<<<BS * V0 / 8, 256, 0, stream>>>(vertices, dd[2], ni1, fbuf, fm2buf, V0, 96, 64);
  pool_kernel<<<BS * V1N / 4, 256, 0, stream>>>(vertices, fm2buf, 96, 96, V0, perm1, V1N, rr1, v1, fm5buf, 192);

  // level 2 (V=512)
  qbp_kernel<<<BS * V1N / 4, 256, 0, stream>>>(v1, V1N, 32, rr2, ni2);
  linear64_kernel<<<BS * V1N * 64 / 256, 256, 0, stream>>>(fm5buf, 192, 96, w[3], bb[3], fbuf, BS * V1N);
  conv_act_kernel<<<BS * V1N / 8, 256, 0, stream>>>(v1, dd[3], ni2, fbuf, fm5buf, V1N, 192, 96);
  linear64_kernel<<<BS * V1N * 64 / 256, 256, 0, stream>>>(fm5buf, 192, 128, w[4], bb[4], fbuf, BS * V1N);
  conv_act_kernel<<<BS * V1N / 8, 256, 0, stream>>>(v1, dd[4], ni2, fbuf, fm5buf, V1N, 192, 128);
  linear64_kernel<<<BS * V1N * 64 / 256, 256, 0, stream>>>(fm5buf, 192, 160, w[5], bb[5], fbuf, BS * V1N);
  conv_act_kernel<<<BS * V1N / 8, 256, 0, stream>>>(v1, dd[5], ni2, fbuf, fm5buf, V1N, 192, 160);
  pool_kernel<<<BS * V2N / 4, 256, 0, stream>>>(v1, fm5buf, 192, 192, V1N, perm2, V2N, rr2, v2, fm7buf, 256);

  // level 3 (V=128)
  qbp_kernel<<<BS * V2N / 4, 256, 0, stream>>>(v2, V2N, 32, rr3, ni3);
  linear64_kernel<<<BS * V2N * 64 / 256, 256, 0, stream>>>(fm7buf, 256, 192, w[6], bb[6], fbuf, BS * V2N);
  conv_act_kernel<<<BS * V2N / 8, 256, 0, stream>>>(v2, dd[6], ni3, fbuf, fm7buf, V2N, 256, 192);
  linear64_kernel<<<BS * V2N * 64 / 256, 256, 0, stream>>>(fm7buf, 256, 224, w[7], bb[7], fbuf, BS * V2N);
  conv_act_kernel<<<BS * V2N / 8, 256, 0, stream>>>(v2, dd[7], ni3, fbuf, fm7buf, V2N, 256, 224);

  gmax_kernel<<<BS, 256, 0, stream>>>(fm7buf, fglob);
  nearest_kernel<<<BS * V0 / 256, 256, 0, stream>>>(vertices, v1, V1N, n1);
  nearest_kernel<<<BS * V0 / 256, 256, 0, stream>>>(vertices, v2, V2N, n2);

  // MLP head, chunked by 4096 rows (h1/h2 stay small; fuse never materialized)
  for (int c0 = 0; c0 < BS * V0; c0 += CH) {
    gemm1_fuse_kernel<<<dim3(1024 / TN, CH / TM), 256, 0, stream>>>(
        fm2buf, fm5buf, fm7buf, fglob, onehot, n1, n2, cw1, cb1, h1c, c0);
    gemm_nt_kernel<<<dim3(512 / TN, CH / TM), 256, 0, stream>>>(
        h1c, cw2, cb2, h2c, CH, 512, 1024, 1);
    gemm_nt_kernel<<<dim3(1, CH / TM), 256, 0, stream>>>(
        h2c, cw3, cb3, out + (size_t)c0 * 50, CH, 50, 512, 0);
  }
}

// Round 5
// 806.070 us; speedup vs baseline: 3.6141x; 3.6141x over previous
//
#include <hip/hip_runtime.h>
#include <hip/hip_bf16.h>

#define BS 8
#define V0 2048
#define V1N 512
#define V2N 128

typedef unsigned short ushort_t;
typedef __attribute__((ext_vector_type(8))) short bf16x8;
typedef __attribute__((ext_vector_type(4))) float f32x4;

// ---------------------------------------------------------------------------
// Threefry2x32 cipher (JAX partitionable mode — verified R4)
// ---------------------------------------------------------------------------
__device__ __forceinline__ void tf2x32(unsigned k0, unsigned k1,
                                       unsigned x0, unsigned x1,
                                       unsigned &o0, unsigned &o1) {
  unsigned ks2 = k0 ^ k1 ^ 0x1BD11BDAu;
  x0 += k0; x1 += k1;
#define RR(r) { x0 += x1; x1 = (x1 << (r)) | (x1 >> (32 - (r))); x1 ^= x0; }
  RR(13) RR(15) RR(26) RR(6)   x0 += k1;  x1 += ks2 + 1u;
  RR(17) RR(29) RR(16) RR(24)  x0 += ks2; x1 += k0 + 2u;
  RR(13) RR(15) RR(26) RR(6)   x0 += k0;  x1 += k1 + 3u;
  RR(17) RR(29) RR(16) RR(24)  x0 += k1;  x1 += ks2 + 4u;
  RR(13) RR(15) RR(26) RR(6)   x0 += ks2; x1 += k0 + 5u;
#undef RR
  o0 = x0; o1 = x1;
}

__device__ void do_perm(unsigned long long* skey, int* sval, int n, int nrounds,
                        unsigned k0, unsigned k1, int m, int* out,
                        int tid, int nthr) {
  for (int i = tid; i < n; i += nthr) sval[i] = i;
  __syncthreads();
  for (int r = 0; r < nrounds; ++r) {
    // partitionable split: newkey = cipher(key,(0,0)), subkey = cipher(key,(0,1))
    unsigned nk0, nk1, sk0, sk1;
    tf2x32(k0, k1, 0u, 0u, nk0, nk1);
    tf2x32(k0, k1, 0u, 1u, sk0, sk1);
    k0 = nk0; k1 = nk1;
    // partitionable random_bits(32): counter (0, i), bits = o0 ^ o1
    for (int t = tid; t < n; t += nthr) {
      unsigned o0, o1;
      tf2x32(sk0, sk1, 0u, (unsigned)t, o0, o1);
      skey[t] = (((unsigned long long)(o0 ^ o1)) << 32) | (unsigned)t;
    }
    __syncthreads();
    for (int kk = 2; kk <= n; kk <<= 1) {
      for (int j = kk >> 1; j > 0; j >>= 1) {
        for (int i = tid; i < n; i += nthr) {
          int ixj = i ^ j;
          if (ixj > i) {
            bool up = ((i & kk) == 0);
            unsigned long long ki = skey[i], kj = skey[ixj];
            if ((ki > kj) == up) {
              skey[i] = kj; skey[ixj] = ki;
              int v = sval[i]; sval[i] = sval[ixj]; sval[ixj] = v;
            }
          }
        }
        __syncthreads();
      }
    }
  }
  for (int i = tid; i < m; i += nthr) out[i] = sval[i];
  __syncthreads();
}

__global__ void perm_kernel(int* perm1, int* perm2) {
  __shared__ unsigned long long skey[2048];
  __shared__ int sval[2048];
  int tid = threadIdx.x, nthr = blockDim.x;
  unsigned k0, k1;
  tf2x32(0u, 42u, 0u, 1u, k0, k1);   // fold_in(key(42), 1)
  do_perm(skey, sval, 2048, 2, k0, k1, 512, perm1, tid, nthr);
  tf2x32(0u, 42u, 0u, 2u, k0, k1);   // fold_in(key(42), 2)
  do_perm(skey, sval, 512, 1, k0, k1, 128, perm2, tid, nthr);
}

// ---------------------------------------------------------------------------
__device__ __forceinline__ float sqdist_f32(float cx, float cy, float cz,
                                            const float* p) {
  float dx = __fsub_rn(cx, p[0]);
  float dy = __fsub_rn(cy, p[1]);
  float dz = __fsub_rn(cz, p[2]);
  return __fadd_rn(__fadd_rn(__fmul_rn(dx, dx), __fmul_rn(dy, dy)),
                   __fmul_rn(dz, dz));
}

__global__ void qbp_kernel(const float* __restrict__ pts, int Nv, int nsample,
                           float rr, int* __restrict__ out) {
  int wid = blockIdx.x * (blockDim.x >> 6) + (threadIdx.x >> 6);
  int lane = threadIdx.x & 63;
  if (wid >= BS * Nv) return;
  int b = wid / Nv, i = wid - b * Nv;
  const float* base = pts + (size_t)b * Nv * 3;
  float cx = base[i * 3], cy = base[i * 3 + 1], cz = base[i * 3 + 2];
  int cnt = 0, idx0 = 0;
  for (int j0 = 0; j0 < Nv; j0 += 64) {
    int j = j0 + lane;
    float d2 = sqdist_f32(cx, cy, cz, base + (size_t)j * 3);
    bool in = (d2 <= rr);
    unsigned long long mask = __ballot(in);
    if (cnt == 0 && mask) idx0 = j0 + __builtin_ctzll(mask);
    if (in) {
      int rank = cnt + __popcll(mask & ((1ull << lane) - 1ull));
      if (rank < nsample) out[(size_t)wid * nsample + rank] = j;
    }
    cnt += __popcll(mask);
    if (cnt >= nsample) break;
  }
  for (int s = cnt + lane; s < nsample; s += 64)
    out[(size_t)wid * nsample + s] = idx0;
}

// ---------------------------------------------------------------------------
__device__ __forceinline__ void dirn(const float* base, int v, int nb,
                                     float& ox, float& oy, float& oz) {
  float dx = __fsub_rn(base[nb * 3 + 0], base[v * 3 + 0]);
  float dy = __fsub_rn(base[nb * 3 + 1], base[v * 3 + 1]);
  float dz = __fsub_rn(base[nb * 3 + 2], base[v * 3 + 2]);
  float s2 = __fadd_rn(__fadd_rn(__fmul_rn(dx, dx), __fmul_rn(dy, dy)),
                       __fmul_rn(dz, dz));
  float nrm = fmaxf(__fsqrt_rn(s2), 1e-12f);
  ox = __fdiv_rn(dx, nrm); oy = __fdiv_rn(dy, nrm); oz = __fdiv_rn(dz, nrm);
}

__device__ __forceinline__ void norm_col(const float* d, int k,
                                         float& ox, float& oy, float& oz) {
  float x = d[k], y = d[32 + k], z = d[64 + k];
  float s2 = __fadd_rn(__fadd_rn(__fmul_rn(x, x), __fmul_rn(y, y)),
                       __fmul_rn(z, z));
  float nrm = fmaxf(__fsqrt_rn(s2), 1e-12f);
  ox = __fdiv_rn(x, nrm); oy = __fdiv_rn(y, nrm); oz = __fdiv_rn(z, nrm);
}

__global__ void conv_surface_kernel(const float* __restrict__ pts,
                                    const int* __restrict__ ni,
                                    const float* __restrict__ d0,
                                    float* __restrict__ out, int Nv,
                                    int ldout) {
  __shared__ float sdir[3][32];
  __shared__ float sdn[8][32][3];
  int tid = threadIdx.x;
  if (tid < 32) {
    float x, y, z; norm_col(d0, tid, x, y, z);
    sdir[0][tid] = x; sdir[1][tid] = y; sdir[2][tid] = z;
  }
  int vloc = tid >> 5, k = tid & 31;
  size_t bvg = (size_t)blockIdx.x * 8 + vloc;
  int b = (int)(bvg / Nv), v = (int)(bvg % Nv);
  const float* base = pts + (size_t)b * Nv * 3;
  int nb = ni[bvg * 32 + k];
  float x, y, z; dirn(base, v, nb, x, y, z);
  sdn[vloc][k][0] = x; sdn[vloc][k][1] = y; sdn[vloc][k][2] = z;
  __syncthreads();
  float m = 0.f;
  for (int n = 0; n < 32; ++n) {
    float d = sdn[vloc][n][0] * sdir[0][k] + sdn[vloc][n][1] * sdir[1][k] +
              sdn[vloc][n][2] * sdir[2][k];
    m = fmaxf(m, fmaxf(d, 0.f));
  }
  out[bvg * ldout + k] = m;
}

__global__ void linear64_kernel(const float* __restrict__ fm, int ld, int Cin,
                                const float* __restrict__ w,
                                const float* __restrict__ bias,
                                float* __restrict__ f, int rows) {
  int t = blockIdx.x * blockDim.x + threadIdx.x;
  int o = t & 63, bv = t >> 6;
  if (bv >= rows) return;
  const float* a = fm + (size_t)bv * ld;
  float acc = bias[o];
  for (int c = 0; c < Cin; ++c) acc += a[c] * w[c * 64 + o];
  f[(size_t)bv * 64 + o] = acc;
}

__global__ void conv_act_kernel(const float* __restrict__ pts,
                                const float* __restrict__ dd,
                                const int* __restrict__ ni,
                                const float* __restrict__ f,
                                float* __restrict__ out, int Nv, int ldout,
                                int colofs) {
  __shared__ float sdir[3][32];
  __shared__ float sdn[8][32][3];
  __shared__ int sidx[8][32];
  int tid = threadIdx.x;
  if (tid < 32) {
    float x, y, z; norm_col(dd, tid, x, y, z);
    sdir[0][tid] = x; sdir[1][tid] = y; sdir[2][tid] = z;
  }
  int vloc = tid >> 5, k = tid & 31;
  size_t bvg = (size_t)blockIdx.x * 8 + vloc;
  int b = (int)(bvg / Nv), v = (int)(bvg % Nv);
  const float* base = pts + (size_t)b * Nv * 3;
  int nb = ni[bvg * 32 + k];
  float x, y, z; dirn(base, v, nb, x, y, z);
  sdn[vloc][k][0] = x; sdn[vloc][k][1] = y; sdn[vloc][k][2] = z;
  sidx[vloc][k] = nb;
  __syncthreads();
  float m = -INFINITY;
  size_t fb = (size_t)b * Nv * 64;
  for (int n = 0; n < 32; ++n) {
    float th = fmaxf(sdn[vloc][n][0] * sdir[0][k] + sdn[vloc][n][1] * sdir[1][k] +
                     sdn[vloc][n][2] * sdir[2][k], 0.f);
    float sup = f[fb + (size_t)sidx[vloc][n] * 64 + 32 + k];
    m = fmaxf(m, th * sup);
  }
  float center = f[bvg * 64 + k];
  out[bvg * ldout + colofs + k] = fmaxf(center + m, 0.f);
}

__global__ void pool_kernel(const float* __restrict__ pts_in,
                            const float* __restrict__ fm_in, int ld_in, int C,
                            int Nv_in, const int* __restrict__ perm, int Nv_out,
                            float rr, float* __restrict__ pts_out,
                            float* __restrict__ fm_out, int ld_out) {
  int wid = blockIdx.x * (blockDim.x >> 6) + (threadIdx.x >> 6);
  int lane = threadIdx.x & 63;
  if (wid >= BS * Nv_out) return;
  int b = wid / Nv_out, pp = wid - b * Nv_out;
  int v = perm[pp];
  const float* base = pts_in + (size_t)b * Nv_in * 3;
  float cx = base[v * 3], cy = base[v * 3 + 1], cz = base[v * 3 + 2];
  int nb[4]; int cnt = 0;
  for (int j0 = 0; j0 < Nv_in && cnt < 4; j0 += 64) {
    int j = j0 + lane;
    float d2 = sqdist_f32(cx, cy, cz, base + (size_t)j * 3);
    unsigned long long mask = __ballot(d2 <= rr);
    while (mask && cnt < 4) {
      int bp = __builtin_ctzll(mask);
      mask &= mask - 1;
      nb[cnt++] = j0 + bp;
    }
  }
  for (int q = cnt; q < 4; ++q) nb[q] = nb[0];
  if (lane < 3) pts_out[((size_t)b * Nv_out + pp) * 3 + lane] = base[v * 3 + lane];
  size_t inrow = (size_t)b * Nv_in;
  size_t outrow = ((size_t)b * Nv_out + pp) * ld_out;
  for (int c = lane; c < C; c += 64) {
    float m = fm_in[(inrow + nb[0]) * ld_in + c];
    m = fmaxf(m, fm_in[(inrow + nb[1]) * ld_in + c]);
    m = fmaxf(m, fm_in[(inrow + nb[2]) * ld_in + c]);
    m = fmaxf(m, fm_in[(inrow + nb[3]) * ld_in + c]);
    fm_out[outrow + c] = m;
  }
}

__global__ void nearest_kernel(const float* __restrict__ tgt,
                               const float* __restrict__ src, int Ns,
                               int* __restrict__ out) {
  int t = blockIdx.x * blockDim.x + threadIdx.x;
  if (t >= BS * V0) return;
  int b = t / V0;
  const float* tb = tgt + (size_t)t * 3;
  float cx = tb[0], cy = tb[1], cz = tb[2];
  const float* sb = src + (size_t)b * Ns * 3;
  float best = INFINITY; int bi = 0;
  for (int j = 0; j < Ns; ++j) {
    float d2 = sqdist_f32(cx, cy, cz, sb + (size_t)j * 3);
    if (d2 < best) { best = d2; bi = j; }
  }
  out[t] = bi;
}

__global__ void gmax_kernel(const float* __restrict__ fm,
                            float* __restrict__ out) {
  int t = blockIdx.x * blockDim.x + threadIdx.x;
  if (t >= BS * 256) return;
  int b = t >> 8, c = t & 255;
  float m = -INFINITY;
  for (int v = 0; v < V2N; ++v)
    m = fmaxf(m, fm[((size_t)b * V2N + v) * 256 + c]);
  out[t] = m;
}

// ---------------------------------------------------------------------------
// bf16 helpers (RNE)
// ---------------------------------------------------------------------------
__device__ __forceinline__ ushort_t f2bf(float f) {
  unsigned u = __float_as_uint(f);
  u += 0x7FFFu + ((u >> 16) & 1u);
  return (ushort_t)(u >> 16);
}

// fuse gather → bf16, K padded 1424→1440 with zeros
#define KP1 1440
__global__ void fuse_cast_kernel(const float* __restrict__ fm2buf,
                                 const float* __restrict__ fm5buf,
                                 const float* __restrict__ fm7buf,
                                 const int* __restrict__ n1,
                                 const int* __restrict__ n2,
                                 const float* __restrict__ fglob,
                                 const float* __restrict__ onehot,
                                 ushort_t* __restrict__ fuse_b) {
  long long t = (long long)blockIdx.x * blockDim.x + threadIdx.x;
  if (t >= (long long)BS * V0 * KP1) return;
  int c = (int)(t % KP1);
  long long bv = t / KP1;
  int b = (int)(bv / V0);
  float val;
  if (c < 192) {
    int cc = (c < 32) ? c : (c < 96 ? c - 32 : c - 96);
    val = fm2buf[(size_t)bv * 96 + cc];
  } else if (c < 672) {
    int j = n1[bv];
    int cc = (c < 320) ? c - 192 : (c < 480 ? c - 320 : c - 480);
    val = fm5buf[((size_t)b * V1N + j) * 192 + cc];
  } else if (c < 1152) {
    int j = n2[bv];
    int cc = (c < 896) ? c - 672 : c - 896;
    val = fm7buf[((size_t)b * V2N + j) * 256 + cc];
  } else if (c < 1408) {
    val = fglob[b * 256 + (c - 1152)];
  } else if (c < 1424) {
    val = onehot[b * 16 + (c - 1408)];
  } else {
    val = 0.f;
  }
  fuse_b[t] = f2bf(val);
}

// generic cast with row/col padding: out[NR][KC], src[nr][kc]
__global__ void castpad_kernel(const float* __restrict__ src, int nr, int kc,
                               ushort_t* __restrict__ out, int NR, int KC) {
  long long t = (long long)blockIdx.x * blockDim.x + threadIdx.x;
  if (t >= (long long)NR * KC) return;
  int k = (int)(t % KC);
  int n = (int)(t / KC);
  float v = (n < nr && k < kc) ? src[(size_t)n * kc + k] : 0.f;
  out[t] = f2bf(v);
}

__global__ void padbias_kernel(const float* __restrict__ src, int n,
                               float* __restrict__ out, int N) {
  int t = blockIdx.x * blockDim.x + threadIdx.x;
  if (t < N) out[t] = (t < n) ? src[t] : 0.f;
}

// ---------------------------------------------------------------------------
// bf16 MFMA GEMM: C[M,N] = op(A[M,K] @ B[N,K]^T + bias)
// 128x128 tile, BK=32, 4 waves (2x2), 4x4 16x16x32 mfma per wave.
// global_load_lds width=16 staging (m97 structure).
// mode 0: relu → bf16 store to Cb (ldc cols). mode 1: f32 store to Cf, col<nvalid.
// ---------------------------------------------------------------------------
typedef const __attribute__((address_space(1))) unsigned int gas_u32;
typedef __attribute__((address_space(3))) unsigned int las_u32;

__global__ __launch_bounds__(256) void gemm_mfma_nt(
    const ushort_t* __restrict__ A, const ushort_t* __restrict__ B,
    const float* __restrict__ bias, ushort_t* __restrict__ Cb,
    float* __restrict__ Cf, int K, int ldc, int nvalid, int mode) {
  __shared__ ushort_t As[128 * 32];
  __shared__ ushort_t Bs[128 * 32];
  int tid = threadIdx.x;
  int lane = tid & 63, w = tid >> 6;
  int wm = (w >> 1) * 64, wn = (w & 1) * 64;
  int bm = blockIdx.y * 128, bn = blockIdx.x * 128;
  f32x4 acc[4][4];
#pragma unroll
  for (int i = 0; i < 4; ++i)
#pragma unroll
    for (int j = 0; j < 4; ++j) acc[i][j] = (f32x4){0.f, 0.f, 0.f, 0.f};

  int rowA0 = lane >> 2;           // 0..15 within segment
  int colA0 = (lane & 3) * 8;      // element offset (8 bf16 = 16 B)
  int seg0 = w * 2;                // this wave's segments
  const ushort_t* ga0 = A + (size_t)(bm + seg0 * 16 + rowA0) * K + colA0;
  const ushort_t* ga1 = A + (size_t)(bm + (seg0 + 1) * 16 + rowA0) * K + colA0;
  const ushort_t* gb0 = B + (size_t)(bn + seg0 * 16 + rowA0) * K + colA0;
  const ushort_t* gb1 = B + (size_t)(bn + (seg0 + 1) * 16 + rowA0) * K + colA0;
  ushort_t* la0 = As + seg0 * 512;
  ushort_t* la1 = As + (seg0 + 1) * 512;
  ushort_t* lb0 = Bs + seg0 * 512;
  ushort_t* lb1 = Bs + (seg0 + 1) * 512;

  int kq = (lane >> 4) * 8;        // frag k offset
  int rA = lane & 15;

  for (int k0 = 0; k0 < K; k0 += 32) {
    __builtin_amdgcn_global_load_lds((gas_u32*)(ga0 + k0), (las_u32*)la0, 16, 0, 0);
    __builtin_amdgcn_global_load_lds((gas_u32*)(ga1 + k0), (las_u32*)la1, 16, 0, 0);
    __builtin_amdgcn_global_load_lds((gas_u32*)(gb0 + k0), (las_u32*)lb0, 16, 0, 0);
    __builtin_amdgcn_global_load_lds((gas_u32*)(gb1 + k0), (las_u32*)lb1, 16, 0, 0);
    __syncthreads();
    bf16x8 af[4], bfr[4];
#pragma unroll
    for (int i = 0; i < 4; ++i)
      af[i] = *(const bf16x8*)(As + (wm + i * 16 + rA) * 32 + kq);
#pragma unroll
    for (int j = 0; j < 4; ++j)
      bfr[j] = *(const bf16x8*)(Bs + (wn + j * 16 + rA) * 32 + kq);
#pragma unroll
    for (int i = 0; i < 4; ++i)
#pragma unroll
      for (int j = 0; j < 4; ++j)
        acc[i][j] = __builtin_amdgcn_mfma_f32_16x16x32_bf16(af[i], bfr[j],
                                                            acc[i][j], 0, 0, 0);
    __syncthreads();
  }

  // epilogue: C/D layout col=lane&15, row=(lane>>4)*4+reg  [verified m89/m91]
  int rowq = (lane >> 4) * 4;
  int coll = lane & 15;
#pragma unroll
  for (int i = 0; i < 4; ++i) {
#pragma unroll
    for (int j = 0; j < 4; ++j) {
      int col = bn + wn + j * 16 + coll;
      float bi = bias[col];
#pragma unroll
      for (int r = 0; r < 4; ++r) {
        int row = bm + wm + i * 16 + rowq + r;
        float v = acc[i][j][r] + bi;
        if (mode == 0) {
          Cb[(size_t)row * ldc + col] = f2bf(fmaxf(v, 0.f));
        } else if (col < nvalid) {
          Cf[(size_t)row * ldc + col] = v;
        }
      }
    }
  }
}

// ---------------------------------------------------------------------------
extern "C" void kernel_launch(void* const* d_in, const int* in_sizes, int n_in,
                              void* d_out, int out_size, void* d_ws,
                              size_t ws_size, hipStream_t stream) {
  const float* vertices = (const float*)d_in[0];
  const float* onehot = (const float*)d_in[1];
  const float* d0 = (const float*)d_in[2];
  const float *w[8], *bb[8], *dd[8];
  for (int i = 1; i <= 7; ++i) {
    w[i] = (const float*)d_in[3 * i];
    bb[i] = (const float*)d_in[3 * i + 1];
    dd[i] = (const float*)d_in[3 * i + 2];
  }
  const float* cw1 = (const float*)d_in[24];
  const float* cb1 = (const float*)d_in[25];
  const float* cw2 = (const float*)d_in[26];
  const float* cb2 = (const float*)d_in[27];
  const float* cw3 = (const float*)d_in[28];
  const float* cb3 = (const float*)d_in[29];
  float* out = (float*)d_out;

  char* wsp = (char*)d_ws;
  size_t off = 0;
  auto alloc = [&](size_t bytes) -> void* {
    void* p = wsp + off;
    off += (bytes + 255) & ~(size_t)255;
    return p;
  };
  const int M = BS * V0;  // 16384
  int* perm1 = (int*)alloc(512 * 4);
  int* perm2 = (int*)alloc(128 * 4);
  int* ni1 = (int*)alloc((size_t)BS * V0 * 32 * 4);
  int* ni2 = (int*)alloc((size_t)BS * V1N * 32 * 4);
  int* ni3 = (int*)alloc((size_t)BS * V2N * 32 * 4);
  float* fm2buf = (float*)alloc((size_t)BS * V0 * 96 * 4);
  float* fm5buf = (float*)alloc((size_t)BS * V1N * 192 * 4);
  float* fm7buf = (float*)alloc((size_t)BS * V2N * 256 * 4);
  float* fbuf = (float*)alloc((size_t)BS * V0 * 64 * 4);
  float* v1 = (float*)alloc((size_t)BS * V1N * 3 * 4);
  float* v2 = (float*)alloc((size_t)BS * V2N * 3 * 4);
  int* n1 = (int*)alloc((size_t)BS * V0 * 4);
  int* n2 = (int*)alloc((size_t)BS * V0 * 4);
  float* fglob = (float*)alloc((size_t)BS * 256 * 4);
  ushort_t* fuse_b = (ushort_t*)alloc((size_t)M * KP1 * 2);   // 47.2 MB
  ushort_t* h1b = (ushort_t*)alloc((size_t)M * 1024 * 2);     // 33.6 MB
  ushort_t* h2b = (ushort_t*)alloc((size_t)M * 512 * 2);      // 16.8 MB
  ushort_t* cw1b = (ushort_t*)alloc((size_t)1024 * KP1 * 2);  // 2.95 MB
  ushort_t* cw2b = (ushort_t*)alloc((size_t)512 * 1024 * 2);  // 1.05 MB
  ushort_t* cw3b = (ushort_t*)alloc((size_t)128 * 512 * 2);   // 0.13 MB
  float* cb3p = (float*)alloc(128 * 4);
  // peak ≈ 116 MB

  perm_kernel<<<1, 1024, 0, stream>>>(perm1, perm2);

  // weight casts (input-only deps)
  castpad_kernel<<<(1024 * KP1 + 255) / 256, 256, 0, stream>>>(cw1, 1024, 1424, cw1b, 1024, KP1);
  castpad_kernel<<<(512 * 1024 + 255) / 256, 256, 0, stream>>>(cw2, 512, 1024, cw2b, 512, 1024);
  castpad_kernel<<<(128 * 512 + 255) / 256, 256, 0, stream>>>(cw3, 50, 512, cw3b, 128, 512);
  padbias_kernel<<<1, 128, 0, stream>>>(cb3, 50, cb3p, 128);

  float rr1 = 0.0625f;
  float rr2 = (float)(0.39 * 0.39);
  float rr3 = (float)(0.63 * 0.63);

  // level 1 (V=2048)
  qbp_kernel<<<BS * V0 / 4, 256, 0, stream>>>(vertices, V0, 32, rr1, ni1);
  conv_surface_kernel<<<BS * V0 / 8, 256, 0, stream>>>(vertices, ni1, d0, fm2buf, V0, 96);
  linear64_kernel<<<BS * V0 * 64 / 256, 256, 0, stream>>>(fm2buf, 96, 32, w[1], bb[1], fbuf, BS * V0);
  conv_act_kernel<<<BS * V0 / 8, 256, 0, stream>>>(vertices, dd[1], ni1, fbuf, fm2buf, V0, 96, 32);
  linear64_kernel<<<BS * V0 * 64 / 256, 256, 0, stream>>>(fm2buf, 96, 64, w[2], bb[2], fbuf, BS * V0);
  conv_act_kernel<<<BS * V0 / 8, 256, 0, stream>>>(vertices, dd[2], ni1, fbuf, fm2buf, V0, 96, 64);
  pool_kernel<<<BS * V1N / 4, 256, 0, stream>>>(vertices, fm2buf, 96, 96, V0, perm1, V1N, rr1, v1, fm5buf, 192);

  // level 2 (V=512)
  qbp_kernel<<<BS * V1N / 4, 256, 0, stream>>>(v1, V1N, 32, rr2, ni2);
  linear64_kernel<<<BS * V1N * 64 / 256, 256, 0, stream>>>(fm5buf, 192, 96, w[3], bb[3], fbuf, BS * V1N);
  conv_act_kernel<<<BS * V1N / 8, 256, 0, stream>>>(v1, dd[3], ni2, fbuf, fm5buf, V1N, 192, 96);
  linear64_kernel<<<BS * V1N * 64 / 256, 256, 0, stream>>>(fm5buf, 192, 128, w[4], bb[4], fbuf, BS * V1N);
  conv_act_kernel<<<BS * V1N / 8, 256, 0, stream>>>(v1, dd[4], ni2, fbuf, fm5buf, V1N, 192, 128);
  linear64_kernel<<<BS * V1N * 64 / 256, 256, 0, stream>>>(fm5buf, 192, 160, w[5], bb[5], fbuf, BS * V1N);
  conv_act_kernel<<<BS * V1N / 8, 256, 0, stream>>>(v1, dd[5], ni2, fbuf, fm5buf, V1N, 192, 160);
  pool_kernel<<<BS * V2N / 4, 256, 0, stream>>>(v1, fm5buf, 192, 192, V1N, perm2, V2N, rr2, v2, fm7buf, 256);

  // level 3 (V=128)
  qbp_kernel<<<BS * V2N / 4, 256, 0, stream>>>(v2, V2N, 32, rr3, ni3);
  linear64_kernel<<<BS * V2N * 64 / 256, 256, 0, stream>>>(fm7buf, 256, 192, w[6], bb[6], fbuf, BS * V2N);
  conv_act_kernel<<<BS * V2N / 8, 256, 0, stream>>>(v2, dd[6], ni3, fbuf, fm7buf, V2N, 256, 192);
  linear64_kernel<<<BS * V2N * 64 / 256, 256, 0, stream>>>(fm7buf, 256, 224, w[7], bb[7], fbuf, BS * V2N);
  conv_act_kernel<<<BS * V2N / 8, 256, 0, stream>>>(v2, dd[7], ni3, fbuf, fm7buf, V2N, 256, 224);

  gmax_kernel<<<BS, 256, 0, stream>>>(fm7buf, fglob);
  nearest_kernel<<<BS * V0 / 256, 256, 0, stream>>>(vertices, v1, V1N, n1);
  nearest_kernel<<<BS * V0 / 256, 256, 0, stream>>>(vertices, v2, V2N, n2);

  fuse_cast_kernel<<<(int)(((long long)M * KP1 + 255) / 256), 256, 0, stream>>>(
      fm2buf, fm5buf, fm7buf, n1, n2, fglob, onehot, fuse_b);

  // MLP head: bf16 MFMA
  gemm_mfma_nt<<<dim3(1024 / 128, M / 128), 256, 0, stream>>>(
      fuse_b, cw1b, cb1, h1b, nullptr, KP1, 1024, 1024, 0);
  gemm_mfma_nt<<<dim3(512 / 128, M / 128), 256, 0, stream>>>(
      h1b, cw2b, cb2, h2b, nullptr, 1024, 512, 512, 0);
  gemm_mfma_nt<<<dim3(1, M / 128), 256, 0, stream>>>(
      h2b, cw3b, cb3p, nullptr, out, 512, 50, 50, 1);
}

// Round 6
// 790.284 us; speedup vs baseline: 3.6863x; 1.0200x over previous
//
#include <hip/hip_runtime.h>
#include <hip/hip_bf16.h>

#define BS 8
#define V0 2048
#define V1N 512
#define V2N 128

typedef unsigned short ushort_t;
typedef __attribute__((ext_vector_type(8))) short bf16x8;
typedef __attribute__((ext_vector_type(4))) float f32x4;

// ---------------------------------------------------------------------------
// Threefry2x32 cipher (JAX partitionable mode — verified R4)
// ---------------------------------------------------------------------------
__device__ __forceinline__ void tf2x32(unsigned k0, unsigned k1,
                                       unsigned x0, unsigned x1,
                                       unsigned &o0, unsigned &o1) {
  unsigned ks2 = k0 ^ k1 ^ 0x1BD11BDAu;
  x0 += k0; x1 += k1;
#define RR(r) { x0 += x1; x1 = (x1 << (r)) | (x1 >> (32 - (r))); x1 ^= x0; }
  RR(13) RR(15) RR(26) RR(6)   x0 += k1;  x1 += ks2 + 1u;
  RR(17) RR(29) RR(16) RR(24)  x0 += ks2; x1 += k0 + 2u;
  RR(13) RR(15) RR(26) RR(6)   x0 += k0;  x1 += k1 + 3u;
  RR(17) RR(29) RR(16) RR(24)  x0 += k1;  x1 += ks2 + 4u;
  RR(13) RR(15) RR(26) RR(6)   x0 += ks2; x1 += k0 + 5u;
#undef RR
  o0 = x0; o1 = x1;
}

// perm via rank-sort (replaces single-block bitonic ~90µs serial):
// bits[0:2048]   = round1 bits for n=2048 (key = fold_in(42,1))
// bits[2048:4096]= round2 bits for n=2048
// bits[4096:4608]= round1 bits for n=512  (key = fold_in(42,2))
__global__ void perm_bits_kernel(unsigned* __restrict__ bits) {
  int t = blockIdx.x * blockDim.x + threadIdx.x;
  unsigned k0, k1, nk0, nk1, sk0, sk1, o0, o1;
  if (t < 2048) {
    tf2x32(0u, 42u, 0u, 1u, k0, k1);         // key1 = fold_in(key42,1)
    tf2x32(k0, k1, 0u, 0u, nk0, nk1);        // newkey (partitionable split)
    tf2x32(k0, k1, 0u, 1u, sk0, sk1);        // subkey round1
    tf2x32(sk0, sk1, 0u, (unsigned)t, o0, o1);
    bits[t] = o0 ^ o1;
    tf2x32(nk0, nk1, 0u, 1u, sk0, sk1);      // subkey round2
    tf2x32(sk0, sk1, 0u, (unsigned)t, o0, o1);
    bits[2048 + t] = o0 ^ o1;
  } else if (t < 2560) {
    int u = t - 2048;
    tf2x32(0u, 42u, 0u, 2u, k0, k1);         // key2 = fold_in(key42,2)
    tf2x32(k0, k1, 0u, 1u, sk0, sk1);        // subkey round1
    tf2x32(sk0, sk1, 0u, (unsigned)u, o0, o1);
    bits[4096 + u] = o0 ^ o1;
  }
}

// stable-sort rank: rank[t] = #{s: b[s]<b[t]} + #{s<t: b[s]==b[t]}
__global__ void perm_rank_kernel(const unsigned* __restrict__ bits,
                                 int* __restrict__ rank) {
  int t = blockIdx.x * 256 + threadIdx.x;
  int n, base;
  if (t < 2048)      { n = 2048; base = 0; }
  else if (t < 4096) { n = 2048; base = 2048; }
  else if (t < 4608) { n = 512;  base = 4096; }
  else return;
  int tt = t - base;
  unsigned bt = bits[t];
  int cnt = 0;
  for (int s = 0; s < n; ++s) {
    unsigned bs = bits[base + s];
    cnt += (bs < bt) || (bs == bt && s < tt);
  }
  rank[t] = cnt;
}

__global__ void perm_compose_kernel(const int* __restrict__ rank,
                                    int* __restrict__ perm1,
                                    int* __restrict__ perm2) {
  __shared__ int a1[2048];
  __shared__ int a2[2048];
  int tid = threadIdx.x;
  for (int i = tid; i < 2048; i += 1024) a1[rank[i]] = i;
  __syncthreads();
  for (int i = tid; i < 2048; i += 1024) a2[rank[2048 + i]] = a1[i];
  __syncthreads();
  for (int i = tid; i < 512; i += 1024) perm1[i] = a2[i];
  for (int i = tid; i < 512; i += 1024) a1[rank[4096 + i]] = i;
  __syncthreads();
  for (int i = tid; i < 128; i += 1024) perm2[i] = a1[i];
}

// ---------------------------------------------------------------------------
__device__ __forceinline__ float sqdist_f32(float cx, float cy, float cz,
                                            const float* p) {
  float dx = __fsub_rn(cx, p[0]);
  float dy = __fsub_rn(cy, p[1]);
  float dz = __fsub_rn(cz, p[2]);
  return __fadd_rn(__fadd_rn(__fmul_rn(dx, dx), __fmul_rn(dy, dy)),
                   __fmul_rn(dz, dz));
}

__global__ void qbp_kernel(const float* __restrict__ pts, int Nv, int nsample,
                           float rr, int* __restrict__ out) {
  int wid = blockIdx.x * (blockDim.x >> 6) + (threadIdx.x >> 6);
  int lane = threadIdx.x & 63;
  if (wid >= BS * Nv) return;
  int b = wid / Nv, i = wid - b * Nv;
  const float* base = pts + (size_t)b * Nv * 3;
  float cx = base[i * 3], cy = base[i * 3 + 1], cz = base[i * 3 + 2];
  int cnt = 0, idx0 = 0;
  for (int j0 = 0; j0 < Nv; j0 += 64) {
    int j = j0 + lane;
    float d2 = sqdist_f32(cx, cy, cz, base + (size_t)j * 3);
    bool in = (d2 <= rr);
    unsigned long long mask = __ballot(in);
    if (cnt == 0 && mask) idx0 = j0 + __builtin_ctzll(mask);
    if (in) {
      int rank = cnt + __popcll(mask & ((1ull << lane) - 1ull));
      if (rank < nsample) out[(size_t)wid * nsample + rank] = j;
    }
    cnt += __popcll(mask);
    if (cnt >= nsample) break;
  }
  for (int s = cnt + lane; s < nsample; s += 64)
    out[(size_t)wid * nsample + s] = idx0;
}

// ---------------------------------------------------------------------------
__device__ __forceinline__ void dirn(const float* base, int v, int nb,
                                     float& ox, float& oy, float& oz) {
  float dx = __fsub_rn(base[nb * 3 + 0], base[v * 3 + 0]);
  float dy = __fsub_rn(base[nb * 3 + 1], base[v * 3 + 1]);
  float dz = __fsub_rn(base[nb * 3 + 2], base[v * 3 + 2]);
  float s2 = __fadd_rn(__fadd_rn(__fmul_rn(dx, dx), __fmul_rn(dy, dy)),
                       __fmul_rn(dz, dz));
  float nrm = fmaxf(__fsqrt_rn(s2), 1e-12f);
  ox = __fdiv_rn(dx, nrm); oy = __fdiv_rn(dy, nrm); oz = __fdiv_rn(dz, nrm);
}

__device__ __forceinline__ void norm_col(const float* d, int k,
                                         float& ox, float& oy, float& oz) {
  float x = d[k], y = d[32 + k], z = d[64 + k];
  float s2 = __fadd_rn(__fadd_rn(__fmul_rn(x, x), __fmul_rn(y, y)),
                       __fmul_rn(z, z));
  float nrm = fmaxf(__fsqrt_rn(s2), 1e-12f);
  ox = __fdiv_rn(x, nrm); oy = __fdiv_rn(y, nrm); oz = __fdiv_rn(z, nrm);
}

__global__ void conv_surface_kernel(const float* __restrict__ pts,
                                    const int* __restrict__ ni,
                                    const float* __restrict__ d0,
                                    float* __restrict__ out, int Nv,
                                    int ldout) {
  __shared__ float sdir[3][32];
  __shared__ float sdn[8][32][3];
  int tid = threadIdx.x;
  if (tid < 32) {
    float x, y, z; norm_col(d0, tid, x, y, z);
    sdir[0][tid] = x; sdir[1][tid] = y; sdir[2][tid] = z;
  }
  int vloc = tid >> 5, k = tid & 31;
  size_t bvg = (size_t)blockIdx.x * 8 + vloc;
  int b = (int)(bvg / Nv), v = (int)(bvg % Nv);
  const float* base = pts + (size_t)b * Nv * 3;
  int nb = ni[bvg * 32 + k];
  float x, y, z; dirn(base, v, nb, x, y, z);
  sdn[vloc][k][0] = x; sdn[vloc][k][1] = y; sdn[vloc][k][2] = z;
  __syncthreads();
  float m = 0.f;
  for (int n = 0; n < 32; ++n) {
    float d = sdn[vloc][n][0] * sdir[0][k] + sdn[vloc][n][1] * sdir[1][k] +
              sdn[vloc][n][2] * sdir[2][k];
    m = fmaxf(m, fmaxf(d, 0.f));
  }
  out[bvg * ldout + k] = m;
}

__global__ void linear64_kernel(const float* __restrict__ fm, int ld, int Cin,
                                const float* __restrict__ w,
                                const float* __restrict__ bias,
                                float* __restrict__ f, int rows) {
  int t = blockIdx.x * blockDim.x + threadIdx.x;
  int o = t & 63, bv = t >> 6;
  if (bv >= rows) return;
  const float* a = fm + (size_t)bv * ld;
  float acc = bias[o];
  for (int c = 0; c < Cin; ++c) acc += a[c] * w[c * 64 + o];
  f[(size_t)bv * 64 + o] = acc;
}

__global__ void conv_act_kernel(const float* __restrict__ pts,
                                const float* __restrict__ dd,
                                const int* __restrict__ ni,
                                const float* __restrict__ f,
                                float* __restrict__ out, int Nv, int ldout,
                                int colofs) {
  __shared__ float sdir[3][32];
  __shared__ float sdn[8][32][3];
  __shared__ int sidx[8][32];
  int tid = threadIdx.x;
  if (tid < 32) {
    float x, y, z; norm_col(dd, tid, x, y, z);
    sdir[0][tid] = x; sdir[1][tid] = y; sdir[2][tid] = z;
  }
  int vloc = tid >> 5, k = tid & 31;
  size_t bvg = (size_t)blockIdx.x * 8 + vloc;
  int b = (int)(bvg / Nv), v = (int)(bvg % Nv);
  const float* base = pts + (size_t)b * Nv * 3;
  int nb = ni[bvg * 32 + k];
  float x, y, z; dirn(base, v, nb, x, y, z);
  sdn[vloc][k][0] = x; sdn[vloc][k][1] = y; sdn[vloc][k][2] = z;
  sidx[vloc][k] = nb;
  __syncthreads();
  float m = -INFINITY;
  size_t fb = (size_t)b * Nv * 64;
  for (int n = 0; n < 32; ++n) {
    float th = fmaxf(sdn[vloc][n][0] * sdir[0][k] + sdn[vloc][n][1] * sdir[1][k] +
                     sdn[vloc][n][2] * sdir[2][k], 0.f);
    float sup = f[fb + (size_t)sidx[vloc][n] * 64 + 32 + k];
    m = fmaxf(m, th * sup);
  }
  float center = f[bvg * 64 + k];
  out[bvg * ldout + colofs + k] = fmaxf(center + m, 0.f);
}

__global__ void pool_kernel(const float* __restrict__ pts_in,
                            const float* __restrict__ fm_in, int ld_in, int C,
                            int Nv_in, const int* __restrict__ perm, int Nv_out,
                            float rr, float* __restrict__ pts_out,
                            float* __restrict__ fm_out, int ld_out) {
  int wid = blockIdx.x * (blockDim.x >> 6) + (threadIdx.x >> 6);
  int lane = threadIdx.x & 63;
  if (wid >= BS * Nv_out) return;
  int b = wid / Nv_out, pp = wid - b * Nv_out;
  int v = perm[pp];
  const float* base = pts_in + (size_t)b * Nv_in * 3;
  float cx = base[v * 3], cy = base[v * 3 + 1], cz = base[v * 3 + 2];
  int nb[4]; int cnt = 0;
  for (int j0 = 0; j0 < Nv_in && cnt < 4; j0 += 64) {
    int j = j0 + lane;
    float d2 = sqdist_f32(cx, cy, cz, base + (size_t)j * 3);
    unsigned long long mask = __ballot(d2 <= rr);
    while (mask && cnt < 4) {
      int bp = __builtin_ctzll(mask);
      mask &= mask - 1;
      nb[cnt++] = j0 + bp;
    }
  }
  for (int q = cnt; q < 4; ++q) nb[q] = nb[0];
  if (lane < 3) pts_out[((size_t)b * Nv_out + pp) * 3 + lane] = base[v * 3 + lane];
  size_t inrow = (size_t)b * Nv_in;
  size_t outrow = ((size_t)b * Nv_out + pp) * ld_out;
  for (int c = lane; c < C; c += 64) {
    float m = fm_in[(inrow + nb[0]) * ld_in + c];
    m = fmaxf(m, fm_in[(inrow + nb[1]) * ld_in + c]);
    m = fmaxf(m, fm_in[(inrow + nb[2]) * ld_in + c]);
    m = fmaxf(m, fm_in[(inrow + nb[3]) * ld_in + c]);
    fm_out[outrow + c] = m;
  }
}

__global__ void gmax_kernel(const float* __restrict__ fm,
                            float* __restrict__ out) {
  int t = blockIdx.x * blockDim.x + threadIdx.x;
  if (t >= BS * 256) return;
  int b = t >> 8, c = t & 255;
  float m = -INFINITY;
  for (int v = 0; v < V2N; ++v)
    m = fmaxf(m, fm[((size_t)b * V2N + v) * 256 + c]);
  out[t] = m;
}

// ---------------------------------------------------------------------------
__device__ __forceinline__ ushort_t f2bf(float f) {
  unsigned u = __float_as_uint(f);
  u += 0x7FFFu + ((u >> 16) & 1u);
  return (ushort_t)(u >> 16);
}

#define KP1 1440
__device__ __forceinline__ float fuse_val(const float* r2, const float* r5,
                                          const float* r7, const float* rg,
                                          const float* roh, int c) {
  if (c < 192) {
    int cc = (c < 32) ? c : (c < 96 ? c - 32 : c - 96);
    return r2[cc];
  } else if (c < 672) {
    int cc = (c < 320) ? c - 192 : (c < 480 ? c - 320 : c - 480);
    return r5[cc];
  } else if (c < 1152) {
    int cc = (c < 896) ? c - 672 : c - 896;
    return r7[cc];
  } else if (c < 1408) {
    return rg[c - 1152];
  } else if (c < 1424) {
    return roh[c - 1408];
  }
  return 0.f;
}

// one block per fused row: inline argmin(n1,n2) + gather + bf16 cast.
// first-occurrence argmin: min over u64 (d2_bits<<32)|idx (d2>=0 so float-bit
// order == numeric order; ties -> smaller idx).
__global__ __launch_bounds__(256) void fuse_row_kernel(
    const float* __restrict__ fm2, const float* __restrict__ fm5,
    const float* __restrict__ fm7, const float* __restrict__ fglob,
    const float* __restrict__ onehot, const float* __restrict__ verts,
    const float* __restrict__ v1, const float* __restrict__ v2,
    ushort_t* __restrict__ fuse_b) {
  __shared__ unsigned long long red[256];
  __shared__ int sn1, sn2;
  int bv = blockIdx.x;
  int b = bv >> 11;
  int tid = threadIdx.x;
  float cx = verts[(size_t)bv * 3 + 0];
  float cy = verts[(size_t)bv * 3 + 1];
  float cz = verts[(size_t)bv * 3 + 2];
  // n1 over 512
  unsigned long long best = ~0ull;
  const float* sb = v1 + (size_t)b * V1N * 3;
  for (int j = tid; j < V1N; j += 256) {
    float d2 = sqdist_f32(cx, cy, cz, sb + (size_t)j * 3);
    unsigned long long key =
        (((unsigned long long)__float_as_uint(d2)) << 32) | (unsigned)j;
    best = best < key ? best : key;
  }
  red[tid] = best;
  __syncthreads();
  for (int s = 128; s > 0; s >>= 1) {
    if (tid < s) red[tid] = red[tid] < red[tid + s] ? red[tid] : red[tid + s];
    __syncthreads();
  }
  if (tid == 0) sn1 = (int)(red[0] & 0xffffffffu);
  __syncthreads();
  // n2 over 128
  best = ~0ull;
  sb = v2 + (size_t)b * V2N * 3;
  for (int j = tid; j < V2N; j += 256) {
    float d2 = sqdist_f32(cx, cy, cz, sb + (size_t)j * 3);
    unsigned long long key =
        (((unsigned long long)__float_as_uint(d2)) << 32) | (unsigned)j;
    best = best < key ? best : key;
  }
  red[tid] = best;
  __syncthreads();
  for (int s = 128; s > 0; s >>= 1) {
    if (tid < s) red[tid] = red[tid] < red[tid + s] ? red[tid] : red[tid + s];
    __syncthreads();
  }
  if (tid == 0) sn2 = (int)(red[0] & 0xffffffffu);
  __syncthreads();
  const float* r2 = fm2 + (size_t)bv * 96;
  const float* r5 = fm5 + ((size_t)b * V1N + sn1) * 192;
  const float* r7 = fm7 + ((size_t)b * V2N + sn2) * 256;
  const float* rg = fglob + b * 256;
  const float* roh = onehot + b * 16;
  ushort_t* orow = fuse_b + (size_t)bv * KP1;
  for (int c = tid; c < KP1; c += 256)
    orow[c] = f2bf(fuse_val(r2, r5, r7, rg, roh, c));
}

// single fused weight-prep: cw1(pad K 1424->1440), cw2, cw3(pad rows 50->128), cb3
__global__ void prep_weights_kernel(const float* __restrict__ cw1,
                                    const float* __restrict__ cw2,
                                    const float* __restrict__ cw3,
                                    const float* __restrict__ cb3,
                                    ushort_t* __restrict__ cw1b,
                                    ushort_t* __restrict__ cw2b,
                                    ushort_t* __restrict__ cw3b,
                                    float* __restrict__ cb3p) {
  long long t = (long long)blockIdx.x * 256 + threadIdx.x;
  const long long N1 = 1024LL * KP1, N2 = 512LL * 1024, N3 = 128LL * 512;
  if (t < N1) {
    int k = (int)(t % KP1);
    int n = (int)(t / KP1);
    cw1b[t] = f2bf(k < 1424 ? cw1[(size_t)n * 1424 + k] : 0.f);
  } else if (t < N1 + N2) {
    long long u = t - N1;
    cw2b[u] = f2bf(cw2[u]);
  } else if (t < N1 + N2 + N3) {
    long long u = t - N1 - N2;
    int k = (int)(u & 511);
    int n = (int)(u >> 9);
    cw3b[u] = f2bf(n < 50 ? cw3[(size_t)n * 512 + k] : 0.f);
  } else if (t < N1 + N2 + N3 + 128) {
    int u = (int)(t - N1 - N2 - N3);
    cb3p[u] = u < 50 ? cb3[u] : 0.f;
  }
}

// ---------------------------------------------------------------------------
// bf16 MFMA GEMM (m97 structure) + XCD-colocating swizzle: all N-tiles of one
// M-band land on the same XCD (dispatch round-robin assumption; perf-only).
// ---------------------------------------------------------------------------
typedef const __attribute__((address_space(1))) unsigned int gas_u32;
typedef __attribute__((address_space(3))) unsigned int las_u32;

__global__ __launch_bounds__(256) void gemm_mfma_nt(
    const ushort_t* __restrict__ A, const ushort_t* __restrict__ B,
    const float* __restrict__ bias, ushort_t* __restrict__ Cb,
    float* __restrict__ Cf, int K, int ldc, int nvalid, int mode) {
  __shared__ ushort_t As[128 * 32];
  __shared__ ushort_t Bs[128 * 32];
  int tid = threadIdx.x;
  int lane = tid & 63, w = tid >> 6;
  int wm = (w >> 1) * 64, wn = (w & 1) * 64;
  // XCD swizzle (requires gridDim.y % 8 == 0; holds for all 3 gemms)
  int nb = gridDim.x;
  int flat = blockIdx.x + nb * blockIdx.y;  // dispatch order (x-fastest)
  int xcd = flat & 7, slot = flat >> 3;
  int nidx = slot % nb;
  int mband = xcd + 8 * (slot / nb);
  int bm = mband * 128, bn = nidx * 128;
  f32x4 acc[4][4];
#pragma unroll
  for (int i = 0; i < 4; ++i)
#pragma unroll
    for (int j = 0; j < 4; ++j) acc[i][j] = (f32x4){0.f, 0.f, 0.f, 0.f};

  int rowA0 = lane >> 2;
  int colA0 = (lane & 3) * 8;
  int seg0 = w * 2;
  const ushort_t* ga0 = A + (size_t)(bm + seg0 * 16 + rowA0) * K + colA0;
  const ushort_t* ga1 = A + (size_t)(bm + (seg0 + 1) * 16 + rowA0) * K + colA0;
  const ushort_t* gb0 = B + (size_t)(bn + seg0 * 16 + rowA0) * K + colA0;
  const ushort_t* gb1 = B + (size_t)(bn + (seg0 + 1) * 16 + rowA0) * K + colA0;
  ushort_t* la0 = As + seg0 * 512;
  ushort_t* la1 = As + (seg0 + 1) * 512;
  ushort_t* lb0 = Bs + seg0 * 512;
  ushort_t* lb1 = Bs + (seg0 + 1) * 512;

  int kq = (lane >> 4) * 8;
  int rA = lane & 15;

  for (int k0 = 0; k0 < K; k0 += 32) {
    __builtin_amdgcn_global_load_lds((gas_u32*)(ga0 + k0), (las_u32*)la0, 16, 0, 0);
    __builtin_amdgcn_global_load_lds((gas_u32*)(ga1 + k0), (las_u32*)la1, 16, 0, 0);
    __builtin_amdgcn_global_load_lds((gas_u32*)(gb0 + k0), (las_u32*)lb0, 16, 0, 0);
    __builtin_amdgcn_global_load_lds((gas_u32*)(gb1 + k0), (las_u32*)lb1, 16, 0, 0);
    __syncthreads();
    bf16x8 af[4], bfr[4];
#pragma unroll
    for (int i = 0; i < 4; ++i)
      af[i] = *(const bf16x8*)(As + (wm + i * 16 + rA) * 32 + kq);
#pragma unroll
    for (int j = 0; j < 4; ++j)
      bfr[j] = *(const bf16x8*)(Bs + (wn + j * 16 + rA) * 32 + kq);
#pragma unroll
    for (int i = 0; i < 4; ++i)
#pragma unroll
      for (int j = 0; j < 4; ++j)
        acc[i][j] = __builtin_amdgcn_mfma_f32_16x16x32_bf16(af[i], bfr[j],
                                                            acc[i][j], 0, 0, 0);
    __syncthreads();
  }

  int rowq = (lane >> 4) * 4;
  int coll = lane & 15;
#pragma unroll
  for (int i = 0; i < 4; ++i) {
#pragma unroll
    for (int j = 0; j < 4; ++j) {
      int col = bn + wn + j * 16 + coll;
      float bi = bias[col];
#pragma unroll
      for (int r = 0; r < 4; ++r) {
        int row = bm + wm + i * 16 + rowq + r;
        float v = acc[i][j][r] + bi;
        if (mode == 0) {
          Cb[(size_t)row * ldc + col] = f2bf(fmaxf(v, 0.f));
        } else if (col < nvalid) {
          Cf[(size_t)row * ldc + col] = v;
        }
      }
    }
  }
}

// ---------------------------------------------------------------------------
extern "C" void kernel_launch(void* const* d_in, const int* in_sizes, int n_in,
                              void* d_out, int out_size, void* d_ws,
                              size_t ws_size, hipStream_t stream) {
  const float* vertices = (const float*)d_in[0];
  const float* onehot = (const float*)d_in[1];
  const float* d0 = (const float*)d_in[2];
  const float *w[8], *bb[8], *dd[8];
  for (int i = 1; i <= 7; ++i) {
    w[i] = (const float*)d_in[3 * i];
    bb[i] = (const float*)d_in[3 * i + 1];
    dd[i] = (const float*)d_in[3 * i + 2];
  }
  const float* cw1 = (const float*)d_in[24];
  const float* cb1 = (const float*)d_in[25];
  const float* cw2 = (const float*)d_in[26];
  const float* cb2 = (const float*)d_in[27];
  const float* cw3 = (const float*)d_in[28];
  const float* cb3 = (const float*)d_in[29];
  float* out = (float*)d_out;

  char* wsp = (char*)d_ws;
  size_t off = 0;
  auto alloc = [&](size_t bytes) -> void* {
    void* p = wsp + off;
    off += (bytes + 255) & ~(size_t)255;
    return p;
  };
  const int M = BS * V0;  // 16384
  unsigned* bits = (unsigned*)alloc(4608 * 4);
  int* rank = (int*)alloc(4608 * 4);
  int* perm1 = (int*)alloc(512 * 4);
  int* perm2 = (int*)alloc(128 * 4);
  int* ni1 = (int*)alloc((size_t)BS * V0 * 32 * 4);
  int* ni2 = (int*)alloc((size_t)BS * V1N * 32 * 4);
  int* ni3 = (int*)alloc((size_t)BS * V2N * 32 * 4);
  float* fm2buf = (float*)alloc((size_t)BS * V0 * 96 * 4);
  float* fm5buf = (float*)alloc((size_t)BS * V1N * 192 * 4);
  float* fm7buf = (float*)alloc((size_t)BS * V2N * 256 * 4);
  float* fbuf = (float*)alloc((size_t)BS * V0 * 64 * 4);
  float* v1 = (float*)alloc((size_t)BS * V1N * 3 * 4);
  float* v2 = (float*)alloc((size_t)BS * V2N * 3 * 4);
  float* fglob = (float*)alloc((size_t)BS * 256 * 4);
  ushort_t* fuse_b = (ushort_t*)alloc((size_t)M * KP1 * 2);
  ushort_t* h1b = (ushort_t*)alloc((size_t)M * 1024 * 2);
  ushort_t* h2b = (ushort_t*)alloc((size_t)M * 512 * 2);
  ushort_t* cw1b = (ushort_t*)alloc((size_t)1024 * KP1 * 2);
  ushort_t* cw2b = (ushort_t*)alloc((size_t)512 * 1024 * 2);
  ushort_t* cw3b = (ushort_t*)alloc((size_t)128 * 512 * 2);
  float* cb3p = (float*)alloc(128 * 4);

  // permutation (rank-sort, grid-parallel)
  perm_bits_kernel<<<10, 256, 0, stream>>>(bits);
  perm_rank_kernel<<<18, 256, 0, stream>>>(bits, rank);
  perm_compose_kernel<<<1, 1024, 0, stream>>>(rank, perm1, perm2);

  // fused weight prep
  {
    long long tot = 1024LL * KP1 + 512LL * 1024 + 128LL * 512 + 128;
    prep_weights_kernel<<<(int)((tot + 255) / 256), 256, 0, stream>>>(
        cw1, cw2, cw3, cb3, cw1b, cw2b, cw3b, cb3p);
  }

  float rr1 = 0.0625f;
  float rr2 = (float)(0.39 * 0.39);
  float rr3 = (float)(0.63 * 0.63);

  // level 1 (V=2048)
  qbp_kernel<<<BS * V0 / 4, 256, 0, stream>>>(vertices, V0, 32, rr1, ni1);
  conv_surface_kernel<<<BS * V0 / 8, 256, 0, stream>>>(vertices, ni1, d0, fm2buf, V0, 96);
  linear64_kernel<<<BS * V0 * 64 / 256, 256, 0, stream>>>(fm2buf, 96, 32, w[1], bb[1], fbuf, BS * V0);
  conv_act_kernel<<<BS * V0 / 8, 256, 0, stream>>>(vertices, dd[1], ni1, fbuf, fm2buf, V0, 96, 32);
  linear64_kernel<<<BS * V0 * 64 / 256, 256, 0, stream>>>(fm2buf, 96, 64, w[2], bb[2], fbuf, BS * V0);
  conv_act_kernel<<<BS * V0 / 8, 256, 0, stream>>>(vertices, dd[2], ni1, fbuf, fm2buf, V0, 96, 64);
  pool_kernel<<<BS * V1N / 4, 256, 0, stream>>>(vertices, fm2buf, 96, 96, V0, perm1, V1N, rr1, v1, fm5buf, 192);

  // level 2 (V=512)
  qbp_kernel<<<BS * V1N / 4, 256, 0, stream>>>(v1, V1N, 32, rr2, ni2);
  linear64_kernel<<<BS * V1N * 64 / 256, 256, 0, stream>>>(fm5buf, 192, 96, w[3], bb[3], fbuf, BS * V1N);
  conv_act_kernel<<<BS * V1N / 8, 256, 0, stream>>>(v1, dd[3], ni2, fbuf, fm5buf, V1N, 192, 96);
  linear64_kernel<<<BS * V1N * 64 / 256, 256, 0, stream>>>(fm5buf, 192, 128, w[4], bb[4], fbuf, BS * V1N);
  conv_act_kernel<<<BS * V1N / 8, 256, 0, stream>>>(v1, dd[4], ni2, fbuf, fm5buf, V1N, 192, 128);
  linear64_kernel<<<BS * V1N * 64 / 256, 256, 0, stream>>>(fm5buf, 192, 160, w[5], bb[5], fbuf, BS * V1N);
  conv_act_kernel<<<BS * V1N / 8, 256, 0, stream>>>(v1, dd[5], ni2, fbuf, fm5buf, V1N, 192, 160);
  pool_kernel<<<BS * V2N / 4, 256, 0, stream>>>(v1, fm5buf, 192, 192, V1N, perm2, V2N, rr2, v2, fm7buf, 256);

  // level 3 (V=128)
  qbp_kernel<<<BS * V2N / 4, 256, 0, stream>>>(v2, V2N, 32, rr3, ni3);
  linear64_kernel<<<BS * V2N * 64 / 256, 256, 0, stream>>>(fm7buf, 256, 192, w[6], bb[6], fbuf, BS * V2N);
  conv_act_kernel<<<BS * V2N / 8, 256, 0, stream>>>(v2, dd[6], ni3, fbuf, fm7buf, V2N, 256, 192);
  linear64_kernel<<<BS * V2N * 64 / 256, 256, 0, stream>>>(fm7buf, 256, 224, w[7], bb[7], fbuf, BS * V2N);
  conv_act_kernel<<<BS * V2N / 8, 256, 0, stream>>>(v2, dd[7], ni3, fbuf, fm7buf, V2N, 256, 224);

  gmax_kernel<<<BS, 256, 0, stream>>>(fm7buf, fglob);

  // fused: nearest(n1,n2) + gather + bf16 cast, one block per row
  fuse_row_kernel<<<M, 256, 0, stream>>>(fm2buf, fm5buf, fm7buf, fglob, onehot,
                                         vertices, v1, v2, fuse_b);

  // MLP head: bf16 MFMA
  gemm_mfma_nt<<<dim3(1024 / 128, M / 128), 256, 0, stream>>>(
      fuse_b, cw1b, cb1, h1b, nullptr, KP1, 1024, 1024, 0);
  gemm_mfma_nt<<<dim3(512 / 128, M / 128), 256, 0, stream>>>(
      h1b, cw2b, cb2, h2b, nullptr, 1024, 512, 512, 0);
  gemm_mfma_nt<<<dim3(1, M / 128), 256, 0, stream>>>(
      h2b, cw3b, cb3p, nullptr, out, 512, 50, 50, 1);
}

// Round 7
// 782.209 us; speedup vs baseline: 3.7244x; 1.0103x over previous
//
#include <hip/hip_runtime.h>
#include <hip/hip_bf16.h>

#define BS 8
#define V0 2048
#define V1N 512
#define V2N 128

typedef unsigned short ushort_t;
typedef __attribute__((ext_vector_type(8))) short bf16x8;
typedef __attribute__((ext_vector_type(4))) float f32x4;

// ---------------------------------------------------------------------------
// Threefry2x32 cipher (JAX partitionable mode — verified R4)
// ---------------------------------------------------------------------------
__device__ __forceinline__ void tf2x32(unsigned k0, unsigned k1,
                                       unsigned x0, unsigned x1,
                                       unsigned &o0, unsigned &o1) {
  unsigned ks2 = k0 ^ k1 ^ 0x1BD11BDAu;
  x0 += k0; x1 += k1;
#define RR(r) { x0 += x1; x1 = (x1 << (r)) | (x1 >> (32 - (r))); x1 ^= x0; }
  RR(13) RR(15) RR(26) RR(6)   x0 += k1;  x1 += ks2 + 1u;
  RR(17) RR(29) RR(16) RR(24)  x0 += ks2; x1 += k0 + 2u;
  RR(13) RR(15) RR(26) RR(6)   x0 += k0;  x1 += k1 + 3u;
  RR(17) RR(29) RR(16) RR(24)  x0 += k1;  x1 += ks2 + 4u;
  RR(13) RR(15) RR(26) RR(6)   x0 += ks2; x1 += k0 + 5u;
#undef RR
  o0 = x0; o1 = x1;
}

// bits[0:2048]   = round1 bits for n=2048 (key = fold_in(42,1))
// bits[2048:4096]= round2 bits for n=2048
// bits[4096:4608]= round1 bits for n=512  (key = fold_in(42,2))
__global__ void perm_bits_kernel(unsigned* __restrict__ bits) {
  int t = blockIdx.x * blockDim.x + threadIdx.x;
  unsigned k0, k1, nk0, nk1, sk0, sk1, o0, o1;
  if (t < 2048) {
    tf2x32(0u, 42u, 0u, 1u, k0, k1);         // key1 = fold_in(key42,1)
    tf2x32(k0, k1, 0u, 0u, nk0, nk1);        // newkey (partitionable split)
    tf2x32(k0, k1, 0u, 1u, sk0, sk1);        // subkey round1
    tf2x32(sk0, sk1, 0u, (unsigned)t, o0, o1);
    bits[t] = o0 ^ o1;
    tf2x32(nk0, nk1, 0u, 1u, sk0, sk1);      // subkey round2
    tf2x32(sk0, sk1, 0u, (unsigned)t, o0, o1);
    bits[2048 + t] = o0 ^ o1;
  } else if (t < 2560) {
    int u = t - 2048;
    tf2x32(0u, 42u, 0u, 2u, k0, k1);         // key2 = fold_in(key42,2)
    tf2x32(k0, k1, 0u, 1u, sk0, sk1);        // subkey round1
    tf2x32(sk0, sk1, 0u, (unsigned)u, o0, o1);
    bits[4096 + u] = o0 ^ o1;
  }
}

// stable-sort rank via LDS-staged scan (R6's global-scan version was
// latency-bound at 0.7% occupancy: 121 µs). Same-address LDS reads broadcast.
// rank[t] = #{s: b[s]<b[t]} + #{s<t: b[s]==b[t]}
__global__ __launch_bounds__(256) void perm_rank_kernel(
    const unsigned* __restrict__ bits, int* __restrict__ rank) {
  __shared__ unsigned sb[2048];
  int t = blockIdx.x * 256 + threadIdx.x;
  int n, base;
  if (t < 2048)      { n = 2048; base = 0; }
  else if (t < 4096) { n = 2048; base = 2048; }
  else               { n = 512;  base = 4096; }   // grid is exactly 18*256
  for (int i = threadIdx.x; i < n; i += 256) sb[i] = bits[base + i];
  __syncthreads();
  int tt = t - base;
  unsigned bt = sb[tt];
  int cnt = 0;
#pragma unroll 8
  for (int s = 0; s < n; ++s) {
    unsigned bs = sb[s];
    cnt += (bs < bt) || (bs == bt && s < tt);
  }
  rank[t] = cnt;
}

__global__ void perm_compose_kernel(const int* __restrict__ rank,
                                    int* __restrict__ perm1,
                                    int* __restrict__ perm2) {
  __shared__ int a1[2048];
  __shared__ int a2[2048];
  int tid = threadIdx.x;
  for (int i = tid; i < 2048; i += 1024) a1[rank[i]] = i;
  __syncthreads();
  for (int i = tid; i < 2048; i += 1024) a2[rank[2048 + i]] = a1[i];
  __syncthreads();
  for (int i = tid; i < 512; i += 1024) perm1[i] = a2[i];
  for (int i = tid; i < 512; i += 1024) a1[rank[4096 + i]] = i;
  __syncthreads();
  for (int i = tid; i < 128; i += 1024) perm2[i] = a1[i];
}

// ---------------------------------------------------------------------------
__device__ __forceinline__ float sqdist_f32(float cx, float cy, float cz,
                                            const float* p) {
  float dx = __fsub_rn(cx, p[0]);
  float dy = __fsub_rn(cy, p[1]);
  float dz = __fsub_rn(cz, p[2]);
  return __fadd_rn(__fadd_rn(__fmul_rn(dx, dx), __fmul_rn(dy, dy)),
                   __fmul_rn(dz, dz));
}

__global__ void qbp_kernel(const float* __restrict__ pts, int Nv, int nsample,
                           float rr, int* __restrict__ out) {
  int wid = blockIdx.x * (blockDim.x >> 6) + (threadIdx.x >> 6);
  int lane = threadIdx.x & 63;
  if (wid >= BS * Nv) return;
  int b = wid / Nv, i = wid - b * Nv;
  const float* base = pts + (size_t)b * Nv * 3;
  float cx = base[i * 3], cy = base[i * 3 + 1], cz = base[i * 3 + 2];
  int cnt = 0, idx0 = 0;
  for (int j0 = 0; j0 < Nv; j0 += 64) {
    int j = j0 + lane;
    float d2 = sqdist_f32(cx, cy, cz, base + (size_t)j * 3);
    bool in = (d2 <= rr);
    unsigned long long mask = __ballot(in);
    if (cnt == 0 && mask) idx0 = j0 + __builtin_ctzll(mask);
    if (in) {
      int rank = cnt + __popcll(mask & ((1ull << lane) - 1ull));
      if (rank < nsample) out[(size_t)wid * nsample + rank] = j;
    }
    cnt += __popcll(mask);
    if (cnt >= nsample) break;
  }
  for (int s = cnt + lane; s < nsample; s += 64)
    out[(size_t)wid * nsample + s] = idx0;
}

// ---------------------------------------------------------------------------
__device__ __forceinline__ void dirn(const float* base, int v, int nb,
                                     float& ox, float& oy, float& oz) {
  float dx = __fsub_rn(base[nb * 3 + 0], base[v * 3 + 0]);
  float dy = __fsub_rn(base[nb * 3 + 1], base[v * 3 + 1]);
  float dz = __fsub_rn(base[nb * 3 + 2], base[v * 3 + 2]);
  float s2 = __fadd_rn(__fadd_rn(__fmul_rn(dx, dx), __fmul_rn(dy, dy)),
                       __fmul_rn(dz, dz));
  float nrm = fmaxf(__fsqrt_rn(s2), 1e-12f);
  ox = __fdiv_rn(dx, nrm); oy = __fdiv_rn(dy, nrm); oz = __fdiv_rn(dz, nrm);
}

__device__ __forceinline__ void norm_col(const float* d, int k,
                                         float& ox, float& oy, float& oz) {
  float x = d[k], y = d[32 + k], z = d[64 + k];
  float s2 = __fadd_rn(__fadd_rn(__fmul_rn(x, x), __fmul_rn(y, y)),
                       __fmul_rn(z, z));
  float nrm = fmaxf(__fsqrt_rn(s2), 1e-12f);
  ox = __fdiv_rn(x, nrm); oy = __fdiv_rn(y, nrm); oz = __fdiv_rn(z, nrm);
}

__global__ void conv_surface_kernel(const float* __restrict__ pts,
                                    const int* __restrict__ ni,
                                    const float* __restrict__ d0,
                                    float* __restrict__ out, int Nv,
                                    int ldout) {
  __shared__ float sdir[3][32];
  __shared__ float sdn[8][32][3];
  int tid = threadIdx.x;
  if (tid < 32) {
    float x, y, z; norm_col(d0, tid, x, y, z);
    sdir[0][tid] = x; sdir[1][tid] = y; sdir[2][tid] = z;
  }
  int vloc = tid >> 5, k = tid & 31;
  size_t bvg = (size_t)blockIdx.x * 8 + vloc;
  int b = (int)(bvg / Nv), v = (int)(bvg % Nv);
  const float* base = pts + (size_t)b * Nv * 3;
  int nb = ni[bvg * 32 + k];
  float x, y, z; dirn(base, v, nb, x, y, z);
  sdn[vloc][k][0] = x; sdn[vloc][k][1] = y; sdn[vloc][k][2] = z;
  __syncthreads();
  float m = 0.f;
  for (int n = 0; n < 32; ++n) {
    float d = sdn[vloc][n][0] * sdir[0][k] + sdn[vloc][n][1] * sdir[1][k] +
              sdn[vloc][n][2] * sdir[2][k];
    m = fmaxf(m, fmaxf(d, 0.f));
  }
  out[bvg * ldout + k] = m;
}

__global__ void linear64_kernel(const float* __restrict__ fm, int ld, int Cin,
                                const float* __restrict__ w,
                                const float* __restrict__ bias,
                                float* __restrict__ f, int rows) {
  int t = blockIdx.x * blockDim.x + threadIdx.x;
  int o = t & 63, bv = t >> 6;
  if (bv >= rows) return;
  const float* a = fm + (size_t)bv * ld;
  float acc = bias[o];
  for (int c = 0; c < Cin; ++c) acc += a[c] * w[c * 64 + o];
  f[(size_t)bv * 64 + o] = acc;
}

__global__ void conv_act_kernel(const float* __restrict__ pts,
                                const float* __restrict__ dd,
                                const int* __restrict__ ni,
                                const float* __restrict__ f,
                                float* __restrict__ out, int Nv, int ldout,
                                int colofs) {
  __shared__ float sdir[3][32];
  __shared__ float sdn[8][32][3];
  __shared__ int sidx[8][32];
  int tid = threadIdx.x;
  if (tid < 32) {
    float x, y, z; norm_col(dd, tid, x, y, z);
    sdir[0][tid] = x; sdir[1][tid] = y; sdir[2][tid] = z;
  }
  int vloc = tid >> 5, k = tid & 31;
  size_t bvg = (size_t)blockIdx.x * 8 + vloc;
  int b = (int)(bvg / Nv), v = (int)(bvg % Nv);
  const float* base = pts + (size_t)b * Nv * 3;
  int nb = ni[bvg * 32 + k];
  float x, y, z; dirn(base, v, nb, x, y, z);
  sdn[vloc][k][0] = x; sdn[vloc][k][1] = y; sdn[vloc][k][2] = z;
  sidx[vloc][k] = nb;
  __syncthreads();
  float m = -INFINITY;
  size_t fb = (size_t)b * Nv * 64;
  for (int n = 0; n < 32; ++n) {
    float th = fmaxf(sdn[vloc][n][0] * sdir[0][k] + sdn[vloc][n][1] * sdir[1][k] +
                     sdn[vloc][n][2] * sdir[2][k], 0.f);
    float sup = f[fb + (size_t)sidx[vloc][n] * 64 + 32 + k];
    m = fmaxf(m, th * sup);
  }
  float center = f[bvg * 64 + k];
  out[bvg * ldout + colofs + k] = fmaxf(center + m, 0.f);
}

__global__ void pool_kernel(const float* __restrict__ pts_in,
                            const float* __restrict__ fm_in, int ld_in, int C,
                            int Nv_in, const int* __restrict__ perm, int Nv_out,
                            float rr, float* __restrict__ pts_out,
                            float* __restrict__ fm_out, int ld_out) {
  int wid = blockIdx.x * (blockDim.x >> 6) + (threadIdx.x >> 6);
  int lane = threadIdx.x & 63;
  if (wid >= BS * Nv_out) return;
  int b = wid / Nv_out, pp = wid - b * Nv_out;
  int v = perm[pp];
  const float* base = pts_in + (size_t)b * Nv_in * 3;
  float cx = base[v * 3], cy = base[v * 3 + 1], cz = base[v * 3 + 2];
  int nb[4]; int cnt = 0;
  for (int j0 = 0; j0 < Nv_in && cnt < 4; j0 += 64) {
    int j = j0 + lane;
    float d2 = sqdist_f32(cx, cy, cz, base + (size_t)j * 3);
    unsigned long long mask = __ballot(d2 <= rr);
    while (mask && cnt < 4) {
      int bp = __builtin_ctzll(mask);
      mask &= mask - 1;
      nb[cnt++] = j0 + bp;
    }
  }
  for (int q = cnt; q < 4; ++q) nb[q] = nb[0];
  if (lane < 3) pts_out[((size_t)b * Nv_out + pp) * 3 + lane] = base[v * 3 + lane];
  size_t inrow = (size_t)b * Nv_in;
  size_t outrow = ((size_t)b * Nv_out + pp) * ld_out;
  for (int c = lane; c < C; c += 64) {
    float m = fm_in[(inrow + nb[0]) * ld_in + c];
    m = fmaxf(m, fm_in[(inrow + nb[1]) * ld_in + c]);
    m = fmaxf(m, fm_in[(inrow + nb[2]) * ld_in + c]);
    m = fmaxf(m, fm_in[(inrow + nb[3]) * ld_in + c]);
    fm_out[outrow + c] = m;
  }
}

__global__ void gmax_kernel(const float* __restrict__ fm,
                            float* __restrict__ out) {
  int t = blockIdx.x * blockDim.x + threadIdx.x;
  if (t >= BS * 256) return;
  int b = t >> 8, c = t & 255;
  float m = -INFINITY;
  for (int v = 0; v < V2N; ++v)
    m = fmaxf(m, fm[((size_t)b * V2N + v) * 256 + c]);
  out[t] = m;
}

// ---------------------------------------------------------------------------
__device__ __forceinline__ ushort_t f2bf(float f) {
  unsigned u = __float_as_uint(f);
  u += 0x7FFFu + ((u >> 16) & 1u);
  return (ushort_t)(u >> 16);
}

#define KP1 1440
__device__ __forceinline__ float fuse_val(const float* r2, const float* r5,
                                          const float* r7, const float* rg,
                                          const float* roh, int c) {
  if (c < 192) {
    int cc = (c < 32) ? c : (c < 96 ? c - 32 : c - 96);
    return r2[cc];
  } else if (c < 672) {
    int cc = (c < 320) ? c - 192 : (c < 480 ? c - 320 : c - 480);
    return r5[cc];
  } else if (c < 1152) {
    int cc = (c < 896) ? c - 672 : c - 896;
    return r7[cc];
  } else if (c < 1408) {
    return rg[c - 1152];
  } else if (c < 1424) {
    return roh[c - 1408];
  }
  return 0.f;
}

// one block per fused row: inline argmin(n1,n2) + gather + bf16 cast.
__global__ __launch_bounds__(256) void fuse_row_kernel(
    const float* __restrict__ fm2, const float* __restrict__ fm5,
    const float* __restrict__ fm7, const float* __restrict__ fglob,
    const float* __restrict__ onehot, const float* __restrict__ verts,
    const float* __restrict__ v1, const float* __restrict__ v2,
    ushort_t* __restrict__ fuse_b) {
  __shared__ unsigned long long red[256];
  __shared__ int sn1, sn2;
  int bv = blockIdx.x;
  int b = bv >> 11;
  int tid = threadIdx.x;
  float cx = verts[(size_t)bv * 3 + 0];
  float cy = verts[(size_t)bv * 3 + 1];
  float cz = verts[(size_t)bv * 3 + 2];
  unsigned long long best = ~0ull;
  const float* sb = v1 + (size_t)b * V1N * 3;
  for (int j = tid; j < V1N; j += 256) {
    float d2 = sqdist_f32(cx, cy, cz, sb + (size_t)j * 3);
    unsigned long long key =
        (((unsigned long long)__float_as_uint(d2)) << 32) | (unsigned)j;
    best = best < key ? best : key;
  }
  red[tid] = best;
  __syncthreads();
  for (int s = 128; s > 0; s >>= 1) {
    if (tid < s) red[tid] = red[tid] < red[tid + s] ? red[tid] : red[tid + s];
    __syncthreads();
  }
  if (tid == 0) sn1 = (int)(red[0] & 0xffffffffu);
  __syncthreads();
  best = ~0ull;
  sb = v2 + (size_t)b * V2N * 3;
  for (int j = tid; j < V2N; j += 256) {
    float d2 = sqdist_f32(cx, cy, cz, sb + (size_t)j * 3);
    unsigned long long key =
        (((unsigned long long)__float_as_uint(d2)) << 32) | (unsigned)j;
    best = best < key ? best : key;
  }
  red[tid] = best;
  __syncthreads();
  for (int s = 128; s > 0; s >>= 1) {
    if (tid < s) red[tid] = red[tid] < red[tid + s] ? red[tid] : red[tid + s];
    __syncthreads();
  }
  if (tid == 0) sn2 = (int)(red[0] & 0xffffffffu);
  __syncthreads();
  const float* r2 = fm2 + (size_t)bv * 96;
  const float* r5 = fm5 + ((size_t)b * V1N + sn1) * 192;
  const float* r7 = fm7 + ((size_t)b * V2N + sn2) * 256;
  const float* rg = fglob + b * 256;
  const float* roh = onehot + b * 16;
  ushort_t* orow = fuse_b + (size_t)bv * KP1;
  for (int c = tid; c < KP1; c += 256)
    orow[c] = f2bf(fuse_val(r2, r5, r7, rg, roh, c));
}

// single fused weight-prep: cw1(pad K 1424->1440), cw2, cw3(pad rows 50->128), cb3
__global__ void prep_weights_kernel(const float* __restrict__ cw1,
                                    const float* __restrict__ cw2,
                                    const float* __restrict__ cw3,
                                    const float* __restrict__ cb3,
                                    ushort_t* __restrict__ cw1b,
                                    ushort_t* __restrict__ cw2b,
                                    ushort_t* __restrict__ cw3b,
                                    float* __restrict__ cb3p) {
  long long t = (long long)blockIdx.x * 256 + threadIdx.x;
  const long long N1 = 1024LL * KP1, N2 = 512LL * 1024, N3 = 128LL * 512;
  if (t < N1) {
    int k = (int)(t % KP1);
    int n = (int)(t / KP1);
    cw1b[t] = f2bf(k < 1424 ? cw1[(size_t)n * 1424 + k] : 0.f);
  } else if (t < N1 + N2) {
    long long u = t - N1;
    cw2b[u] = f2bf(cw2[u]);
  } else if (t < N1 + N2 + N3) {
    long long u = t - N1 - N2;
    int k = (int)(u & 511);
    int n = (int)(u >> 9);
    cw3b[u] = f2bf(n < 50 ? cw3[(size_t)n * 512 + k] : 0.f);
  } else if (t < N1 + N2 + N3 + 128) {
    int u = (int)(t - N1 - N2 - N3);
    cb3p[u] = u < 50 ? cb3[u] : 0.f;
  }
}

// ---------------------------------------------------------------------------
// bf16 MFMA GEMM (m97 structure) + XCD-colocating swizzle
// ---------------------------------------------------------------------------
typedef const __attribute__((address_space(1))) unsigned int gas_u32;
typedef __attribute__((address_space(3))) unsigned int las_u32;

__global__ __launch_bounds__(256) void gemm_mfma_nt(
    const ushort_t* __restrict__ A, const ushort_t* __restrict__ B,
    const float* __restrict__ bias, ushort_t* __restrict__ Cb,
    float* __restrict__ Cf, int K, int ldc, int nvalid, int mode) {
  __shared__ ushort_t As[128 * 32];
  __shared__ ushort_t Bs[128 * 32];
  int tid = threadIdx.x;
  int lane = tid & 63, w = tid >> 6;
  int wm = (w >> 1) * 64, wn = (w & 1) * 64;
  int nb = gridDim.x;
  int flat = blockIdx.x + nb * blockIdx.y;  // dispatch order (x-fastest)
  int xcd = flat & 7, slot = flat >> 3;
  int nidx = slot % nb;
  int mband = xcd + 8 * (slot / nb);
  int bm = mband * 128, bn = nidx * 128;
  f32x4 acc[4][4];
#pragma unroll
  for (int i = 0; i < 4; ++i)
#pragma unroll
    for (int j = 0; j < 4; ++j) acc[i][j] = (f32x4){0.f, 0.f, 0.f, 0.f};

  int rowA0 = lane >> 2;
  int colA0 = (lane & 3) * 8;
  int seg0 = w * 2;
  const ushort_t* ga0 = A + (size_t)(bm + seg0 * 16 + rowA0) * K + colA0;
  const ushort_t* ga1 = A + (size_t)(bm + (seg0 + 1) * 16 + rowA0) * K + colA0;
  const ushort_t* gb0 = B + (size_t)(bn + seg0 * 16 + rowA0) * K + colA0;
  const ushort_t* gb1 = B + (size_t)(bn + (seg0 + 1) * 16 + rowA0) * K + colA0;
  ushort_t* la0 = As + seg0 * 512;
  ushort_t* la1 = As + (seg0 + 1) * 512;
  ushort_t* lb0 = Bs + seg0 * 512;
  ushort_t* lb1 = Bs + (seg0 + 1) * 512;

  int kq = (lane >> 4) * 8;
  int rA = lane & 15;

  for (int k0 = 0; k0 < K; k0 += 32) {
    __builtin_amdgcn_global_load_lds((gas_u32*)(ga0 + k0), (las_u32*)la0, 16, 0, 0);
    __builtin_amdgcn_global_load_lds((gas_u32*)(ga1 + k0), (las_u32*)la1, 16, 0, 0);
    __builtin_amdgcn_global_load_lds((gas_u32*)(gb0 + k0), (las_u32*)lb0, 16, 0, 0);
    __builtin_amdgcn_global_load_lds((gas_u32*)(gb1 + k0), (las_u32*)lb1, 16, 0, 0);
    __syncthreads();
    bf16x8 af[4], bfr[4];
#pragma unroll
    for (int i = 0; i < 4; ++i)
      af[i] = *(const bf16x8*)(As + (wm + i * 16 + rA) * 32 + kq);
#pragma unroll
    for (int j = 0; j < 4; ++j)
      bfr[j] = *(const bf16x8*)(Bs + (wn + j * 16 + rA) * 32 + kq);
#pragma unroll
    for (int i = 0; i < 4; ++i)
#pragma unroll
      for (int j = 0; j < 4; ++j)
        acc[i][j] = __builtin_amdgcn_mfma_f32_16x16x32_bf16(af[i], bfr[j],
                                                            acc[i][j], 0, 0, 0);
    __syncthreads();
  }

  int rowq = (lane >> 4) * 4;
  int coll = lane & 15;
#pragma unroll
  for (int i = 0; i < 4; ++i) {
#pragma unroll
    for (int j = 0; j < 4; ++j) {
      int col = bn + wn + j * 16 + coll;
      float bi = bias[col];
#pragma unroll
      for (int r = 0; r < 4; ++r) {
        int row = bm + wm + i * 16 + rowq + r;
        float v = acc[i][j][r] + bi;
        if (mode == 0) {
          Cb[(size_t)row * ldc + col] = f2bf(fmaxf(v, 0.f));
        } else if (col < nvalid) {
          Cf[(size_t)row * ldc + col] = v;
        }
      }
    }
  }
}

// ---------------------------------------------------------------------------
extern "C" void kernel_launch(void* const* d_in, const int* in_sizes, int n_in,
                              void* d_out, int out_size, void* d_ws,
                              size_t ws_size, hipStream_t stream) {
  const float* vertices = (const float*)d_in[0];
  const float* onehot = (const float*)d_in[1];
  const float* d0 = (const float*)d_in[2];
  const float *w[8], *bb[8], *dd[8];
  for (int i = 1; i <= 7; ++i) {
    w[i] = (const float*)d_in[3 * i];
    bb[i] = (const float*)d_in[3 * i + 1];
    dd[i] = (const float*)d_in[3 * i + 2];
  }
  const float* cw1 = (const float*)d_in[24];
  const float* cb1 = (const float*)d_in[25];
  const float* cw2 = (const float*)d_in[26];
  const float* cb2 = (const float*)d_in[27];
  const float* cw3 = (const float*)d_in[28];
  const float* cb3 = (const float*)d_in[29];
  float* out = (float*)d_out;

  char* wsp = (char*)d_ws;
  size_t off = 0;
  auto alloc = [&](size_t bytes) -> void* {
    void* p = wsp + off;
    off += (bytes + 255) & ~(size_t)255;
    return p;
  };
  const int M = BS * V0;  // 16384
  unsigned* bits = (unsigned*)alloc(4608 * 4);
  int* rank = (int*)alloc(4608 * 4);
  int* perm1 = (int*)alloc(512 * 4);
  int* perm2 = (int*)alloc(128 * 4);
  int* ni1 = (int*)alloc((size_t)BS * V0 * 32 * 4);
  int* ni2 = (int*)alloc((size_t)BS * V1N * 32 * 4);
  int* ni3 = (int*)alloc((size_t)BS * V2N * 32 * 4);
  float* fm2buf = (float*)alloc((size_t)BS * V0 * 96 * 4);
  float* fm5buf = (float*)alloc((size_t)BS * V1N * 192 * 4);
  float* fm7buf = (float*)alloc((size_t)BS * V2N * 256 * 4);
  float* fbuf = (float*)alloc((size_t)BS * V0 * 64 * 4);
  float* v1 = (float*)alloc((size_t)BS * V1N * 3 * 4);
  float* v2 = (float*)alloc((size_t)BS * V2N * 3 * 4);
  float* fglob = (float*)alloc((size_t)BS * 256 * 4);
  ushort_t* fuse_b = (ushort_t*)alloc((size_t)M * KP1 * 2);
  ushort_t* h1b = (ushort_t*)alloc((size_t)M * 1024 * 2);
  ushort_t* h2b = (ushort_t*)alloc((size_t)M * 512 * 2);
  ushort_t* cw1b = (ushort_t*)alloc((size_t)1024 * KP1 * 2);
  ushort_t* cw2b = (ushort_t*)alloc((size_t)512 * 1024 * 2);
  ushort_t* cw3b = (ushort_t*)alloc((size_t)128 * 512 * 2);
  float* cb3p = (float*)alloc(128 * 4);

  // permutation (rank-sort, LDS-staged)
  perm_bits_kernel<<<10, 256, 0, stream>>>(bits);
  perm_rank_kernel<<<18, 256, 0, stream>>>(bits, rank);
  perm_compose_kernel<<<1, 1024, 0, stream>>>(rank, perm1, perm2);

  // fused weight prep
  {
    long long tot = 1024LL * KP1 + 512LL * 1024 + 128LL * 512 + 128;
    prep_weights_kernel<<<(int)((tot + 255) / 256), 256, 0, stream>>>(
        cw1, cw2, cw3, cb3, cw1b, cw2b, cw3b, cb3p);
  }

  float rr1 = 0.0625f;
  float rr2 = (float)(0.39 * 0.39);
  float rr3 = (float)(0.63 * 0.63);

  // level 1 (V=2048)
  qbp_kernel<<<BS * V0 / 4, 256, 0, stream>>>(vertices, V0, 32, rr1, ni1);
  conv_surface_kernel<<<BS * V0 / 8, 256, 0, stream>>>(vertices, ni1, d0, fm2buf, V0, 96);
  linear64_kernel<<<BS * V0 * 64 / 256, 256, 0, stream>>>(fm2buf, 96, 32, w[1], bb[1], fbuf, BS * V0);
  conv_act_kernel<<<BS * V0 / 8, 256, 0, stream>>>(vertices, dd[1], ni1, fbuf, fm2buf, V0, 96, 32);
  linear64_kernel<<<BS * V0 * 64 / 256, 256, 0, stream>>>(fm2buf, 96, 64, w[2], bb[2], fbuf, BS * V0);
  conv_act_kernel<<<BS * V0 / 8, 256, 0, stream>>>(vertices, dd[2], ni1, fbuf, fm2buf, V0, 96, 64);
  pool_kernel<<<BS * V1N / 4, 256, 0, stream>>>(vertices, fm2buf, 96, 96, V0, perm1, V1N, rr1, v1, fm5buf, 192);

  // level 2 (V=512)
  qbp_kernel<<<BS * V1N / 4, 256, 0, stream>>>(v1, V1N, 32, rr2, ni2);
  linear64_kernel<<<BS * V1N * 64 / 256, 256, 0, stream>>>(fm5buf, 192, 96, w[3], bb[3], fbuf, BS * V1N);
  conv_act_kernel<<<BS * V1N / 8, 256, 0, stream>>>(v1, dd[3], ni2, fbuf, fm5buf, V1N, 192, 96);
  linear64_kernel<<<BS * V1N * 64 / 256, 256, 0, stream>>>(fm5buf, 192, 128, w[4], bb[4], fbuf, BS * V1N);
  conv_act_kernel<<<BS * V1N / 8, 256, 0, stream>>>(v1, dd[4], ni2, fbuf, fm5buf, V1N, 192, 128);
  linear64_kernel<<<BS * V1N * 64 / 256, 256, 0, stream>>>(fm5buf, 192, 160, w[5], bb[5], fbuf, BS * V1N);
  conv_act_kernel<<<BS * V1N / 8, 256, 0, stream>>>(v1, dd[5], ni2, fbuf, fm5buf, V1N, 192, 160);
  pool_kernel<<<BS * V2N / 4, 256, 0, stream>>>(v1, fm5buf, 192, 192, V1N, perm2, V2N, rr2, v2, fm7buf, 256);

  // level 3 (V=128)
  qbp_kernel<<<BS * V2N / 4, 256, 0, stream>>>(v2, V2N, 32, rr3, ni3);
  linear64_kernel<<<BS * V2N * 64 / 256, 256, 0, stream>>>(fm7buf, 256, 192, w[6], bb[6], fbuf, BS * V2N);
  conv_act_kernel<<<BS * V2N / 8, 256, 0, stream>>>(v2, dd[6], ni3, fbuf, fm7buf, V2N, 256, 192);
  linear64_kernel<<<BS * V2N * 64 / 256, 256, 0, stream>>>(fm7buf, 256, 224, w[7], bb[7], fbuf, BS * V2N);
  conv_act_kernel<<<BS * V2N / 8, 256, 0, stream>>>(v2, dd[7], ni3, fbuf, fm7buf, V2N, 256, 224);

  gmax_kernel<<<BS, 256, 0, stream>>>(fm7buf, fglob);

  // fused: nearest(n1,n2) + gather + bf16 cast, one block per row
  fuse_row_kernel<<<M, 256, 0, stream>>>(fm2buf, fm5buf, fm7buf, fglob, onehot,
                                         vertices, v1, v2, fuse_b);

  // MLP head: bf16 MFMA
  gemm_mfma_nt<<<dim3(1024 / 128, M / 128), 256, 0, stream>>>(
      fuse_b, cw1b, cb1, h1b, nullptr, KP1, 1024, 1024, 0);
  gemm_mfma_nt<<<dim3(512 / 128, M / 128), 256, 0, stream>>>(
      h1b, cw2b, cb2, h2b, nullptr, 1024, 512, 512, 0);
  gemm_mfma_nt<<<dim3(1, M / 128), 256, 0, stream>>>(
      h2b, cw3b, cb3p, nullptr, out, 512, 50, 50, 1);
}

// Round 8
// 476.559 us; speedup vs baseline: 6.1131x; 1.6414x over previous
//
#include <hip/hip_runtime.h>
#include <hip/hip_bf16.h>

#define BS 8
#define V0 2048
#define V1N 512
#define V2N 128

typedef unsigned short ushort_t;
typedef __attribute__((ext_vector_type(8))) short bf16x8;
typedef __attribute__((ext_vector_type(4))) float f32x4;

// ---------------------------------------------------------------------------
// Threefry2x32 cipher (JAX partitionable mode — verified R4)
// ---------------------------------------------------------------------------
__device__ __forceinline__ void tf2x32(unsigned k0, unsigned k1,
                                       unsigned x0, unsigned x1,
                                       unsigned &o0, unsigned &o1) {
  unsigned ks2 = k0 ^ k1 ^ 0x1BD11BDAu;
  x0 += k0; x1 += k1;
#define RR(r) { x0 += x1; x1 = (x1 << (r)) | (x1 >> (32 - (r))); x1 ^= x0; }
  RR(13) RR(15) RR(26) RR(6)   x0 += k1;  x1 += ks2 + 1u;
  RR(17) RR(29) RR(16) RR(24)  x0 += ks2; x1 += k0 + 2u;
  RR(13) RR(15) RR(26) RR(6)   x0 += k0;  x1 += k1 + 3u;
  RR(17) RR(29) RR(16) RR(24)  x0 += k1;  x1 += ks2 + 4u;
  RR(13) RR(15) RR(26) RR(6)   x0 += ks2; x1 += k0 + 5u;
#undef RR
  o0 = x0; o1 = x1;
}

__device__ __forceinline__ ushort_t f2bf(float f) {
  unsigned u = __float_as_uint(f);
  u += 0x7FFFu + ((u >> 16) & 1u);
  return (ushort_t)(u >> 16);
}

__device__ __forceinline__ float sqdist_f32(float cx, float cy, float cz,
                                            const float* p) {
  float dx = __fsub_rn(cx, p[0]);
  float dy = __fsub_rn(cy, p[1]);
  float dz = __fsub_rn(cz, p[2]);
  return __fadd_rn(__fadd_rn(__fmul_rn(dx, dx), __fmul_rn(dy, dy)),
                   __fmul_rn(dz, dz));
}

#define KP1 1440

// ---------------------------------------------------------------------------
// misc1: block-range dispatch of three independent root tasks:
//  [0,18)            threefry rank (bits recomputed in LDS per block)
//  [18,18+8065)      weight prep (cast/pad cw1/cw2/cw3/cb3)
//  [18+8065, +4096)  qbp level-1
// ---------------------------------------------------------------------------
#define PREP_BLKS 8065
__global__ __launch_bounds__(256) void misc1_kernel(
    int* __restrict__ rank, const float* __restrict__ cw1,
    const float* __restrict__ cw2, const float* __restrict__ cw3,
    const float* __restrict__ cb3, ushort_t* __restrict__ cw1b,
    ushort_t* __restrict__ cw2b, ushort_t* __restrict__ cw3b,
    float* __restrict__ cb3p, const float* __restrict__ pts,
    int* __restrict__ ni1) {
  int bid = blockIdx.x, tid = threadIdx.x;
  if (bid < 18) {
    __shared__ unsigned sb[2048];
    int seg, segfirst, n, base;
    if (bid < 8)       { seg = 0; segfirst = 0;  n = 2048; base = 0; }
    else if (bid < 16) { seg = 1; segfirst = 8;  n = 2048; base = 2048; }
    else               { seg = 2; segfirst = 16; n = 512;  base = 4096; }
    unsigned k0, k1, nk0, nk1, sk0, sk1;
    if (seg == 0) {        // round1 of fold_in(42,1)
      tf2x32(0u, 42u, 0u, 1u, k0, k1);
      tf2x32(k0, k1, 0u, 1u, sk0, sk1);
    } else if (seg == 1) { // round2: newkey = cipher(key1,(0,0))
      tf2x32(0u, 42u, 0u, 1u, k0, k1);
      tf2x32(k0, k1, 0u, 0u, nk0, nk1);
      tf2x32(nk0, nk1, 0u, 1u, sk0, sk1);
    } else {               // round1 of fold_in(42,2)
      tf2x32(0u, 42u, 0u, 2u, k0, k1);
      tf2x32(k0, k1, 0u, 1u, sk0, sk1);
    }
    for (int i = tid; i < n; i += 256) {
      unsigned o0, o1;
      tf2x32(sk0, sk1, 0u, (unsigned)i, o0, o1);
      sb[i] = o0 ^ o1;
    }
    __syncthreads();
    int tt = (bid - segfirst) * 256 + tid;
    unsigned bt = sb[tt];
    int cnt = 0;
#pragma unroll 8
    for (int s = 0; s < n; ++s) {
      unsigned bs = sb[s];
      cnt += (bs < bt) || (bs == bt && s < tt);
    }
    rank[base + tt] = cnt;
  } else if (bid < 18 + PREP_BLKS) {
    long long t = (long long)(bid - 18) * 256 + tid;
    const long long N1 = 1024LL * KP1, N2 = 512LL * 1024, N3 = 128LL * 512;
    if (t < N1) {
      int k = (int)(t % KP1);
      int n = (int)(t / KP1);
      cw1b[t] = f2bf(k < 1424 ? cw1[(size_t)n * 1424 + k] : 0.f);
    } else if (t < N1 + N2) {
      long long u = t - N1;
      cw2b[u] = f2bf(cw2[u]);
    } else if (t < N1 + N2 + N3) {
      long long u = t - N1 - N2;
      int k = (int)(u & 511);
      int n = (int)(u >> 9);
      cw3b[u] = f2bf(n < 50 ? cw3[(size_t)n * 512 + k] : 0.f);
    } else if (t < N1 + N2 + N3 + 128) {
      int u = (int)(t - N1 - N2 - N3);
      cb3p[u] = u < 50 ? cb3[u] : 0.f;
    }
  } else {
    // qbp level-1 (V0, rr=0.0625, nsample=32)
    int bq = bid - 18 - PREP_BLKS;
    int wid = bq * 4 + (tid >> 6);
    int lane = tid & 63;
    int b = wid >> 11, i = wid & 2047;
    const float* base = pts + (size_t)b * V0 * 3;
    float cx = base[i * 3], cy = base[i * 3 + 1], cz = base[i * 3 + 2];
    int cnt = 0, idx0 = 0;
    for (int j0 = 0; j0 < V0; j0 += 64) {
      int j = j0 + lane;
      float d2 = sqdist_f32(cx, cy, cz, base + (size_t)j * 3);
      bool in = (d2 <= 0.0625f);
      unsigned long long mask = __ballot(in);
      if (cnt == 0 && mask) idx0 = j0 + __builtin_ctzll(mask);
      if (in) {
        int rk = cnt + __popcll(mask & ((1ull << lane) - 1ull));
        if (rk < 32) ni1[(size_t)wid * 32 + rk] = j;
      }
      cnt += __popcll(mask);
      if (cnt >= 32) break;
    }
    for (int s = cnt + lane; s < 32; s += 64) ni1[(size_t)wid * 32 + s] = idx0;
  }
}

// ---------------------------------------------------------------------------
// misc2: block 0 = perm compose; blocks [1,2049) = conv_surface (+linear1)
// ---------------------------------------------------------------------------
__device__ __forceinline__ void dirn(const float* base, int v, int nb,
                                     float& ox, float& oy, float& oz) {
  float dx = __fsub_rn(base[nb * 3 + 0], base[v * 3 + 0]);
  float dy = __fsub_rn(base[nb * 3 + 1], base[v * 3 + 1]);
  float dz = __fsub_rn(base[nb * 3 + 2], base[v * 3 + 2]);
  float s2 = __fadd_rn(__fadd_rn(__fmul_rn(dx, dx), __fmul_rn(dy, dy)),
                       __fmul_rn(dz, dz));
  float nrm = fmaxf(__fsqrt_rn(s2), 1e-12f);
  ox = __fdiv_rn(dx, nrm); oy = __fdiv_rn(dy, nrm); oz = __fdiv_rn(dz, nrm);
}

__device__ __forceinline__ void norm_col(const float* d, int k,
                                         float& ox, float& oy, float& oz) {
  float x = d[k], y = d[32 + k], z = d[64 + k];
  float s2 = __fadd_rn(__fadd_rn(__fmul_rn(x, x), __fmul_rn(y, y)),
                       __fmul_rn(z, z));
  float nrm = fmaxf(__fsqrt_rn(s2), 1e-12f);
  ox = __fdiv_rn(x, nrm); oy = __fdiv_rn(y, nrm); oz = __fdiv_rn(z, nrm);
}

__global__ __launch_bounds__(256) void misc2_kernel(
    const int* __restrict__ rank, int* __restrict__ perm1,
    int* __restrict__ perm2, const float* __restrict__ pts,
    const int* __restrict__ ni, const float* __restrict__ d0,
    const float* __restrict__ w1, const float* __restrict__ b1,
    float* __restrict__ out, float* __restrict__ fn) {
  int bid = blockIdx.x, tid = threadIdx.x;
  if (bid == 0) {
    __shared__ int a1[2048];
    __shared__ int a2[2048];
    for (int i = tid; i < 2048; i += 256) a1[rank[i]] = i;
    __syncthreads();
    for (int i = tid; i < 2048; i += 256) a2[rank[2048 + i]] = a1[i];
    __syncthreads();
    for (int i = tid; i < 512; i += 256) perm1[i] = a2[i];
    for (int i = tid; i < 512; i += 256) a1[rank[4096 + i]] = i;
    __syncthreads();
    for (int i = tid; i < 128; i += 256) perm2[i] = a1[i];
    return;
  }
  __shared__ float sdir[3][32];
  __shared__ float sdn[8][32][3];
  __shared__ float sfm[8][32];
  if (tid < 32) {
    float x, y, z; norm_col(d0, tid, x, y, z);
    sdir[0][tid] = x; sdir[1][tid] = y; sdir[2][tid] = z;
  }
  int vloc = tid >> 5, k = tid & 31;
  size_t bvg = (size_t)(bid - 1) * 8 + vloc;
  int b = (int)(bvg >> 11), v = (int)(bvg & 2047);
  const float* base = pts + (size_t)b * V0 * 3;
  int nb = ni[bvg * 32 + k];
  float x, y, z; dirn(base, v, nb, x, y, z);
  sdn[vloc][k][0] = x; sdn[vloc][k][1] = y; sdn[vloc][k][2] = z;
  __syncthreads();
  float m = 0.f;
  for (int n = 0; n < 32; ++n) {
    float d = sdn[vloc][n][0] * sdir[0][k] + sdn[vloc][n][1] * sdir[1][k] +
              sdn[vloc][n][2] * sdir[2][k];
    m = fmaxf(m, fmaxf(d, 0.f));
  }
  out[bvg * 96 + k] = m;
  sfm[vloc][k] = m;
  __syncthreads();
  // fused linear1: f1 = fm0(32) @ w1 + b1
  float a1v = b1[k], a2v = b1[k + 32];
  for (int c = 0; c < 32; ++c) {
    float vv = sfm[vloc][c];
    a1v += vv * w1[c * 64 + k];
    a2v += vv * w1[c * 64 + k + 32];
  }
  fn[bvg * 64 + k] = a1v;
  fn[bvg * 64 + k + 32] = a2v;
}

// ---------------------------------------------------------------------------
// qbp (levels 2/3)
// ---------------------------------------------------------------------------
__global__ void qbp_kernel(const float* __restrict__ pts, int Nv, int nsample,
                           float rr, int* __restrict__ out) {
  int wid = blockIdx.x * (blockDim.x >> 6) + (threadIdx.x >> 6);
  int lane = threadIdx.x & 63;
  if (wid >= BS * Nv) return;
  int b = wid / Nv, i = wid - b * Nv;
  const float* base = pts + (size_t)b * Nv * 3;
  float cx = base[i * 3], cy = base[i * 3 + 1], cz = base[i * 3 + 2];
  int cnt = 0, idx0 = 0;
  for (int j0 = 0; j0 < Nv; j0 += 64) {
    int j = j0 + lane;
    float d2 = sqdist_f32(cx, cy, cz, base + (size_t)j * 3);
    bool in = (d2 <= rr);
    unsigned long long mask = __ballot(in);
    if (cnt == 0 && mask) idx0 = j0 + __builtin_ctzll(mask);
    if (in) {
      int rk = cnt + __popcll(mask & ((1ull << lane) - 1ull));
      if (rk < nsample) out[(size_t)wid * nsample + rk] = j;
    }
    cnt += __popcll(mask);
    if (cnt >= nsample) break;
  }
  for (int s = cnt + lane; s < nsample; s += 64)
    out[(size_t)wid * nsample + s] = idx0;
}

// ---------------------------------------------------------------------------
// conv_act (+ optional fused next-linear): wn==nullptr → no epilogue
// ---------------------------------------------------------------------------
__global__ __launch_bounds__(256) void conv_act_kernel(
    const float* __restrict__ pts, const float* __restrict__ dd,
    const int* __restrict__ ni, const float* __restrict__ f,
    float* __restrict__ out, int Nv, int ldout, int colofs,
    const float* __restrict__ wn, const float* __restrict__ bn,
    float* __restrict__ fn) {
  __shared__ float sdir[3][32];
  __shared__ float sdn[8][32][3];
  __shared__ int sidx[8][32];
  __shared__ float sfm[8][256];
  int tid = threadIdx.x;
  if (tid < 32) {
    float x, y, z; norm_col(dd, tid, x, y, z);
    sdir[0][tid] = x; sdir[1][tid] = y; sdir[2][tid] = z;
  }
  int vloc = tid >> 5, k = tid & 31;
  size_t bvg = (size_t)blockIdx.x * 8 + vloc;
  int b = (int)(bvg / Nv), v = (int)(bvg % Nv);
  const float* base = pts + (size_t)b * Nv * 3;
  int nb = ni[bvg * 32 + k];
  float x, y, z; dirn(base, v, nb, x, y, z);
  sdn[vloc][k][0] = x; sdn[vloc][k][1] = y; sdn[vloc][k][2] = z;
  sidx[vloc][k] = nb;
  __syncthreads();
  float m = -INFINITY;
  size_t fb = (size_t)b * Nv * 64;
  for (int n = 0; n < 32; ++n) {
    float th = fmaxf(sdn[vloc][n][0] * sdir[0][k] + sdn[vloc][n][1] * sdir[1][k] +
                     sdn[vloc][n][2] * sdir[2][k], 0.f);
    float sup = f[fb + (size_t)sidx[vloc][n] * 64 + 32 + k];
    m = fmaxf(m, th * sup);
  }
  float center = f[bvg * 64 + k];
  float res = fmaxf(center + m, 0.f);
  out[bvg * ldout + colofs + k] = res;
  if (wn) {
    // stage full row [0, colofs+32): old channels from global, new from res
    size_t rowbase = (size_t)blockIdx.x * 8;
#pragma unroll 1
    for (int r = 0; r < 8; ++r)
      if (tid < colofs) sfm[r][tid] = out[(rowbase + r) * ldout + tid];
    sfm[vloc][colofs + k] = res;
    __syncthreads();
    int cin = colofs + 32;
    float a1v = bn[k], a2v = bn[k + 32];
    for (int c = 0; c < cin; ++c) {
      float vv = sfm[vloc][c];
      a1v += vv * wn[c * 64 + k];
      a2v += vv * wn[c * 64 + k + 32];
    }
    fn[bvg * 64 + k] = a1v;
    fn[bvg * 64 + k + 32] = a2v;
  }
}

// ---------------------------------------------------------------------------
// pool (+ fused next-linear, always present): 4 output vertices per block
// ---------------------------------------------------------------------------
__global__ __launch_bounds__(256) void pool_kernel(
    const float* __restrict__ pts_in, const float* __restrict__ fm_in,
    int ld_in, int C, int Nv_in, const int* __restrict__ perm, int Nv_out,
    float rr, float* __restrict__ pts_out, float* __restrict__ fm_out,
    int ld_out, const float* __restrict__ wn, const float* __restrict__ bn,
    float* __restrict__ fn) {
  __shared__ float spf[4][192];
  int wv = threadIdx.x >> 6;
  int lane = threadIdx.x & 63;
  int wid = blockIdx.x * 4 + wv;
  int b = wid / Nv_out, pp = wid - b * Nv_out;
  int v = perm[pp];
  const float* base = pts_in + (size_t)b * Nv_in * 3;
  float cx = base[v * 3], cy = base[v * 3 + 1], cz = base[v * 3 + 2];
  int nb[4]; int cnt = 0;
  for (int j0 = 0; j0 < Nv_in && cnt < 4; j0 += 64) {
    int j = j0 + lane;
    float d2 = sqdist_f32(cx, cy, cz, base + (size_t)j * 3);
    unsigned long long mask = __ballot(d2 <= rr);
    while (mask && cnt < 4) {
      int bp = __builtin_ctzll(mask);
      mask &= mask - 1;
      nb[cnt++] = j0 + bp;
    }
  }
  for (int q = cnt; q < 4; ++q) nb[q] = nb[0];
  if (lane < 3) pts_out[(size_t)wid * 3 + lane] = base[v * 3 + lane];
  size_t inrow = (size_t)b * Nv_in;
  size_t outrow = (size_t)wid * ld_out;
  for (int c = lane; c < C; c += 64) {
    float m = fm_in[(inrow + nb[0]) * ld_in + c];
    m = fmaxf(m, fm_in[(inrow + nb[1]) * ld_in + c]);
    m = fmaxf(m, fm_in[(inrow + nb[2]) * ld_in + c]);
    m = fmaxf(m, fm_in[(inrow + nb[3]) * ld_in + c]);
    fm_out[outrow + c] = m;
    spf[wv][c] = m;
  }
  __syncthreads();
  // fused linear: f = pooled_row(C) @ wn + bn
  int o = threadIdx.x & 63, w_ = threadIdx.x >> 6;
  int wid0 = blockIdx.x * 4 + w_;
  float a = bn[o];
  for (int c = 0; c < C; ++c) a += spf[w_][c] * wn[c * 64 + o];
  fn[(size_t)wid0 * 64 + o] = a;
}

// ---------------------------------------------------------------------------
__global__ void gmax_kernel(const float* __restrict__ fm,
                            float* __restrict__ out) {
  int t = blockIdx.x * blockDim.x + threadIdx.x;
  if (t >= BS * 256) return;
  int b = t >> 8, c = t & 255;
  float m = -INFINITY;
  for (int v = 0; v < V2N; ++v)
    m = fmaxf(m, fm[((size_t)b * V2N + v) * 256 + c]);
  out[t] = m;
}

// ---------------------------------------------------------------------------
__device__ __forceinline__ float fuse_val(const float* r2, const float* r5,
                                          const float* r7, const float* rg,
                                          const float* roh, int c) {
  if (c < 192) {
    int cc = (c < 32) ? c : (c < 96 ? c - 32 : c - 96);
    return r2[cc];
  } else if (c < 672) {
    int cc = (c < 320) ? c - 192 : (c < 480 ? c - 320 : c - 480);
    return r5[cc];
  } else if (c < 1152) {
    int cc = (c < 896) ? c - 672 : c - 896;
    return r7[cc];
  } else if (c < 1408) {
    return rg[c - 1152];
  } else if (c < 1424) {
    return roh[c - 1408];
  }
  return 0.f;
}

__global__ __launch_bounds__(256) void fuse_row_kernel(
    const float* __restrict__ fm2, const float* __restrict__ fm5,
    const float* __restrict__ fm7, const float* __restrict__ fglob,
    const float* __restrict__ onehot, const float* __restrict__ verts,
    const float* __restrict__ v1, const float* __restrict__ v2,
    ushort_t* __restrict__ fuse_b) {
  __shared__ unsigned long long red[256];
  __shared__ int sn1, sn2;
  int bv = blockIdx.x;
  int b = bv >> 11;
  int tid = threadIdx.x;
  float cx = verts[(size_t)bv * 3 + 0];
  float cy = verts[(size_t)bv * 3 + 1];
  float cz = verts[(size_t)bv * 3 + 2];
  unsigned long long best = ~0ull;
  const float* sb = v1 + (size_t)b * V1N * 3;
  for (int j = tid; j < V1N; j += 256) {
    float d2 = sqdist_f32(cx, cy, cz, sb + (size_t)j * 3);
    unsigned long long key =
        (((unsigned long long)__float_as_uint(d2)) << 32) | (unsigned)j;
    best = best < key ? best : key;
  }
  red[tid] = best;
  __syncthreads();
  for (int s = 128; s > 0; s >>= 1) {
    if (tid < s) red[tid] = red[tid] < red[tid + s] ? red[tid] : red[tid + s];
    __syncthreads();
  }
  if (tid == 0) sn1 = (int)(red[0] & 0xffffffffu);
  __syncthreads();
  best = ~0ull;
  sb = v2 + (size_t)b * V2N * 3;
  for (int j = tid; j < V2N; j += 256) {
    float d2 = sqdist_f32(cx, cy, cz, sb + (size_t)j * 3);
    unsigned long long key =
        (((unsigned long long)__float_as_uint(d2)) << 32) | (unsigned)j;
    best = best < key ? best : key;
  }
  red[tid] = best;
  __syncthreads();
  for (int s = 128; s > 0; s >>= 1) {
    if (tid < s) red[tid] = red[tid] < red[tid + s] ? red[tid] : red[tid + s];
    __syncthreads();
  }
  if (tid == 0) sn2 = (int)(red[0] & 0xffffffffu);
  __syncthreads();
  const float* r2 = fm2 + (size_t)bv * 96;
  const float* r5 = fm5 + ((size_t)b * V1N + sn1) * 192;
  const float* r7 = fm7 + ((size_t)b * V2N + sn2) * 256;
  const float* rg = fglob + b * 256;
  const float* roh = onehot + b * 16;
  ushort_t* orow = fuse_b + (size_t)bv * KP1;
  for (int c = tid; c < KP1; c += 256)
    orow[c] = f2bf(fuse_val(r2, r5, r7, rg, roh, c));
}

// ---------------------------------------------------------------------------
// bf16 MFMA GEMM (m97 structure) + XCD-colocating swizzle (R7: FETCH 192→47MB)
// ---------------------------------------------------------------------------
typedef const __attribute__((address_space(1))) unsigned int gas_u32;
typedef __attribute__((address_space(3))) unsigned int las_u32;

__global__ __launch_bounds__(256) void gemm_mfma_nt(
    const ushort_t* __restrict__ A, const ushort_t* __restrict__ B,
    const float* __restrict__ bias, ushort_t* __restrict__ Cb,
    float* __restrict__ Cf, int K, int ldc, int nvalid, int mode) {
  __shared__ ushort_t As[128 * 32];
  __shared__ ushort_t Bs[128 * 32];
  int tid = threadIdx.x;
  int lane = tid & 63, w = tid >> 6;
  int wm = (w >> 1) * 64, wn = (w & 1) * 64;
  int nb = gridDim.x;
  int flat = blockIdx.x + nb * blockIdx.y;
  int xcd = flat & 7, slot = flat >> 3;
  int nidx = slot % nb;
  int mband = xcd + 8 * (slot / nb);
  int bm = mband * 128, bn = nidx * 128;
  f32x4 acc[4][4];
#pragma unroll
  for (int i = 0; i < 4; ++i)
#pragma unroll
    for (int j = 0; j < 4; ++j) acc[i][j] = (f32x4){0.f, 0.f, 0.f, 0.f};

  int rowA0 = lane >> 2;
  int colA0 = (lane & 3) * 8;
  int seg0 = w * 2;
  const ushort_t* ga0 = A + (size_t)(bm + seg0 * 16 + rowA0) * K + colA0;
  const ushort_t* ga1 = A + (size_t)(bm + (seg0 + 1) * 16 + rowA0) * K + colA0;
  const ushort_t* gb0 = B + (size_t)(bn + seg0 * 16 + rowA0) * K + colA0;
  const ushort_t* gb1 = B + (size_t)(bn + (seg0 + 1) * 16 + rowA0) * K + colA0;
  ushort_t* la0 = As + seg0 * 512;
  ushort_t* la1 = As + (seg0 + 1) * 512;
  ushort_t* lb0 = Bs + seg0 * 512;
  ushort_t* lb1 = Bs + (seg0 + 1) * 512;

  int kq = (lane >> 4) * 8;
  int rA = lane & 15;

  for (int k0 = 0; k0 < K; k0 += 32) {
    __builtin_amdgcn_global_load_lds((gas_u32*)(ga0 + k0), (las_u32*)la0, 16, 0, 0);
    __builtin_amdgcn_global_load_lds((gas_u32*)(ga1 + k0), (las_u32*)la1, 16, 0, 0);
    __builtin_amdgcn_global_load_lds((gas_u32*)(gb0 + k0), (las_u32*)lb0, 16, 0, 0);
    __builtin_amdgcn_global_load_lds((gas_u32*)(gb1 + k0), (las_u32*)lb1, 16, 0, 0);
    __syncthreads();
    bf16x8 af[4], bfr[4];
#pragma unroll
    for (int i = 0; i < 4; ++i)
      af[i] = *(const bf16x8*)(As + (wm + i * 16 + rA) * 32 + kq);
#pragma unroll
    for (int j = 0; j < 4; ++j)
      bfr[j] = *(const bf16x8*)(Bs + (wn + j * 16 + rA) * 32 + kq);
#pragma unroll
    for (int i = 0; i < 4; ++i)
#pragma unroll
      for (int j = 0; j < 4; ++j)
        acc[i][j] = __builtin_amdgcn_mfma_f32_16x16x32_bf16(af[i], bfr[j],
                                                            acc[i][j], 0, 0, 0);
    __syncthreads();
  }

  int rowq = (lane >> 4) * 4;
  int coll = lane & 15;
#pragma unroll
  for (int i = 0; i < 4; ++i) {
#pragma unroll
    for (int j = 0; j < 4; ++j) {
      int col = bn + wn + j * 16 + coll;
      float bi = bias[col];
#pragma unroll
      for (int r = 0; r < 4; ++r) {
        int row = bm + wm + i * 16 + rowq + r;
        float v = acc[i][j][r] + bi;
        if (mode == 0) {
          Cb[(size_t)row * ldc + col] = f2bf(fmaxf(v, 0.f));
        } else if (col < nvalid) {
          Cf[(size_t)row * ldc + col] = v;
        }
      }
    }
  }
}

// ---------------------------------------------------------------------------
extern "C" void kernel_launch(void* const* d_in, const int* in_sizes, int n_in,
                              void* d_out, int out_size, void* d_ws,
                              size_t ws_size, hipStream_t stream) {
  const float* vertices = (const float*)d_in[0];
  const float* onehot = (const float*)d_in[1];
  const float* d0 = (const float*)d_in[2];
  const float *w[8], *bb[8], *dd[8];
  for (int i = 1; i <= 7; ++i) {
    w[i] = (const float*)d_in[3 * i];
    bb[i] = (const float*)d_in[3 * i + 1];
    dd[i] = (const float*)d_in[3 * i + 2];
  }
  const float* cw1 = (const float*)d_in[24];
  const float* cb1 = (const float*)d_in[25];
  const float* cw2 = (const float*)d_in[26];
  const float* cb2 = (const float*)d_in[27];
  const float* cw3 = (const float*)d_in[28];
  const float* cb3 = (const float*)d_in[29];
  float* out = (float*)d_out;

  char* wsp = (char*)d_ws;
  size_t off = 0;
  auto alloc = [&](size_t bytes) -> void* {
    void* p = wsp + off;
    off += (bytes + 255) & ~(size_t)255;
    return p;
  };
  const int M = BS * V0;  // 16384
  int* rank = (int*)alloc(4608 * 4);
  int* perm1 = (int*)alloc(512 * 4);
  int* perm2 = (int*)alloc(128 * 4);
  int* ni1 = (int*)alloc((size_t)BS * V0 * 32 * 4);
  int* ni2 = (int*)alloc((size_t)BS * V1N * 32 * 4);
  int* ni3 = (int*)alloc((size_t)BS * V2N * 32 * 4);
  float* fm2buf = (float*)alloc((size_t)BS * V0 * 96 * 4);
  float* fm5buf = (float*)alloc((size_t)BS * V1N * 192 * 4);
  float* fm7buf = (float*)alloc((size_t)BS * V2N * 256 * 4);
  float* fbuf = (float*)alloc((size_t)BS * V0 * 64 * 4);
  float* v1 = (float*)alloc((size_t)BS * V1N * 3 * 4);
  float* v2 = (float*)alloc((size_t)BS * V2N * 3 * 4);
  float* fglob = (float*)alloc((size_t)BS * 256 * 4);
  ushort_t* fuse_b = (ushort_t*)alloc((size_t)M * KP1 * 2);
  ushort_t* h1b = (ushort_t*)alloc((size_t)M * 1024 * 2);
  ushort_t* h2b = (ushort_t*)alloc((size_t)M * 512 * 2);
  ushort_t* cw1b = (ushort_t*)alloc((size_t)1024 * KP1 * 2);
  ushort_t* cw2b = (ushort_t*)alloc((size_t)512 * 1024 * 2);
  ushort_t* cw3b = (ushort_t*)alloc((size_t)128 * 512 * 2);
  float* cb3p = (float*)alloc(128 * 4);

  float rr1 = 0.0625f;
  float rr2 = (float)(0.39 * 0.39);
  float rr3 = (float)(0.63 * 0.63);

  // 1: rank + weight-prep + qbp1 (all input-only deps)
  misc1_kernel<<<18 + PREP_BLKS + 4096, 256, 0, stream>>>(
      rank, cw1, cw2, cw3, cb3, cw1b, cw2b, cw3b, cb3p, vertices, ni1);
  // 2: perm compose + conv_surface(+linear1)
  misc2_kernel<<<1 + BS * V0 / 8, 256, 0, stream>>>(
      rank, perm1, perm2, vertices, ni1, d0, w[1], bb[1], fm2buf, fbuf);
  // 3-4: level-1 convs (conv_act1 fuses linear2)
  conv_act_kernel<<<BS * V0 / 8, 256, 0, stream>>>(
      vertices, dd[1], ni1, fbuf, fm2buf, V0, 96, 32, w[2], bb[2], fbuf);
  conv_act_kernel<<<BS * V0 / 8, 256, 0, stream>>>(
      vertices, dd[2], ni1, fbuf, fm2buf, V0, 96, 64, nullptr, nullptr, nullptr);
  // 5: pool1 (+linear3)
  pool_kernel<<<BS * V1N / 4, 256, 0, stream>>>(
      vertices, fm2buf, 96, 96, V0, perm1, V1N, rr1, v1, fm5buf, 192,
      w[3], bb[3], fbuf);
  // 6: qbp2
  qbp_kernel<<<BS * V1N / 4, 256, 0, stream>>>(v1, V1N, 32, rr2, ni2);
  // 7-9: level-2 convs
  conv_act_kernel<<<BS * V1N / 8, 256, 0, stream>>>(
      v1, dd[3], ni2, fbuf, fm5buf, V1N, 192, 96, w[4], bb[4], fbuf);
  conv_act_kernel<<<BS * V1N / 8, 256, 0, stream>>>(
      v1, dd[4], ni2, fbuf, fm5buf, V1N, 192, 128, w[5], bb[5], fbuf);
  conv_act_kernel<<<BS * V1N / 8, 256, 0, stream>>>(
      v1, dd[5], ni2, fbuf, fm5buf, V1N, 192, 160, nullptr, nullptr, nullptr);
  // 10: pool2 (+linear6)
  pool_kernel<<<BS * V2N / 4, 256, 0, stream>>>(
      v1, fm5buf, 192, 192, V1N, perm2, V2N, rr2, v2, fm7buf, 256,
      w[6], bb[6], fbuf);
  // 11: qbp3
  qbp_kernel<<<BS * V2N / 4, 256, 0, stream>>>(v2, V2N, 32, rr3, ni3);
  // 12-13: level-3 convs (conv_act6 fuses linear7)
  conv_act_kernel<<<BS * V2N / 8, 256, 0, stream>>>(
      v2, dd[6], ni3, fbuf, fm7buf, V2N, 256, 192, w[7], bb[7], fbuf);
  conv_act_kernel<<<BS * V2N / 8, 256, 0, stream>>>(
      v2, dd[7], ni3, fbuf, fm7buf, V2N, 256, 224, nullptr, nullptr, nullptr);
  // 14: global max
  gmax_kernel<<<BS, 256, 0, stream>>>(fm7buf, fglob);
  // 15: fused nearest + gather + bf16 cast
  fuse_row_kernel<<<M, 256, 0, stream>>>(fm2buf, fm5buf, fm7buf, fglob, onehot,
                                         vertices, v1, v2, fuse_b);
  // 16-18: MLP head (bf16 MFMA)
  gemm_mfma_nt<<<dim3(1024 / 128, M / 128), 256, 0, stream>>>(
      fuse_b, cw1b, cb1, h1b, nullptr, KP1, 1024, 1024, 0);
  gemm_mfma_nt<<<dim3(512 / 128, M / 128), 256, 0, stream>>>(
      h1b, cw2b, cb2, h2b, nullptr, 1024, 512, 512, 0);
  gemm_mfma_nt<<<dim3(1, M / 128), 256, 0, stream>>>(
      h2b, cw3b, cb3p, nullptr, out, 512, 50, 50, 1);
}

// Round 9
// 474.415 us; speedup vs baseline: 6.1407x; 1.0045x over previous
//
#include <hip/hip_runtime.h>
#include <hip/hip_bf16.h>

#define BS 8
#define V0 2048
#define V1N 512
#define V2N 128

typedef unsigned short ushort_t;
typedef __attribute__((ext_vector_type(8))) short bf16x8;
typedef __attribute__((ext_vector_type(4))) float f32x4;

// ---------------------------------------------------------------------------
// Threefry2x32 cipher (JAX partitionable mode — verified R4)
// ---------------------------------------------------------------------------
__device__ __forceinline__ void tf2x32(unsigned k0, unsigned k1,
                                       unsigned x0, unsigned x1,
                                       unsigned &o0, unsigned &o1) {
  unsigned ks2 = k0 ^ k1 ^ 0x1BD11BDAu;
  x0 += k0; x1 += k1;
#define RR(r) { x0 += x1; x1 = (x1 << (r)) | (x1 >> (32 - (r))); x1 ^= x0; }
  RR(13) RR(15) RR(26) RR(6)   x0 += k1;  x1 += ks2 + 1u;
  RR(17) RR(29) RR(16) RR(24)  x0 += ks2; x1 += k0 + 2u;
  RR(13) RR(15) RR(26) RR(6)   x0 += k0;  x1 += k1 + 3u;
  RR(17) RR(29) RR(16) RR(24)  x0 += k1;  x1 += ks2 + 4u;
  RR(13) RR(15) RR(26) RR(6)   x0 += ks2; x1 += k0 + 5u;
#undef RR
  o0 = x0; o1 = x1;
}

__device__ __forceinline__ ushort_t f2bf(float f) {
  unsigned u = __float_as_uint(f);
  u += 0x7FFFu + ((u >> 16) & 1u);
  return (ushort_t)(u >> 16);
}

__device__ __forceinline__ float sqdist_f32(float cx, float cy, float cz,
                                            const float* p) {
  float dx = __fsub_rn(cx, p[0]);
  float dy = __fsub_rn(cy, p[1]);
  float dz = __fsub_rn(cz, p[2]);
  return __fadd_rn(__fadd_rn(__fmul_rn(dx, dx), __fmul_rn(dy, dy)),
                   __fmul_rn(dz, dz));
}

#define KP1 1440

// ---------------------------------------------------------------------------
// misc1: [0,18) threefry rank · [18,18+8065) weight prep · rest qbp level-1
// ---------------------------------------------------------------------------
#define PREP_BLKS 8065
__global__ __launch_bounds__(256) void misc1_kernel(
    int* __restrict__ rank, const float* __restrict__ cw1,
    const float* __restrict__ cw2, const float* __restrict__ cw3,
    const float* __restrict__ cb3, ushort_t* __restrict__ cw1b,
    ushort_t* __restrict__ cw2b, ushort_t* __restrict__ cw3b,
    float* __restrict__ cb3p, const float* __restrict__ pts,
    int* __restrict__ ni1) {
  int bid = blockIdx.x, tid = threadIdx.x;
  if (bid < 18) {
    __shared__ unsigned sb[2048];
    int seg, segfirst, n, base;
    if (bid < 8)       { seg = 0; segfirst = 0;  n = 2048; base = 0; }
    else if (bid < 16) { seg = 1; segfirst = 8;  n = 2048; base = 2048; }
    else               { seg = 2; segfirst = 16; n = 512;  base = 4096; }
    unsigned k0, k1, nk0, nk1, sk0, sk1;
    if (seg == 0) {
      tf2x32(0u, 42u, 0u, 1u, k0, k1);
      tf2x32(k0, k1, 0u, 1u, sk0, sk1);
    } else if (seg == 1) {
      tf2x32(0u, 42u, 0u, 1u, k0, k1);
      tf2x32(k0, k1, 0u, 0u, nk0, nk1);
      tf2x32(nk0, nk1, 0u, 1u, sk0, sk1);
    } else {
      tf2x32(0u, 42u, 0u, 2u, k0, k1);
      tf2x32(k0, k1, 0u, 1u, sk0, sk1);
    }
    for (int i = tid; i < n; i += 256) {
      unsigned o0, o1;
      tf2x32(sk0, sk1, 0u, (unsigned)i, o0, o1);
      sb[i] = o0 ^ o1;
    }
    __syncthreads();
    int tt = (bid - segfirst) * 256 + tid;
    unsigned bt = sb[tt];
    int cnt = 0;
#pragma unroll 8
    for (int s = 0; s < n; ++s) {
      unsigned bs = sb[s];
      cnt += (bs < bt) || (bs == bt && s < tt);
    }
    rank[base + tt] = cnt;
  } else if (bid < 18 + PREP_BLKS) {
    long long t = (long long)(bid - 18) * 256 + tid;
    const long long N1 = 1024LL * KP1, N2 = 512LL * 1024, N3 = 128LL * 512;
    if (t < N1) {
      int k = (int)(t % KP1);
      int n = (int)(t / KP1);
      cw1b[t] = f2bf(k < 1424 ? cw1[(size_t)n * 1424 + k] : 0.f);
    } else if (t < N1 + N2) {
      long long u = t - N1;
      cw2b[u] = f2bf(cw2[u]);
    } else if (t < N1 + N2 + N3) {
      long long u = t - N1 - N2;
      int k = (int)(u & 511);
      int n = (int)(u >> 9);
      cw3b[u] = f2bf(n < 50 ? cw3[(size_t)n * 512 + k] : 0.f);
    } else if (t < N1 + N2 + N3 + 128) {
      int u = (int)(t - N1 - N2 - N3);
      cb3p[u] = u < 50 ? cb3[u] : 0.f;
    }
  } else {
    int bq = bid - 18 - PREP_BLKS;
    int wid = bq * 4 + (tid >> 6);
    int lane = tid & 63;
    int b = wid >> 11, i = wid & 2047;
    const float* base = pts + (size_t)b * V0 * 3;
    float cx = base[i * 3], cy = base[i * 3 + 1], cz = base[i * 3 + 2];
    int cnt = 0, idx0 = 0;
    for (int j0 = 0; j0 < V0; j0 += 64) {
      int j = j0 + lane;
      float d2 = sqdist_f32(cx, cy, cz, base + (size_t)j * 3);
      bool in = (d2 <= 0.0625f);
      unsigned long long mask = __ballot(in);
      if (cnt == 0 && mask) idx0 = j0 + __builtin_ctzll(mask);
      if (in) {
        int rk = cnt + __popcll(mask & ((1ull << lane) - 1ull));
        if (rk < 32) ni1[(size_t)wid * 32 + rk] = j;
      }
      cnt += __popcll(mask);
      if (cnt >= 32) break;
    }
    for (int s = cnt + lane; s < 32; s += 64) ni1[(size_t)wid * 32 + s] = idx0;
  }
}

// ---------------------------------------------------------------------------
__device__ __forceinline__ void dirn(const float* base, int v, int nb,
                                     float& ox, float& oy, float& oz) {
  float dx = __fsub_rn(base[nb * 3 + 0], base[v * 3 + 0]);
  float dy = __fsub_rn(base[nb * 3 + 1], base[v * 3 + 1]);
  float dz = __fsub_rn(base[nb * 3 + 2], base[v * 3 + 2]);
  float s2 = __fadd_rn(__fadd_rn(__fmul_rn(dx, dx), __fmul_rn(dy, dy)),
                       __fmul_rn(dz, dz));
  float nrm = fmaxf(__fsqrt_rn(s2), 1e-12f);
  ox = __fdiv_rn(dx, nrm); oy = __fdiv_rn(dy, nrm); oz = __fdiv_rn(dz, nrm);
}

__device__ __forceinline__ void norm_col(const float* d, int k,
                                         float& ox, float& oy, float& oz) {
  float x = d[k], y = d[32 + k], z = d[64 + k];
  float s2 = __fadd_rn(__fadd_rn(__fmul_rn(x, x), __fmul_rn(y, y)),
                       __fmul_rn(z, z));
  float nrm = fmaxf(__fsqrt_rn(s2), 1e-12f);
  ox = __fdiv_rn(x, nrm); oy = __fdiv_rn(y, nrm); oz = __fdiv_rn(z, nrm);
}

// ---------------------------------------------------------------------------
// misc2: block 0 = perm compose; blocks [1,2049) = conv_surface (+linear1)
// ---------------------------------------------------------------------------
__global__ __launch_bounds__(256) void misc2_kernel(
    const int* __restrict__ rank, int* __restrict__ perm1,
    int* __restrict__ perm2, const float* __restrict__ pts,
    const int* __restrict__ ni, const float* __restrict__ d0,
    const float* __restrict__ w1, const float* __restrict__ b1,
    float* __restrict__ out, float* __restrict__ fn) {
  int bid = blockIdx.x, tid = threadIdx.x;
  if (bid == 0) {
    __shared__ int a1[2048];
    __shared__ int a2[2048];
    for (int i = tid; i < 2048; i += 256) a1[rank[i]] = i;
    __syncthreads();
    for (int i = tid; i < 2048; i += 256) a2[rank[2048 + i]] = a1[i];
    __syncthreads();
    for (int i = tid; i < 512; i += 256) perm1[i] = a2[i];
    for (int i = tid; i < 512; i += 256) a1[rank[4096 + i]] = i;
    __syncthreads();
    for (int i = tid; i < 128; i += 256) perm2[i] = a1[i];
    return;
  }
  __shared__ float sdir[3][32];
  __shared__ float sdn[8][32][3];
  __shared__ float sfm[8][32];
  if (tid < 32) {
    float x, y, z; norm_col(d0, tid, x, y, z);
    sdir[0][tid] = x; sdir[1][tid] = y; sdir[2][tid] = z;
  }
  int vloc = tid >> 5, k = tid & 31;
  size_t bvg = (size_t)(bid - 1) * 8 + vloc;
  int b = (int)(bvg >> 11), v = (int)(bvg & 2047);
  const float* base = pts + (size_t)b * V0 * 3;
  int nb = ni[bvg * 32 + k];
  float x, y, z; dirn(base, v, nb, x, y, z);
  sdn[vloc][k][0] = x; sdn[vloc][k][1] = y; sdn[vloc][k][2] = z;
  __syncthreads();
  float m = 0.f;
  for (int n = 0; n < 32; ++n) {
    float d = sdn[vloc][n][0] * sdir[0][k] + sdn[vloc][n][1] * sdir[1][k] +
              sdn[vloc][n][2] * sdir[2][k];
    m = fmaxf(m, fmaxf(d, 0.f));
  }
  out[bvg * 96 + k] = m;
  sfm[vloc][k] = m;
  __syncthreads();
  float a1v = b1[k], a2v = b1[k + 32];
  for (int c = 0; c < 32; ++c) {
    float vv = sfm[vloc][c];
    a1v += vv * w1[c * 64 + k];
    a2v += vv * w1[c * 64 + k + 32];
  }
  fn[bvg * 64 + k] = a1v;
  fn[bvg * 64 + k + 32] = a2v;
}

// ---------------------------------------------------------------------------
// conv_act (+ optional fused next-linear)
// ---------------------------------------------------------------------------
__global__ __launch_bounds__(256) void conv_act_kernel(
    const float* __restrict__ pts, const float* __restrict__ dd,
    const int* __restrict__ ni, const float* __restrict__ f,
    float* __restrict__ out, int Nv, int ldout, int colofs,
    const float* __restrict__ wn, const float* __restrict__ bn,
    float* __restrict__ fn) {
  __shared__ float sdir[3][32];
  __shared__ float sdn[8][32][3];
  __shared__ int sidx[8][32];
  __shared__ float sfm[8][256];
  int tid = threadIdx.x;
  if (tid < 32) {
    float x, y, z; norm_col(dd, tid, x, y, z);
    sdir[0][tid] = x; sdir[1][tid] = y; sdir[2][tid] = z;
  }
  int vloc = tid >> 5, k = tid & 31;
  size_t bvg = (size_t)blockIdx.x * 8 + vloc;
  int b = (int)(bvg / Nv), v = (int)(bvg % Nv);
  const float* base = pts + (size_t)b * Nv * 3;
  int nb = ni[bvg * 32 + k];
  float x, y, z; dirn(base, v, nb, x, y, z);
  sdn[vloc][k][0] = x; sdn[vloc][k][1] = y; sdn[vloc][k][2] = z;
  sidx[vloc][k] = nb;
  __syncthreads();
  float m = -INFINITY;
  size_t fb = (size_t)b * Nv * 64;
  for (int n = 0; n < 32; ++n) {
    float th = fmaxf(sdn[vloc][n][0] * sdir[0][k] + sdn[vloc][n][1] * sdir[1][k] +
                     sdn[vloc][n][2] * sdir[2][k], 0.f);
    float sup = f[fb + (size_t)sidx[vloc][n] * 64 + 32 + k];
    m = fmaxf(m, th * sup);
  }
  float center = f[bvg * 64 + k];
  float res = fmaxf(center + m, 0.f);
  out[bvg * ldout + colofs + k] = res;
  if (wn) {
    size_t rowbase = (size_t)blockIdx.x * 8;
#pragma unroll 1
    for (int r = 0; r < 8; ++r)
      if (tid < colofs) sfm[r][tid] = out[(rowbase + r) * ldout + tid];
    sfm[vloc][colofs + k] = res;
    __syncthreads();
    int cin = colofs + 32;
    float a1v = bn[k], a2v = bn[k + 32];
    for (int c = 0; c < cin; ++c) {
      float vv = sfm[vloc][c];
      a1v += vv * wn[c * 64 + k];
      a2v += vv * wn[c * 64 + k + 32];
    }
    fn[bvg * 64 + k] = a1v;
    fn[bvg * 64 + k + 32] = a2v;
  }
}

// ---------------------------------------------------------------------------
// conv_act_qbp: qbp (ball query) fused in front of conv_act (+fused linear).
// Block stages this batch's Nv positions into LDS, ballot-scans 8 vertices,
// writes ni to global (for later convs) and proceeds with the conv.
// ---------------------------------------------------------------------------
__global__ __launch_bounds__(256) void conv_act_qbp_kernel(
    const float* __restrict__ pts, int Nv, float rrq,
    const float* __restrict__ dd, int* __restrict__ ni_out,
    const float* __restrict__ f, float* __restrict__ out, int ldout,
    int colofs, const float* __restrict__ wn, const float* __restrict__ bn,
    float* __restrict__ fn) {
  __shared__ float spts[512 * 3];
  __shared__ float sdir[3][32];
  __shared__ float sdn[8][32][3];
  __shared__ int sni[8][32];
  __shared__ float sfm[8][256];
  int tid = threadIdx.x;
  int b = (blockIdx.x * 8) / Nv;
  int vbase = (blockIdx.x * 8) % Nv;
  const float* gp = pts + (size_t)b * Nv * 3;
  for (int i = tid; i < Nv * 3; i += 256) spts[i] = gp[i];
  if (tid < 32) {
    float x, y, z; norm_col(dd, tid, x, y, z);
    sdir[0][tid] = x; sdir[1][tid] = y; sdir[2][tid] = z;
  }
  __syncthreads();
  // qbp phase: wave wv handles vertices 2wv, 2wv+1 (bit-exact f32 semantics)
  int lane = tid & 63, wv = tid >> 6;
  for (int rep = 0; rep < 2; ++rep) {
    int vl = wv * 2 + rep;
    int v = vbase + vl;
    float cx = spts[v * 3], cy = spts[v * 3 + 1], cz = spts[v * 3 + 2];
    int cnt = 0, idx0 = 0;
    for (int j0 = 0; j0 < Nv; j0 += 64) {
      int j = j0 + lane;
      float d2 = sqdist_f32(cx, cy, cz, spts + (size_t)j * 3);
      bool in = (d2 <= rrq);
      unsigned long long mask = __ballot(in);
      if (cnt == 0 && mask) idx0 = j0 + __builtin_ctzll(mask);
      if (in) {
        int rk = cnt + __popcll(mask & ((1ull << lane) - 1ull));
        if (rk < 32) sni[vl][rk] = j;
      }
      cnt += __popcll(mask);
      if (cnt >= 32) break;
    }
    for (int s = cnt + lane; s < 32; s += 64) sni[vl][s] = idx0;
  }
  __syncthreads();
  ni_out[(size_t)(blockIdx.x * 8) * 32 + tid] = sni[tid >> 5][tid & 31];
  // conv phase
  int vloc = tid >> 5, k = tid & 31;
  size_t bvg = (size_t)blockIdx.x * 8 + vloc;
  int v = vbase + vloc;
  int nb = sni[vloc][k];
  float x, y, z; dirn(spts, v, nb, x, y, z);
  sdn[vloc][k][0] = x; sdn[vloc][k][1] = y; sdn[vloc][k][2] = z;
  __syncthreads();
  float m = -INFINITY;
  size_t fb = (size_t)b * Nv * 64;
  for (int n = 0; n < 32; ++n) {
    float th = fmaxf(sdn[vloc][n][0] * sdir[0][k] + sdn[vloc][n][1] * sdir[1][k] +
                     sdn[vloc][n][2] * sdir[2][k], 0.f);
    float sup = f[fb + (size_t)sni[vloc][n] * 64 + 32 + k];
    m = fmaxf(m, th * sup);
  }
  float center = f[bvg * 64 + k];
  float res = fmaxf(center + m, 0.f);
  out[bvg * ldout + colofs + k] = res;
  size_t rowbase = (size_t)blockIdx.x * 8;
#pragma unroll 1
  for (int r = 0; r < 8; ++r)
    if (tid < colofs) sfm[r][tid] = out[(rowbase + r) * ldout + tid];
  sfm[vloc][colofs + k] = res;
  __syncthreads();
  int cin = colofs + 32;
  float a1v = bn[k], a2v = bn[k + 32];
  for (int c = 0; c < cin; ++c) {
    float vv = sfm[vloc][c];
    a1v += vv * wn[c * 64 + k];
    a2v += vv * wn[c * 64 + k + 32];
  }
  fn[bvg * 64 + k] = a1v;
  fn[bvg * 64 + k + 32] = a2v;
}

// ---------------------------------------------------------------------------
// pool (+ fused next-linear)
// ---------------------------------------------------------------------------
__global__ __launch_bounds__(256) void pool_kernel(
    const float* __restrict__ pts_in, const float* __restrict__ fm_in,
    int ld_in, int C, int Nv_in, const int* __restrict__ perm, int Nv_out,
    float rr, float* __restrict__ pts_out, float* __restrict__ fm_out,
    int ld_out, const float* __restrict__ wn, const float* __restrict__ bn,
    float* __restrict__ fn) {
  __shared__ float spf[4][192];
  int wv = threadIdx.x >> 6;
  int lane = threadIdx.x & 63;
  int wid = blockIdx.x * 4 + wv;
  int b = wid / Nv_out, pp = wid - b * Nv_out;
  int v = perm[pp];
  const float* base = pts_in + (size_t)b * Nv_in * 3;
  float cx = base[v * 3], cy = base[v * 3 + 1], cz = base[v * 3 + 2];
  int nb[4]; int cnt = 0;
  for (int j0 = 0; j0 < Nv_in && cnt < 4; j0 += 64) {
    int j = j0 + lane;
    float d2 = sqdist_f32(cx, cy, cz, base + (size_t)j * 3);
    unsigned long long mask = __ballot(d2 <= rr);
    while (mask && cnt < 4) {
      int bp = __builtin_ctzll(mask);
      mask &= mask - 1;
      nb[cnt++] = j0 + bp;
    }
  }
  for (int q = cnt; q < 4; ++q) nb[q] = nb[0];
  if (lane < 3) pts_out[(size_t)wid * 3 + lane] = base[v * 3 + lane];
  size_t inrow = (size_t)b * Nv_in;
  size_t outrow = (size_t)wid * ld_out;
  for (int c = lane; c < C; c += 64) {
    float m = fm_in[(inrow + nb[0]) * ld_in + c];
    m = fmaxf(m, fm_in[(inrow + nb[1]) * ld_in + c]);
    m = fmaxf(m, fm_in[(inrow + nb[2]) * ld_in + c]);
    m = fmaxf(m, fm_in[(inrow + nb[3]) * ld_in + c]);
    fm_out[outrow + c] = m;
    spf[wv][c] = m;
  }
  __syncthreads();
  int o = threadIdx.x & 63, w_ = threadIdx.x >> 6;
  int wid0 = blockIdx.x * 4 + w_;
  float a = bn[o];
  for (int c = 0; c < C; ++c) a += spf[w_][c] * wn[c * 64 + o];
  fn[(size_t)wid0 * 64 + o] = a;
}

// ---------------------------------------------------------------------------
__global__ void gmax_kernel(const float* __restrict__ fm,
                            float* __restrict__ out) {
  int t = blockIdx.x * blockDim.x + threadIdx.x;
  if (t >= BS * 256) return;
  int b = t >> 8, c = t & 255;
  float m = -INFINITY;
  for (int v = 0; v < V2N; ++v)
    m = fmaxf(m, fm[((size_t)b * V2N + v) * 256 + c]);
  out[t] = m;
}

// ---------------------------------------------------------------------------
__device__ __forceinline__ float fuse_val(const float* r2, const float* r5,
                                          const float* r7, const float* rg,
                                          const float* roh, int c) {
  if (c < 192) {
    int cc = (c < 32) ? c : (c < 96 ? c - 32 : c - 96);
    return r2[cc];
  } else if (c < 672) {
    int cc = (c < 320) ? c - 192 : (c < 480 ? c - 320 : c - 480);
    return r5[cc];
  } else if (c < 1152) {
    int cc = (c < 896) ? c - 672 : c - 896;
    return r7[cc];
  } else if (c < 1408) {
    return rg[c - 1152];
  } else if (c < 1424) {
    return roh[c - 1408];
  }
  return 0.f;
}

__global__ __launch_bounds__(256) void fuse_row_kernel(
    const float* __restrict__ fm2, const float* __restrict__ fm5,
    const float* __restrict__ fm7, const float* __restrict__ fglob,
    const float* __restrict__ onehot, const float* __restrict__ verts,
    const float* __restrict__ v1, const float* __restrict__ v2,
    ushort_t* __restrict__ fuse_b) {
  __shared__ unsigned long long red[256];
  __shared__ int sn1, sn2;
  int bv = blockIdx.x;
  int b = bv >> 11;
  int tid = threadIdx.x;
  float cx = verts[(size_t)bv * 3 + 0];
  float cy = verts[(size_t)bv * 3 + 1];
  float cz = verts[(size_t)bv * 3 + 2];
  unsigned long long best = ~0ull;
  const float* sb = v1 + (size_t)b * V1N * 3;
  for (int j = tid; j < V1N; j += 256) {
    float d2 = sqdist_f32(cx, cy, cz, sb + (size_t)j * 3);
    unsigned long long key =
        (((unsigned long long)__float_as_uint(d2)) << 32) | (unsigned)j;
    best = best < key ? best : key;
  }
  red[tid] = best;
  __syncthreads();
  for (int s = 128; s > 0; s >>= 1) {
    if (tid < s) red[tid] = red[tid] < red[tid + s] ? red[tid] : red[tid + s];
    __syncthreads();
  }
  if (tid == 0) sn1 = (int)(red[0] & 0xffffffffu);
  __syncthreads();
  best = ~0ull;
  sb = v2 + (size_t)b * V2N * 3;
  for (int j = tid; j < V2N; j += 256) {
    float d2 = sqdist_f32(cx, cy, cz, sb + (size_t)j * 3);
    unsigned long long key =
        (((unsigned long long)__float_as_uint(d2)) << 32) | (unsigned)j;
    best = best < key ? best : key;
  }
  red[tid] = best;
  __syncthreads();
  for (int s = 128; s > 0; s >>= 1) {
    if (tid < s) red[tid] = red[tid] < red[tid + s] ? red[tid] : red[tid + s];
    __syncthreads();
  }
  if (tid == 0) sn2 = (int)(red[0] & 0xffffffffu);
  __syncthreads();
  const float* r2 = fm2 + (size_t)bv * 96;
  const float* r5 = fm5 + ((size_t)b * V1N + sn1) * 192;
  const float* r7 = fm7 + ((size_t)b * V2N + sn2) * 256;
  const float* rg = fglob + b * 256;
  const float* roh = onehot + b * 16;
  ushort_t* orow = fuse_b + (size_t)bv * KP1;
  for (int c = tid; c < KP1; c += 256)
    orow[c] = f2bf(fuse_val(r2, r5, r7, rg, roh, c));
}

// ---------------------------------------------------------------------------
// bf16 MFMA GEMM — m97 structure + XCD swizzle + XOR-4 bank-conflict swizzle.
// Staging lane fetches global chunk (l&3)^(row&3) of its row (coalescing
// preserved: same 64B per row, lanes permuted). Reads address slot q^(row&3).
// ---------------------------------------------------------------------------
typedef const __attribute__((address_space(1))) unsigned int gas_u32;
typedef __attribute__((address_space(3))) unsigned int las_u32;

__global__ __launch_bounds__(256) void gemm_mfma_nt(
    const ushort_t* __restrict__ A, const ushort_t* __restrict__ B,
    const float* __restrict__ bias, ushort_t* __restrict__ Cb,
    float* __restrict__ Cf, int K, int ldc, int nvalid, int mode) {
  __shared__ ushort_t As[128 * 32];
  __shared__ ushort_t Bs[128 * 32];
  int tid = threadIdx.x;
  int lane = tid & 63, w = tid >> 6;
  int wm = (w >> 1) * 64, wn = (w & 1) * 64;
  int nb = gridDim.x;
  int flat = blockIdx.x + nb * blockIdx.y;
  int xcd = flat & 7, slot = flat >> 3;
  int nidx = slot % nb;
  int mband = xcd + 8 * (slot / nb);
  int bm = mband * 128, bn = nidx * 128;
  f32x4 acc[4][4];
#pragma unroll
  for (int i = 0; i < 4; ++i)
#pragma unroll
    for (int j = 0; j < 4; ++j) acc[i][j] = (f32x4){0.f, 0.f, 0.f, 0.f};

  int rowA0 = lane >> 2;
  int chunkA = (lane & 3) ^ (rowA0 & 3);        // XOR-4 swizzle
  int colA0 = chunkA * 8;
  int seg0 = w * 2;
  const ushort_t* ga0 = A + (size_t)(bm + seg0 * 16 + rowA0) * K + colA0;
  const ushort_t* ga1 = A + (size_t)(bm + (seg0 + 1) * 16 + rowA0) * K + colA0;
  const ushort_t* gb0 = B + (size_t)(bn + seg0 * 16 + rowA0) * K + colA0;
  const ushort_t* gb1 = B + (size_t)(bn + (seg0 + 1) * 16 + rowA0) * K + colA0;
  ushort_t* la0 = As + seg0 * 512;
  ushort_t* la1 = As + (seg0 + 1) * 512;
  ushort_t* lb0 = Bs + seg0 * 512;
  ushort_t* lb1 = Bs + (seg0 + 1) * 512;

  int rA = lane & 15;
  int sl = ((lane >> 4) ^ (rA & 3)) * 8;        // de-swizzled read slot

  for (int k0 = 0; k0 < K; k0 += 32) {
    __builtin_amdgcn_global_load_lds((gas_u32*)(ga0 + k0), (las_u32*)la0, 16, 0, 0);
    __builtin_amdgcn_global_load_lds((gas_u32*)(ga1 + k0), (las_u32*)la1, 16, 0, 0);
    __builtin_amdgcn_global_load_lds((gas_u32*)(gb0 + k0), (las_u32*)lb0, 16, 0, 0);
    __builtin_amdgcn_global_load_lds((gas_u32*)(gb1 + k0), (las_u32*)lb1, 16, 0, 0);
    __syncthreads();
    bf16x8 af[4], bfr[4];
#pragma unroll
    for (int i = 0; i < 4; ++i)
      af[i] = *(const bf16x8*)(As + (wm + i * 16 + rA) * 32 + sl);
#pragma unroll
    for (int j = 0; j < 4; ++j)
      bfr[j] = *(const bf16x8*)(Bs + (wn + j * 16 + rA) * 32 + sl);
#pragma unroll
    for (int i = 0; i < 4; ++i)
#pragma unroll
      for (int j = 0; j < 4; ++j)
        acc[i][j] = __builtin_amdgcn_mfma_f32_16x16x32_bf16(af[i], bfr[j],
                                                            acc[i][j], 0, 0, 0);
    __syncthreads();
  }

  int rowq = (lane >> 4) * 4;
  int coll = lane & 15;
#pragma unroll
  for (int i = 0; i < 4; ++i) {
#pragma unroll
    for (int j = 0; j < 4; ++j) {
      int col = bn + wn + j * 16 + coll;
      float bi = bias[col];
#pragma unroll
      for (int r = 0; r < 4; ++r) {
        int row = bm + wm + i * 16 + rowq + r;
        float v = acc[i][j][r] + bi;
        if (mode == 0) {
          Cb[(size_t)row * ldc + col] = f2bf(fmaxf(v, 0.f));
        } else if (col < nvalid) {
          Cf[(size_t)row * ldc + col] = v;
        }
      }
    }
  }
}

// ---------------------------------------------------------------------------
extern "C" void kernel_launch(void* const* d_in, const int* in_sizes, int n_in,
                              void* d_out, int out_size, void* d_ws,
                              size_t ws_size, hipStream_t stream) {
  const float* vertices = (const float*)d_in[0];
  const float* onehot = (const float*)d_in[1];
  const float* d0 = (const float*)d_in[2];
  const float *w[8], *bb[8], *dd[8];
  for (int i = 1; i <= 7; ++i) {
    w[i] = (const float*)d_in[3 * i];
    bb[i] = (const float*)d_in[3 * i + 1];
    dd[i] = (const float*)d_in[3 * i + 2];
  }
  const float* cw1 = (const float*)d_in[24];
  const float* cb1 = (const float*)d_in[25];
  const float* cw2 = (const float*)d_in[26];
  const float* cb2 = (const float*)d_in[27];
  const float* cw3 = (const float*)d_in[28];
  const float* cb3 = (const float*)d_in[29];
  float* out = (float*)d_out;

  char* wsp = (char*)d_ws;
  size_t off = 0;
  auto alloc = [&](size_t bytes) -> void* {
    void* p = wsp + off;
    off += (bytes + 255) & ~(size_t)255;
    return p;
  };
  const int M = BS * V0;  // 16384
  int* rank = (int*)alloc(4608 * 4);
  int* perm1 = (int*)alloc(512 * 4);
  int* perm2 = (int*)alloc(128 * 4);
  int* ni1 = (int*)alloc((size_t)BS * V0 * 32 * 4);
  int* ni2 = (int*)alloc((size_t)BS * V1N * 32 * 4);
  int* ni3 = (int*)alloc((size_t)BS * V2N * 32 * 4);
  float* fm2buf = (float*)alloc((size_t)BS * V0 * 96 * 4);
  float* fm5buf = (float*)alloc((size_t)BS * V1N * 192 * 4);
  float* fm7buf = (float*)alloc((size_t)BS * V2N * 256 * 4);
  float* fbuf = (float*)alloc((size_t)BS * V0 * 64 * 4);
  float* v1 = (float*)alloc((size_t)BS * V1N * 3 * 4);
  float* v2 = (float*)alloc((size_t)BS * V2N * 3 * 4);
  float* fglob = (float*)alloc((size_t)BS * 256 * 4);
  ushort_t* fuse_b = (ushort_t*)alloc((size_t)M * KP1 * 2);
  ushort_t* h1b = (ushort_t*)alloc((size_t)M * 1024 * 2);
  ushort_t* h2b = (ushort_t*)alloc((size_t)M * 512 * 2);
  ushort_t* cw1b = (ushort_t*)alloc((size_t)1024 * KP1 * 2);
  ushort_t* cw2b = (ushort_t*)alloc((size_t)512 * 1024 * 2);
  ushort_t* cw3b = (ushort_t*)alloc((size_t)128 * 512 * 2);
  float* cb3p = (float*)alloc(128 * 4);

  float rr1 = 0.0625f;
  float rr2 = (float)(0.39 * 0.39);
  float rr3 = (float)(0.63 * 0.63);

  // 1: rank + weight-prep + qbp1
  misc1_kernel<<<18 + PREP_BLKS + 4096, 256, 0, stream>>>(
      rank, cw1, cw2, cw3, cb3, cw1b, cw2b, cw3b, cb3p, vertices, ni1);
  // 2: perm compose + conv_surface(+linear1)
  misc2_kernel<<<1 + BS * V0 / 8, 256, 0, stream>>>(
      rank, perm1, perm2, vertices, ni1, d0, w[1], bb[1], fm2buf, fbuf);
  // 3-4: level-1 convs
  conv_act_kernel<<<BS * V0 / 8, 256, 0, stream>>>(
      vertices, dd[1], ni1, fbuf, fm2buf, V0, 96, 32, w[2], bb[2], fbuf);
  conv_act_kernel<<<BS * V0 / 8, 256, 0, stream>>>(
      vertices, dd[2], ni1, fbuf, fm2buf, V0, 96, 64, nullptr, nullptr, nullptr);
  // 5: pool1 (+linear3)
  pool_kernel<<<BS * V1N / 4, 256, 0, stream>>>(
      vertices, fm2buf, 96, 96, V0, perm1, V1N, rr1, v1, fm5buf, 192,
      w[3], bb[3], fbuf);
  // 6-8: level-2 convs (first fuses qbp2 + linear4)
  conv_act_qbp_kernel<<<BS * V1N / 8, 256, 0, stream>>>(
      v1, V1N, rr2, dd[3], ni2, fbuf, fm5buf, 192, 96, w[4], bb[4], fbuf);
  conv_act_kernel<<<BS * V1N / 8, 256, 0, stream>>>(
      v1, dd[4], ni2, fbuf, fm5buf, V1N, 192, 128, w[5], bb[5], fbuf);
  conv_act_kernel<<<BS * V1N / 8, 256, 0, stream>>>(
      v1, dd[5], ni2, fbuf, fm5buf, V1N, 192, 160, nullptr, nullptr, nullptr);
  // 9: pool2 (+linear6)
  pool_kernel<<<BS * V2N / 4, 256, 0, stream>>>(
      v1, fm5buf, 192, 192, V1N, perm2, V2N, rr2, v2, fm7buf, 256,
      w[6], bb[6], fbuf);
  // 10-11: level-3 convs (first fuses qbp3 + linear7)
  conv_act_qbp_kernel<<<BS * V2N / 8, 256, 0, stream>>>(
      v2, V2N, rr3, dd[6], ni3, fbuf, fm7buf, 256, 192, w[7], bb[7], fbuf);
  conv_act_kernel<<<BS * V2N / 8, 256, 0, stream>>>(
      v2, dd[7], ni3, fbuf, fm7buf, V2N, 256, 224, nullptr, nullptr, nullptr);
  // 12: global max
  gmax_kernel<<<BS, 256, 0, stream>>>(fm7buf, fglob);
  // 13: fused nearest + gather + bf16 cast
  fuse_row_kernel<<<M, 256, 0, stream>>>(fm2buf, fm5buf, fm7buf, fglob, onehot,
                                         vertices, v1, v2, fuse_b);
  // 14-16: MLP head (bf16 MFMA)
  gemm_mfma_nt<<<dim3(1024 / 128, M / 128), 256, 0, stream>>>(
      fuse_b, cw1b, cb1, h1b, nullptr, KP1, 1024, 1024, 0);
  gemm_mfma_nt<<<dim3(512 / 128, M / 128), 256, 0, stream>>>(
      h1b, cw2b, cb2, h2b, nullptr, 1024, 512, 512, 0);
  gemm_mfma_nt<<<dim3(1, M / 128), 256, 0, stream>>>(
      h2b, cw3b, cb3p, nullptr, out, 512, 50, 50, 1);
}

// Round 10
// 447.141 us; speedup vs baseline: 6.5153x; 1.0610x over previous
//
#include <hip/hip_runtime.h>
#include <hip/hip_bf16.h>

#define BS 8
#define V0 2048
#define V1N 512
#define V2N 128

typedef unsigned short ushort_t;
typedef __attribute__((ext_vector_type(8))) short bf16x8;
typedef __attribute__((ext_vector_type(4))) float f32x4;

// ---------------------------------------------------------------------------
// Threefry2x32 cipher (JAX partitionable mode — verified R4)
// ---------------------------------------------------------------------------
__device__ __forceinline__ void tf2x32(unsigned k0, unsigned k1,
                                       unsigned x0, unsigned x1,
                                       unsigned &o0, unsigned &o1) {
  unsigned ks2 = k0 ^ k1 ^ 0x1BD11BDAu;
  x0 += k0; x1 += k1;
#define RR(r) { x0 += x1; x1 = (x1 << (r)) | (x1 >> (32 - (r))); x1 ^= x0; }
  RR(13) RR(15) RR(26) RR(6)   x0 += k1;  x1 += ks2 + 1u;
  RR(17) RR(29) RR(16) RR(24)  x0 += ks2; x1 += k0 + 2u;
  RR(13) RR(15) RR(26) RR(6)   x0 += k0;  x1 += k1 + 3u;
  RR(17) RR(29) RR(16) RR(24)  x0 += k1;  x1 += ks2 + 4u;
  RR(13) RR(15) RR(26) RR(6)   x0 += ks2; x1 += k0 + 5u;
#undef RR
  o0 = x0; o1 = x1;
}

__device__ __forceinline__ ushort_t f2bf(float f) {
  unsigned u = __float_as_uint(f);
  u += 0x7FFFu + ((u >> 16) & 1u);
  return (ushort_t)(u >> 16);
}

__device__ __forceinline__ float sqdist_f32(float cx, float cy, float cz,
                                            const float* p) {
  float dx = __fsub_rn(cx, p[0]);
  float dy = __fsub_rn(cy, p[1]);
  float dz = __fsub_rn(cz, p[2]);
  return __fadd_rn(__fadd_rn(__fmul_rn(dx, dx), __fmul_rn(dy, dy)),
                   __fmul_rn(dz, dz));
}

#define KP1 1472   // 1424 real + zero pad to 64-multiple (BK=64)

// ---------------------------------------------------------------------------
// misc1: [0,18) threefry rank · [18,18+PREP_BLKS) weight prep · rest qbp lvl-1
// ---------------------------------------------------------------------------
#define PREP_BLKS 8193
__global__ __launch_bounds__(256) void misc1_kernel(
    int* __restrict__ rank, const float* __restrict__ cw1,
    const float* __restrict__ cw2, const float* __restrict__ cw3,
    const float* __restrict__ cb3, ushort_t* __restrict__ cw1b,
    ushort_t* __restrict__ cw2b, ushort_t* __restrict__ cw3b,
    float* __restrict__ cb3p, const float* __restrict__ pts,
    int* __restrict__ ni1) {
  int bid = blockIdx.x, tid = threadIdx.x;
  if (bid < 18) {
    __shared__ unsigned sb[2048];
    int seg, segfirst, n, base;
    if (bid < 8)       { seg = 0; segfirst = 0;  n = 2048; base = 0; }
    else if (bid < 16) { seg = 1; segfirst = 8;  n = 2048; base = 2048; }
    else               { seg = 2; segfirst = 16; n = 512;  base = 4096; }
    unsigned k0, k1, nk0, nk1, sk0, sk1;
    if (seg == 0) {
      tf2x32(0u, 42u, 0u, 1u, k0, k1);
      tf2x32(k0, k1, 0u, 1u, sk0, sk1);
    } else if (seg == 1) {
      tf2x32(0u, 42u, 0u, 1u, k0, k1);
      tf2x32(k0, k1, 0u, 0u, nk0, nk1);
      tf2x32(nk0, nk1, 0u, 1u, sk0, sk1);
    } else {
      tf2x32(0u, 42u, 0u, 2u, k0, k1);
      tf2x32(k0, k1, 0u, 1u, sk0, sk1);
    }
    for (int i = tid; i < n; i += 256) {
      unsigned o0, o1;
      tf2x32(sk0, sk1, 0u, (unsigned)i, o0, o1);
      sb[i] = o0 ^ o1;
    }
    __syncthreads();
    int tt = (bid - segfirst) * 256 + tid;
    unsigned bt = sb[tt];
    int cnt = 0;
#pragma unroll 8
    for (int s = 0; s < n; ++s) {
      unsigned bs = sb[s];
      cnt += (bs < bt) || (bs == bt && s < tt);
    }
    rank[base + tt] = cnt;
  } else if (bid < 18 + PREP_BLKS) {
    long long t = (long long)(bid - 18) * 256 + tid;
    const long long N1 = 1024LL * KP1, N2 = 512LL * 1024, N3 = 128LL * 512;
    if (t < N1) {
      int k = (int)(t % KP1);
      int n = (int)(t / KP1);
      cw1b[t] = f2bf(k < 1424 ? cw1[(size_t)n * 1424 + k] : 0.f);
    } else if (t < N1 + N2) {
      long long u = t - N1;
      cw2b[u] = f2bf(cw2[u]);
    } else if (t < N1 + N2 + N3) {
      long long u = t - N1 - N2;
      int k = (int)(u & 511);
      int n = (int)(u >> 9);
      cw3b[u] = f2bf(n < 50 ? cw3[(size_t)n * 512 + k] : 0.f);
    } else if (t < N1 + N2 + N3 + 128) {
      int u = (int)(t - N1 - N2 - N3);
      cb3p[u] = u < 50 ? cb3[u] : 0.f;
    }
  } else {
    int bq = bid - 18 - PREP_BLKS;
    int wid = bq * 4 + (tid >> 6);
    int lane = tid & 63;
    int b = wid >> 11, i = wid & 2047;
    const float* base = pts + (size_t)b * V0 * 3;
    float cx = base[i * 3], cy = base[i * 3 + 1], cz = base[i * 3 + 2];
    int cnt = 0, idx0 = 0;
    for (int j0 = 0; j0 < V0; j0 += 64) {
      int j = j0 + lane;
      float d2 = sqdist_f32(cx, cy, cz, base + (size_t)j * 3);
      bool in = (d2 <= 0.0625f);
      unsigned long long mask = __ballot(in);
      if (cnt == 0 && mask) idx0 = j0 + __builtin_ctzll(mask);
      if (in) {
        int rk = cnt + __popcll(mask & ((1ull << lane) - 1ull));
        if (rk < 32) ni1[(size_t)wid * 32 + rk] = j;
      }
      cnt += __popcll(mask);
      if (cnt >= 32) break;
    }
    for (int s = cnt + lane; s < 32; s += 64) ni1[(size_t)wid * 32 + s] = idx0;
  }
}

// ---------------------------------------------------------------------------
__device__ __forceinline__ void dirn(const float* base, int v, int nb,
                                     float& ox, float& oy, float& oz) {
  float dx = __fsub_rn(base[nb * 3 + 0], base[v * 3 + 0]);
  float dy = __fsub_rn(base[nb * 3 + 1], base[v * 3 + 1]);
  float dz = __fsub_rn(base[nb * 3 + 2], base[v * 3 + 2]);
  float s2 = __fadd_rn(__fadd_rn(__fmul_rn(dx, dx), __fmul_rn(dy, dy)),
                       __fmul_rn(dz, dz));
  float nrm = fmaxf(__fsqrt_rn(s2), 1e-12f);
  ox = __fdiv_rn(dx, nrm); oy = __fdiv_rn(dy, nrm); oz = __fdiv_rn(dz, nrm);
}

__device__ __forceinline__ void norm_col(const float* d, int k,
                                         float& ox, float& oy, float& oz) {
  float x = d[k], y = d[32 + k], z = d[64 + k];
  float s2 = __fadd_rn(__fadd_rn(__fmul_rn(x, x), __fmul_rn(y, y)),
                       __fmul_rn(z, z));
  float nrm = fmaxf(__fsqrt_rn(s2), 1e-12f);
  ox = __fdiv_rn(x, nrm); oy = __fdiv_rn(y, nrm); oz = __fdiv_rn(z, nrm);
}

// ---------------------------------------------------------------------------
// misc2: block 0 = perm compose; blocks [1,2049) = conv_surface (+linear1)
// ---------------------------------------------------------------------------
__global__ __launch_bounds__(256) void misc2_kernel(
    const int* __restrict__ rank, int* __restrict__ perm1,
    int* __restrict__ perm2, const float* __restrict__ pts,
    const int* __restrict__ ni, const float* __restrict__ d0,
    const float* __restrict__ w1, const float* __restrict__ b1,
    float* __restrict__ out, float* __restrict__ fn) {
  int bid = blockIdx.x, tid = threadIdx.x;
  if (bid == 0) {
    __shared__ int a1[2048];
    __shared__ int a2[2048];
    for (int i = tid; i < 2048; i += 256) a1[rank[i]] = i;
    __syncthreads();
    for (int i = tid; i < 2048; i += 256) a2[rank[2048 + i]] = a1[i];
    __syncthreads();
    for (int i = tid; i < 512; i += 256) perm1[i] = a2[i];
    for (int i = tid; i < 512; i += 256) a1[rank[4096 + i]] = i;
    __syncthreads();
    for (int i = tid; i < 128; i += 256) perm2[i] = a1[i];
    return;
  }
  __shared__ float sdir[3][32];
  __shared__ float sdn[8][32][3];
  __shared__ float sfm[8][32];
  if (tid < 32) {
    float x, y, z; norm_col(d0, tid, x, y, z);
    sdir[0][tid] = x; sdir[1][tid] = y; sdir[2][tid] = z;
  }
  int vloc = tid >> 5, k = tid & 31;
  size_t bvg = (size_t)(bid - 1) * 8 + vloc;
  int b = (int)(bvg >> 11), v = (int)(bvg & 2047);
  const float* base = pts + (size_t)b * V0 * 3;
  int nb = ni[bvg * 32 + k];
  float x, y, z; dirn(base, v, nb, x, y, z);
  sdn[vloc][k][0] = x; sdn[vloc][k][1] = y; sdn[vloc][k][2] = z;
  __syncthreads();
  float m = 0.f;
  for (int n = 0; n < 32; ++n) {
    float d = sdn[vloc][n][0] * sdir[0][k] + sdn[vloc][n][1] * sdir[1][k] +
              sdn[vloc][n][2] * sdir[2][k];
    m = fmaxf(m, fmaxf(d, 0.f));
  }
  out[bvg * 96 + k] = m;
  sfm[vloc][k] = m;
  __syncthreads();
  float a1v = b1[k], a2v = b1[k + 32];
  for (int c = 0; c < 32; ++c) {
    float vv = sfm[vloc][c];
    a1v += vv * w1[c * 64 + k];
    a2v += vv * w1[c * 64 + k + 32];
  }
  fn[bvg * 64 + k] = a1v;
  fn[bvg * 64 + k + 32] = a2v;
}

// ---------------------------------------------------------------------------
// conv_act (+ optional fused next-linear)
// ---------------------------------------------------------------------------
__global__ __launch_bounds__(256) void conv_act_kernel(
    const float* __restrict__ pts, const float* __restrict__ dd,
    const int* __restrict__ ni, const float* __restrict__ f,
    float* __restrict__ out, int Nv, int ldout, int colofs,
    const float* __restrict__ wn, const float* __restrict__ bn,
    float* __restrict__ fn) {
  __shared__ float sdir[3][32];
  __shared__ float sdn[8][32][3];
  __shared__ int sidx[8][32];
  __shared__ float sfm[8][256];
  int tid = threadIdx.x;
  if (tid < 32) {
    float x, y, z; norm_col(dd, tid, x, y, z);
    sdir[0][tid] = x; sdir[1][tid] = y; sdir[2][tid] = z;
  }
  int vloc = tid >> 5, k = tid & 31;
  size_t bvg = (size_t)blockIdx.x * 8 + vloc;
  int b = (int)(bvg / Nv), v = (int)(bvg % Nv);
  const float* base = pts + (size_t)b * Nv * 3;
  int nb = ni[bvg * 32 + k];
  float x, y, z; dirn(base, v, nb, x, y, z);
  sdn[vloc][k][0] = x; sdn[vloc][k][1] = y; sdn[vloc][k][2] = z;
  sidx[vloc][k] = nb;
  __syncthreads();
  float m = -INFINITY;
  size_t fb = (size_t)b * Nv * 64;
  for (int n = 0; n < 32; ++n) {
    float th = fmaxf(sdn[vloc][n][0] * sdir[0][k] + sdn[vloc][n][1] * sdir[1][k] +
                     sdn[vloc][n][2] * sdir[2][k], 0.f);
    float sup = f[fb + (size_t)sidx[vloc][n] * 64 + 32 + k];
    m = fmaxf(m, th * sup);
  }
  float center = f[bvg * 64 + k];
  float res = fmaxf(center + m, 0.f);
  out[bvg * ldout + colofs + k] = res;
  if (wn) {
    size_t rowbase = (size_t)blockIdx.x * 8;
#pragma unroll 1
    for (int r = 0; r < 8; ++r)
      if (tid < colofs) sfm[r][tid] = out[(rowbase + r) * ldout + tid];
    sfm[vloc][colofs + k] = res;
    __syncthreads();
    int cin = colofs + 32;
    float a1v = bn[k], a2v = bn[k + 32];
    for (int c = 0; c < cin; ++c) {
      float vv = sfm[vloc][c];
      a1v += vv * wn[c * 64 + k];
      a2v += vv * wn[c * 64 + k + 32];
    }
    fn[bvg * 64 + k] = a1v;
    fn[bvg * 64 + k + 32] = a2v;
  }
}

// ---------------------------------------------------------------------------
// conv_act_qbp: qbp fused in front of conv_act (+fused linear)
// ---------------------------------------------------------------------------
__global__ __launch_bounds__(256) void conv_act_qbp_kernel(
    const float* __restrict__ pts, int Nv, float rrq,
    const float* __restrict__ dd, int* __restrict__ ni_out,
    const float* __restrict__ f, float* __restrict__ out, int ldout,
    int colofs, const float* __restrict__ wn, const float* __restrict__ bn,
    float* __restrict__ fn) {
  __shared__ float spts[512 * 3];
  __shared__ float sdir[3][32];
  __shared__ float sdn[8][32][3];
  __shared__ int sni[8][32];
  __shared__ float sfm[8][256];
  int tid = threadIdx.x;
  int b = (blockIdx.x * 8) / Nv;
  int vbase = (blockIdx.x * 8) % Nv;
  const float* gp = pts + (size_t)b * Nv * 3;
  for (int i = tid; i < Nv * 3; i += 256) spts[i] = gp[i];
  if (tid < 32) {
    float x, y, z; norm_col(dd, tid, x, y, z);
    sdir[0][tid] = x; sdir[1][tid] = y; sdir[2][tid] = z;
  }
  __syncthreads();
  int lane = tid & 63, wv = tid >> 6;
  for (int rep = 0; rep < 2; ++rep) {
    int vl = wv * 2 + rep;
    int v = vbase + vl;
    float cx = spts[v * 3], cy = spts[v * 3 + 1], cz = spts[v * 3 + 2];
    int cnt = 0, idx0 = 0;
    for (int j0 = 0; j0 < Nv; j0 += 64) {
      int j = j0 + lane;
      float d2 = sqdist_f32(cx, cy, cz, spts + (size_t)j * 3);
      bool in = (d2 <= rrq);
      unsigned long long mask = __ballot(in);
      if (cnt == 0 && mask) idx0 = j0 + __builtin_ctzll(mask);
      if (in) {
        int rk = cnt + __popcll(mask & ((1ull << lane) - 1ull));
        if (rk < 32) sni[vl][rk] = j;
      }
      cnt += __popcll(mask);
      if (cnt >= 32) break;
    }
    for (int s = cnt + lane; s < 32; s += 64) sni[vl][s] = idx0;
  }
  __syncthreads();
  ni_out[(size_t)(blockIdx.x * 8) * 32 + tid] = sni[tid >> 5][tid & 31];
  int vloc = tid >> 5, k = tid & 31;
  size_t bvg = (size_t)blockIdx.x * 8 + vloc;
  int v = vbase + vloc;
  int nb = sni[vloc][k];
  float x, y, z; dirn(spts, v, nb, x, y, z);
  sdn[vloc][k][0] = x; sdn[vloc][k][1] = y; sdn[vloc][k][2] = z;
  __syncthreads();
  float m = -INFINITY;
  size_t fb = (size_t)b * Nv * 64;
  for (int n = 0; n < 32; ++n) {
    float th = fmaxf(sdn[vloc][n][0] * sdir[0][k] + sdn[vloc][n][1] * sdir[1][k] +
                     sdn[vloc][n][2] * sdir[2][k], 0.f);
    float sup = f[fb + (size_t)sni[vloc][n] * 64 + 32 + k];
    m = fmaxf(m, th * sup);
  }
  float center = f[bvg * 64 + k];
  float res = fmaxf(center + m, 0.f);
  out[bvg * ldout + colofs + k] = res;
  size_t rowbase = (size_t)blockIdx.x * 8;
#pragma unroll 1
  for (int r = 0; r < 8; ++r)
    if (tid < colofs) sfm[r][tid] = out[(rowbase + r) * ldout + tid];
  sfm[vloc][colofs + k] = res;
  __syncthreads();
  int cin = colofs + 32;
  float a1v = bn[k], a2v = bn[k + 32];
  for (int c = 0; c < cin; ++c) {
    float vv = sfm[vloc][c];
    a1v += vv * wn[c * 64 + k];
    a2v += vv * wn[c * 64 + k + 32];
  }
  fn[bvg * 64 + k] = a1v;
  fn[bvg * 64 + k + 32] = a2v;
}

// ---------------------------------------------------------------------------
// pool (+ fused next-linear)
// ---------------------------------------------------------------------------
__global__ __launch_bounds__(256) void pool_kernel(
    const float* __restrict__ pts_in, const float* __restrict__ fm_in,
    int ld_in, int C, int Nv_in, const int* __restrict__ perm, int Nv_out,
    float rr, float* __restrict__ pts_out, float* __restrict__ fm_out,
    int ld_out, const float* __restrict__ wn, const float* __restrict__ bn,
    float* __restrict__ fn) {
  __shared__ float spf[4][192];
  int wv = threadIdx.x >> 6;
  int lane = threadIdx.x & 63;
  int wid = blockIdx.x * 4 + wv;
  int b = wid / Nv_out, pp = wid - b * Nv_out;
  int v = perm[pp];
  const float* base = pts_in + (size_t)b * Nv_in * 3;
  float cx = base[v * 3], cy = base[v * 3 + 1], cz = base[v * 3 + 2];
  int nb[4]; int cnt = 0;
  for (int j0 = 0; j0 < Nv_in && cnt < 4; j0 += 64) {
    int j = j0 + lane;
    float d2 = sqdist_f32(cx, cy, cz, base + (size_t)j * 3);
    unsigned long long mask = __ballot(d2 <= rr);
    while (mask && cnt < 4) {
      int bp = __builtin_ctzll(mask);
      mask &= mask - 1;
      nb[cnt++] = j0 + bp;
    }
  }
  for (int q = cnt; q < 4; ++q) nb[q] = nb[0];
  if (lane < 3) pts_out[(size_t)wid * 3 + lane] = base[v * 3 + lane];
  size_t inrow = (size_t)b * Nv_in;
  size_t outrow = (size_t)wid * ld_out;
  for (int c = lane; c < C; c += 64) {
    float m = fm_in[(inrow + nb[0]) * ld_in + c];
    m = fmaxf(m, fm_in[(inrow + nb[1]) * ld_in + c]);
    m = fmaxf(m, fm_in[(inrow + nb[2]) * ld_in + c]);
    m = fmaxf(m, fm_in[(inrow + nb[3]) * ld_in + c]);
    fm_out[outrow + c] = m;
    spf[wv][c] = m;
  }
  __syncthreads();
  int o = threadIdx.x & 63, w_ = threadIdx.x >> 6;
  int wid0 = blockIdx.x * 4 + w_;
  float a = bn[o];
  for (int c = 0; c < C; ++c) a += spf[w_][c] * wn[c * 64 + o];
  fn[(size_t)wid0 * 64 + o] = a;
}

// ---------------------------------------------------------------------------
__global__ void gmax_kernel(const float* __restrict__ fm,
                            float* __restrict__ out) {
  int t = blockIdx.x * blockDim.x + threadIdx.x;
  if (t >= BS * 256) return;
  int b = t >> 8, c = t & 255;
  float m = -INFINITY;
  for (int v = 0; v < V2N; ++v)
    m = fmaxf(m, fm[((size_t)b * V2N + v) * 256 + c]);
  out[t] = m;
}

// ---------------------------------------------------------------------------
// fuse_row: inline argmin(n1,n2) + vectorized gather (all segment boundaries
// are 8-aligned → one bf16x8 chunk per thread, 184 chunks)
// ---------------------------------------------------------------------------
__global__ __launch_bounds__(256) void fuse_row_kernel(
    const float* __restrict__ fm2, const float* __restrict__ fm5,
    const float* __restrict__ fm7, const float* __restrict__ fglob,
    const float* __restrict__ onehot, const float* __restrict__ verts,
    const float* __restrict__ v1, const float* __restrict__ v2,
    ushort_t* __restrict__ fuse_b) {
  __shared__ unsigned long long red[256];
  __shared__ int sn1, sn2;
  int bv = blockIdx.x;
  int b = bv >> 11;
  int tid = threadIdx.x;
  float cx = verts[(size_t)bv * 3 + 0];
  float cy = verts[(size_t)bv * 3 + 1];
  float cz = verts[(size_t)bv * 3 + 2];
  unsigned long long best = ~0ull;
  const float* sb = v1 + (size_t)b * V1N * 3;
  for (int j = tid; j < V1N; j += 256) {
    float d2 = sqdist_f32(cx, cy, cz, sb + (size_t)j * 3);
    unsigned long long key =
        (((unsigned long long)__float_as_uint(d2)) << 32) | (unsigned)j;
    best = best < key ? best : key;
  }
  red[tid] = best;
  __syncthreads();
  for (int s = 128; s > 0; s >>= 1) {
    if (tid < s) red[tid] = red[tid] < red[tid + s] ? red[tid] : red[tid + s];
    __syncthreads();
  }
  if (tid == 0) sn1 = (int)(red[0] & 0xffffffffu);
  __syncthreads();
  best = ~0ull;
  sb = v2 + (size_t)b * V2N * 3;
  for (int j = tid; j < V2N; j += 256) {
    float d2 = sqdist_f32(cx, cy, cz, sb + (size_t)j * 3);
    unsigned long long key =
        (((unsigned long long)__float_as_uint(d2)) << 32) | (unsigned)j;
    best = best < key ? best : key;
  }
  red[tid] = best;
  __syncthreads();
  for (int s = 128; s > 0; s >>= 1) {
    if (tid < s) red[tid] = red[tid] < red[tid + s] ? red[tid] : red[tid + s];
    __syncthreads();
  }
  if (tid == 0) sn2 = (int)(red[0] & 0xffffffffu);
  __syncthreads();
  const float* r2 = fm2 + (size_t)bv * 96;
  const float* r5 = fm5 + ((size_t)b * V1N + sn1) * 192;
  const float* r7 = fm7 + ((size_t)b * V2N + sn2) * 256;
  const float* rg = fglob + b * 256;
  const float* roh = onehot + b * 16;
  if (tid < KP1 / 8) {
    int c = tid * 8;
    const float* src = nullptr;
    if (c < 192) {
      int cc = (c < 32) ? c : (c < 96 ? c - 32 : c - 96);
      src = r2 + cc;
    } else if (c < 672) {
      int cc = (c < 320) ? c - 192 : (c < 480 ? c - 320 : c - 480);
      src = r5 + cc;
    } else if (c < 1152) {
      int cc = (c < 896) ? c - 672 : c - 896;
      src = r7 + cc;
    } else if (c < 1408) {
      src = rg + (c - 1152);
    } else if (c < 1424) {
      src = roh + (c - 1408);
    }
    float4 lo = make_float4(0.f, 0.f, 0.f, 0.f), hi = lo;
    if (src) { lo = *(const float4*)src; hi = *(const float4*)(src + 4); }
    bf16x8 o;
    o[0] = (short)f2bf(lo.x); o[1] = (short)f2bf(lo.y);
    o[2] = (short)f2bf(lo.z); o[3] = (short)f2bf(lo.w);
    o[4] = (short)f2bf(hi.x); o[5] = (short)f2bf(hi.y);
    o[6] = (short)f2bf(hi.z); o[7] = (short)f2bf(hi.w);
    *(bf16x8*)(fuse_b + (size_t)bv * KP1 + c) = o;
  }
}

// ---------------------------------------------------------------------------
// bf16 MFMA GEMM — BK=64 (halves barrier/drain count vs BK=32) + XCD swizzle.
// Staging: 8 rows per 1024B DMA call (row=lane>>3, chunk=lane&7); LDS rows
// 128B, DMA-contiguous. MFMA k-order identical to BK=32 → bit-exact.
// ---------------------------------------------------------------------------
typedef const __attribute__((address_space(1))) unsigned int gas_u32;
typedef __attribute__((address_space(3))) unsigned int las_u32;

__global__ __launch_bounds__(256) void gemm_mfma_nt(
    const ushort_t* __restrict__ A, const ushort_t* __restrict__ B,
    const float* __restrict__ bias, ushort_t* __restrict__ Cb,
    float* __restrict__ Cf, int K, int ldc, int nvalid, int mode) {
  __shared__ ushort_t As[128 * 64];
  __shared__ ushort_t Bs[128 * 64];
  int tid = threadIdx.x;
  int lane = tid & 63, w = tid >> 6;
  int wm = (w >> 1) * 64, wn = (w & 1) * 64;
  int nb = gridDim.x;
  int flat = blockIdx.x + nb * blockIdx.y;
  int xcd = flat & 7, slot = flat >> 3;
  int nidx = slot % nb;
  int mband = xcd + 8 * (slot / nb);
  int bm = mband * 128, bn = nidx * 128;
  f32x4 acc[4][4];
#pragma unroll
  for (int i = 0; i < 4; ++i)
#pragma unroll
    for (int j = 0; j < 4; ++j) acc[i][j] = (f32x4){0.f, 0.f, 0.f, 0.f};

  // wave w stages rows [w*32, w*32+32) of A and B in 4 groups of 8 rows
  const ushort_t* gA[4];
  const ushort_t* gB[4];
  ushort_t* lA[4];
  ushort_t* lB[4];
  int scol = (lane & 7) * 8;
#pragma unroll
  for (int g = 0; g < 4; ++g) {
    int r = w * 32 + g * 8 + (lane >> 3);
    gA[g] = A + (size_t)(bm + r) * K + scol;
    gB[g] = B + (size_t)(bn + r) * K + scol;
    lA[g] = As + (w * 32 + g * 8) * 64;
    lB[g] = Bs + (w * 32 + g * 8) * 64;
  }
  int rA = lane & 15, q = lane >> 4;

  for (int k0 = 0; k0 < K; k0 += 64) {
#pragma unroll
    for (int g = 0; g < 4; ++g)
      __builtin_amdgcn_global_load_lds((gas_u32*)(gA[g] + k0), (las_u32*)lA[g],
                                       16, 0, 0);
#pragma unroll
    for (int g = 0; g < 4; ++g)
      __builtin_amdgcn_global_load_lds((gas_u32*)(gB[g] + k0), (las_u32*)lB[g],
                                       16, 0, 0);
    __syncthreads();
#pragma unroll
    for (int s = 0; s < 2; ++s) {
      bf16x8 af[4], bfr[4];
#pragma unroll
      for (int i = 0; i < 4; ++i)
        af[i] = *(const bf16x8*)(As + (wm + i * 16 + rA) * 64 + s * 32 + q * 8);
#pragma unroll
      for (int j = 0; j < 4; ++j)
        bfr[j] = *(const bf16x8*)(Bs + (wn + j * 16 + rA) * 64 + s * 32 + q * 8);
#pragma unroll
      for (int i = 0; i < 4; ++i)
#pragma unroll
        for (int j = 0; j < 4; ++j)
          acc[i][j] = __builtin_amdgcn_mfma_f32_16x16x32_bf16(af[i], bfr[j],
                                                              acc[i][j], 0, 0, 0);
    }
    __syncthreads();
  }

  int rowq = (lane >> 4) * 4;
  int coll = lane & 15;
#pragma unroll
  for (int i = 0; i < 4; ++i) {
#pragma unroll
    for (int j = 0; j < 4; ++j) {
      int col = bn + wn + j * 16 + coll;
      float bi = bias[col];
#pragma unroll
      for (int r = 0; r < 4; ++r) {
        int row = bm + wm + i * 16 + rowq + r;
        float v = acc[i][j][r] + bi;
        if (mode == 0) {
          Cb[(size_t)row * ldc + col] = f2bf(fmaxf(v, 0.f));
        } else if (col < nvalid) {
          Cf[(size_t)row * ldc + col] = v;
        }
      }
    }
  }
}

// ---------------------------------------------------------------------------
extern "C" void kernel_launch(void* const* d_in, const int* in_sizes, int n_in,
                              void* d_out, int out_size, void* d_ws,
                              size_t ws_size, hipStream_t stream) {
  const float* vertices = (const float*)d_in[0];
  const float* onehot = (const float*)d_in[1];
  const float* d0 = (const float*)d_in[2];
  const float *w[8], *bb[8], *dd[8];
  for (int i = 1; i <= 7; ++i) {
    w[i] = (const float*)d_in[3 * i];
    bb[i] = (const float*)d_in[3 * i + 1];
    dd[i] = (const float*)d_in[3 * i + 2];
  }
  const float* cw1 = (const float*)d_in[24];
  const float* cb1 = (const float*)d_in[25];
  const float* cw2 = (const float*)d_in[26];
  const float* cb2 = (const float*)d_in[27];
  const float* cw3 = (const float*)d_in[28];
  const float* cb3 = (const float*)d_in[29];
  float* out = (float*)d_out;

  char* wsp = (char*)d_ws;
  size_t off = 0;
  auto alloc = [&](size_t bytes) -> void* {
    void* p = wsp + off;
    off += (bytes + 255) & ~(size_t)255;
    return p;
  };
  const int M = BS * V0;  // 16384
  int* rank = (int*)alloc(4608 * 4);
  int* perm1 = (int*)alloc(512 * 4);
  int* perm2 = (int*)alloc(128 * 4);
  int* ni1 = (int*)alloc((size_t)BS * V0 * 32 * 4);
  int* ni2 = (int*)alloc((size_t)BS * V1N * 32 * 4);
  int* ni3 = (int*)alloc((size_t)BS * V2N * 32 * 4);
  float* fm2buf = (float*)alloc((size_t)BS * V0 * 96 * 4);
  float* fm5buf = (float*)alloc((size_t)BS * V1N * 192 * 4);
  float* fm7buf = (float*)alloc((size_t)BS * V2N * 256 * 4);
  float* fbuf = (float*)alloc((size_t)BS * V0 * 64 * 4);
  float* v1 = (float*)alloc((size_t)BS * V1N * 3 * 4);
  float* v2 = (float*)alloc((size_t)BS * V2N * 3 * 4);
  float* fglob = (float*)alloc((size_t)BS * 256 * 4);
  ushort_t* fuse_b = (ushort_t*)alloc((size_t)M * KP1 * 2);
  ushort_t* h1b = (ushort_t*)alloc((size_t)M * 1024 * 2);
  ushort_t* h2b = (ushort_t*)alloc((size_t)M * 512 * 2);
  ushort_t* cw1b = (ushort_t*)alloc((size_t)1024 * KP1 * 2);
  ushort_t* cw2b = (ushort_t*)alloc((size_t)512 * 1024 * 2);
  ushort_t* cw3b = (ushort_t*)alloc((size_t)128 * 512 * 2);
  float* cb3p = (float*)alloc(128 * 4);

  float rr1 = 0.0625f;
  float rr2 = (float)(0.39 * 0.39);
  float rr3 = (float)(0.63 * 0.63);

  // 1: rank + weight-prep + qbp1
  misc1_kernel<<<18 + PREP_BLKS + 4096, 256, 0, stream>>>(
      rank, cw1, cw2, cw3, cb3, cw1b, cw2b, cw3b, cb3p, vertices, ni1);
  // 2: perm compose + conv_surface(+linear1)
  misc2_kernel<<<1 + BS * V0 / 8, 256, 0, stream>>>(
      rank, perm1, perm2, vertices, ni1, d0, w[1], bb[1], fm2buf, fbuf);
  // 3-4: level-1 convs
  conv_act_kernel<<<BS * V0 / 8, 256, 0, stream>>>(
      vertices, dd[1], ni1, fbuf, fm2buf, V0, 96, 32, w[2], bb[2], fbuf);
  conv_act_kernel<<<BS * V0 / 8, 256, 0, stream>>>(
      vertices, dd[2], ni1, fbuf, fm2buf, V0, 96, 64, nullptr, nullptr, nullptr);
  // 5: pool1 (+linear3)
  pool_kernel<<<BS * V1N / 4, 256, 0, stream>>>(
      vertices, fm2buf, 96, 96, V0, perm1, V1N, rr1, v1, fm5buf, 192,
      w[3], bb[3], fbuf);
  // 6-8: level-2 convs (first fuses qbp2 + linear4)
  conv_act_qbp_kernel<<<BS * V1N / 8, 256, 0, stream>>>(
      v1, V1N, rr2, dd[3], ni2, fbuf, fm5buf, 192, 96, w[4], bb[4], fbuf);
  conv_act_kernel<<<BS * V1N / 8, 256, 0, stream>>>(
      v1, dd[4], ni2, fbuf, fm5buf, V1N, 192, 128, w[5], bb[5], fbuf);
  conv_act_kernel<<<BS * V1N / 8, 256, 0, stream>>>(
      v1, dd[5], ni2, fbuf, fm5buf, V1N, 192, 160, nullptr, nullptr, nullptr);
  // 9: pool2 (+linear6)
  pool_kernel<<<BS * V2N / 4, 256, 0, stream>>>(
      v1, fm5buf, 192, 192, V1N, perm2, V2N, rr2, v2, fm7buf, 256,
      w[6], bb[6], fbuf);
  // 10-11: level-3 convs (first fuses qbp3 + linear7)
  conv_act_qbp_kernel<<<BS * V2N / 8, 256, 0, stream>>>(
      v2, V2N, rr3, dd[6], ni3, fbuf, fm7buf, 256, 192, w[7], bb[7], fbuf);
  conv_act_kernel<<<BS * V2N / 8, 256, 0, stream>>>(
      v2, dd[7], ni3, fbuf, fm7buf, V2N, 256, 224, nullptr, nullptr, nullptr);
  // 12: global max
  gmax_kernel<<<BS, 256, 0, stream>>>(fm7buf, fglob);
  // 13: fused nearest + gather + bf16 cast
  fuse_row_kernel<<<M, 256, 0, stream>>>(fm2buf, fm5buf, fm7buf, fglob, onehot,
                                         vertices, v1, v2, fuse_b);
  // 14-16: MLP head (bf16 MFMA, BK=64)
  gemm_mfma_nt<<<dim3(1024 / 128, M / 128), 256, 0, stream>>>(
      fuse_b, cw1b, cb1, h1b, nullptr, KP1, 1024, 1024, 0);
  gemm_mfma_nt<<<dim3(512 / 128, M / 128), 256, 0, stream>>>(
      h1b, cw2b, cb2, h2b, nullptr, 1024, 512, 512, 0);
  gemm_mfma_nt<<<dim3(1, M / 128), 256, 0, stream>>>(
      h2b, cw3b, cb3p, nullptr, out, 512, 50, 50, 1);
}

// Round 11
// 423.267 us; speedup vs baseline: 6.8828x; 1.0564x over previous
//
#include <hip/hip_runtime.h>
#include <hip/hip_bf16.h>

#define BS 8
#define V0 2048
#define V1N 512
#define V2N 128

typedef unsigned short ushort_t;
typedef __attribute__((ext_vector_type(8))) short bf16x8;
typedef __attribute__((ext_vector_type(4))) float f32x4;

// ---------------------------------------------------------------------------
// Threefry2x32 cipher (JAX partitionable mode — verified R4)
// ---------------------------------------------------------------------------
__device__ __forceinline__ void tf2x32(unsigned k0, unsigned k1,
                                       unsigned x0, unsigned x1,
                                       unsigned &o0, unsigned &o1) {
  unsigned ks2 = k0 ^ k1 ^ 0x1BD11BDAu;
  x0 += k0; x1 += k1;
#define RR(r) { x0 += x1; x1 = (x1 << (r)) | (x1 >> (32 - (r))); x1 ^= x0; }
  RR(13) RR(15) RR(26) RR(6)   x0 += k1;  x1 += ks2 + 1u;
  RR(17) RR(29) RR(16) RR(24)  x0 += ks2; x1 += k0 + 2u;
  RR(13) RR(15) RR(26) RR(6)   x0 += k0;  x1 += k1 + 3u;
  RR(17) RR(29) RR(16) RR(24)  x0 += k1;  x1 += ks2 + 4u;
  RR(13) RR(15) RR(26) RR(6)   x0 += ks2; x1 += k0 + 5u;
#undef RR
  o0 = x0; o1 = x1;
}

__device__ __forceinline__ ushort_t f2bf(float f) {
  unsigned u = __float_as_uint(f);
  u += 0x7FFFu + ((u >> 16) & 1u);
  return (ushort_t)(u >> 16);
}

__device__ __forceinline__ float sqdist_f32(float cx, float cy, float cz,
                                            const float* p) {
  float dx = __fsub_rn(cx, p[0]);
  float dy = __fsub_rn(cy, p[1]);
  float dz = __fsub_rn(cz, p[2]);
  return __fadd_rn(__fadd_rn(__fmul_rn(dx, dx), __fmul_rn(dy, dy)),
                   __fmul_rn(dz, dz));
}

#define KP1 1472   // 1424 real + zero pad to 64-multiple (BK=64)

// ---------------------------------------------------------------------------
// misc1: [0,18) threefry rank · [18,18+PREP_BLKS) weight prep · rest qbp lvl-1
// ---------------------------------------------------------------------------
#define PREP_BLKS 8193
__global__ __launch_bounds__(256) void misc1_kernel(
    int* __restrict__ rank, const float* __restrict__ cw1,
    const float* __restrict__ cw2, const float* __restrict__ cw3,
    const float* __restrict__ cb3, ushort_t* __restrict__ cw1b,
    ushort_t* __restrict__ cw2b, ushort_t* __restrict__ cw3b,
    float* __restrict__ cb3p, const float* __restrict__ pts,
    int* __restrict__ ni1) {
  int bid = blockIdx.x, tid = threadIdx.x;
  if (bid < 18) {
    __shared__ unsigned sb[2048];
    int seg, segfirst, n, base;
    if (bid < 8)       { seg = 0; segfirst = 0;  n = 2048; base = 0; }
    else if (bid < 16) { seg = 1; segfirst = 8;  n = 2048; base = 2048; }
    else               { seg = 2; segfirst = 16; n = 512;  base = 4096; }
    unsigned k0, k1, nk0, nk1, sk0, sk1;
    if (seg == 0) {
      tf2x32(0u, 42u, 0u, 1u, k0, k1);
      tf2x32(k0, k1, 0u, 1u, sk0, sk1);
    } else if (seg == 1) {
      tf2x32(0u, 42u, 0u, 1u, k0, k1);
      tf2x32(k0, k1, 0u, 0u, nk0, nk1);
      tf2x32(nk0, nk1, 0u, 1u, sk0, sk1);
    } else {
      tf2x32(0u, 42u, 0u, 2u, k0, k1);
      tf2x32(k0, k1, 0u, 1u, sk0, sk1);
    }
    for (int i = tid; i < n; i += 256) {
      unsigned o0, o1;
      tf2x32(sk0, sk1, 0u, (unsigned)i, o0, o1);
      sb[i] = o0 ^ o1;
    }
    __syncthreads();
    int tt = (bid - segfirst) * 256 + tid;
    unsigned bt = sb[tt];
    int cnt = 0;
#pragma unroll 8
    for (int s = 0; s < n; ++s) {
      unsigned bs = sb[s];
      cnt += (bs < bt) || (bs == bt && s < tt);
    }
    rank[base + tt] = cnt;
  } else if (bid < 18 + PREP_BLKS) {
    long long t = (long long)(bid - 18) * 256 + tid;
    const long long N1 = 1024LL * KP1, N2 = 512LL * 1024, N3 = 128LL * 512;
    if (t < N1) {
      int k = (int)(t % KP1);
      int n = (int)(t / KP1);
      cw1b[t] = f2bf(k < 1424 ? cw1[(size_t)n * 1424 + k] : 0.f);
    } else if (t < N1 + N2) {
      long long u = t - N1;
      cw2b[u] = f2bf(cw2[u]);
    } else if (t < N1 + N2 + N3) {
      long long u = t - N1 - N2;
      int k = (int)(u & 511);
      int n = (int)(u >> 9);
      cw3b[u] = f2bf(n < 50 ? cw3[(size_t)n * 512 + k] : 0.f);
    } else if (t < N1 + N2 + N3 + 128) {
      int u = (int)(t - N1 - N2 - N3);
      cb3p[u] = u < 50 ? cb3[u] : 0.f;
    }
  } else {
    int bq = bid - 18 - PREP_BLKS;
    int wid = bq * 4 + (tid >> 6);
    int lane = tid & 63;
    int b = wid >> 11, i = wid & 2047;
    const float* base = pts + (size_t)b * V0 * 3;
    float cx = base[i * 3], cy = base[i * 3 + 1], cz = base[i * 3 + 2];
    int cnt = 0, idx0 = 0;
    for (int j0 = 0; j0 < V0; j0 += 64) {
      int j = j0 + lane;
      float d2 = sqdist_f32(cx, cy, cz, base + (size_t)j * 3);
      bool in = (d2 <= 0.0625f);
      unsigned long long mask = __ballot(in);
      if (cnt == 0 && mask) idx0 = j0 + __builtin_ctzll(mask);
      if (in) {
        int rk = cnt + __popcll(mask & ((1ull << lane) - 1ull));
        if (rk < 32) ni1[(size_t)wid * 32 + rk] = j;
      }
      cnt += __popcll(mask);
      if (cnt >= 32) break;
    }
    for (int s = cnt + lane; s < 32; s += 64) ni1[(size_t)wid * 32 + s] = idx0;
  }
}

// ---------------------------------------------------------------------------
__device__ __forceinline__ void dirn(const float* base, int v, int nb,
                                     float& ox, float& oy, float& oz) {
  float dx = __fsub_rn(base[nb * 3 + 0], base[v * 3 + 0]);
  float dy = __fsub_rn(base[nb * 3 + 1], base[v * 3 + 1]);
  float dz = __fsub_rn(base[nb * 3 + 2], base[v * 3 + 2]);
  float s2 = __fadd_rn(__fadd_rn(__fmul_rn(dx, dx), __fmul_rn(dy, dy)),
                       __fmul_rn(dz, dz));
  float nrm = fmaxf(__fsqrt_rn(s2), 1e-12f);
  ox = __fdiv_rn(dx, nrm); oy = __fdiv_rn(dy, nrm); oz = __fdiv_rn(dz, nrm);
}

__device__ __forceinline__ void norm_col(const float* d, int k,
                                         float& ox, float& oy, float& oz) {
  float x = d[k], y = d[32 + k], z = d[64 + k];
  float s2 = __fadd_rn(__fadd_rn(__fmul_rn(x, x), __fmul_rn(y, y)),
                       __fmul_rn(z, z));
  float nrm = fmaxf(__fsqrt_rn(s2), 1e-12f);
  ox = __fdiv_rn(x, nrm); oy = __fdiv_rn(y, nrm); oz = __fdiv_rn(z, nrm);
}

// ---------------------------------------------------------------------------
// misc2: block 0 = perm compose; blocks [1,2049) = conv_surface (+linear1)
// ---------------------------------------------------------------------------
__global__ __launch_bounds__(256) void misc2_kernel(
    const int* __restrict__ rank, int* __restrict__ perm1,
    int* __restrict__ perm2, const float* __restrict__ pts,
    const int* __restrict__ ni, const float* __restrict__ d0,
    const float* __restrict__ w1, const float* __restrict__ b1,
    float* __restrict__ out, float* __restrict__ fn) {
  int bid = blockIdx.x, tid = threadIdx.x;
  if (bid == 0) {
    __shared__ int a1[2048];
    __shared__ int a2[2048];
    for (int i = tid; i < 2048; i += 256) a1[rank[i]] = i;
    __syncthreads();
    for (int i = tid; i < 2048; i += 256) a2[rank[2048 + i]] = a1[i];
    __syncthreads();
    for (int i = tid; i < 512; i += 256) perm1[i] = a2[i];
    for (int i = tid; i < 512; i += 256) a1[rank[4096 + i]] = i;
    __syncthreads();
    for (int i = tid; i < 128; i += 256) perm2[i] = a1[i];
    return;
  }
  __shared__ float sdir[3][32];
  __shared__ float sdn[8][32][3];
  __shared__ float sfm[8][32];
  if (tid < 32) {
    float x, y, z; norm_col(d0, tid, x, y, z);
    sdir[0][tid] = x; sdir[1][tid] = y; sdir[2][tid] = z;
  }
  int vloc = tid >> 5, k = tid & 31;
  size_t bvg = (size_t)(bid - 1) * 8 + vloc;
  int b = (int)(bvg >> 11), v = (int)(bvg & 2047);
  const float* base = pts + (size_t)b * V0 * 3;
  int nb = ni[bvg * 32 + k];
  float x, y, z; dirn(base, v, nb, x, y, z);
  sdn[vloc][k][0] = x; sdn[vloc][k][1] = y; sdn[vloc][k][2] = z;
  __syncthreads();
  float m = 0.f;
  for (int n = 0; n < 32; ++n) {
    float d = sdn[vloc][n][0] * sdir[0][k] + sdn[vloc][n][1] * sdir[1][k] +
              sdn[vloc][n][2] * sdir[2][k];
    m = fmaxf(m, fmaxf(d, 0.f));
  }
  out[bvg * 96 + k] = m;
  sfm[vloc][k] = m;
  __syncthreads();
  float a1v = b1[k], a2v = b1[k + 32];
  for (int c = 0; c < 32; ++c) {
    float vv = sfm[vloc][c];
    a1v += vv * w1[c * 64 + k];
    a2v += vv * w1[c * 64 + k + 32];
  }
  fn[bvg * 64 + k] = a1v;
  fn[bvg * 64 + k + 32] = a2v;
}

// ---------------------------------------------------------------------------
// conv_act (+ optional fused next-linear)
// ---------------------------------------------------------------------------
__global__ __launch_bounds__(256) void conv_act_kernel(
    const float* __restrict__ pts, const float* __restrict__ dd,
    const int* __restrict__ ni, const float* __restrict__ f,
    float* __restrict__ out, int Nv, int ldout, int colofs,
    const float* __restrict__ wn, const float* __restrict__ bn,
    float* __restrict__ fn) {
  __shared__ float sdir[3][32];
  __shared__ float sdn[8][32][3];
  __shared__ int sidx[8][32];
  __shared__ float sfm[8][256];
  int tid = threadIdx.x;
  if (tid < 32) {
    float x, y, z; norm_col(dd, tid, x, y, z);
    sdir[0][tid] = x; sdir[1][tid] = y; sdir[2][tid] = z;
  }
  int vloc = tid >> 5, k = tid & 31;
  size_t bvg = (size_t)blockIdx.x * 8 + vloc;
  int b = (int)(bvg / Nv), v = (int)(bvg % Nv);
  const float* base = pts + (size_t)b * Nv * 3;
  int nb = ni[bvg * 32 + k];
  float x, y, z; dirn(base, v, nb, x, y, z);
  sdn[vloc][k][0] = x; sdn[vloc][k][1] = y; sdn[vloc][k][2] = z;
  sidx[vloc][k] = nb;
  __syncthreads();
  float m = -INFINITY;
  size_t fb = (size_t)b * Nv * 64;
  for (int n = 0; n < 32; ++n) {
    float th = fmaxf(sdn[vloc][n][0] * sdir[0][k] + sdn[vloc][n][1] * sdir[1][k] +
                     sdn[vloc][n][2] * sdir[2][k], 0.f);
    float sup = f[fb + (size_t)sidx[vloc][n] * 64 + 32 + k];
    m = fmaxf(m, th * sup);
  }
  float center = f[bvg * 64 + k];
  float res = fmaxf(center + m, 0.f);
  out[bvg * ldout + colofs + k] = res;
  if (wn) {
    size_t rowbase = (size_t)blockIdx.x * 8;
#pragma unroll 1
    for (int r = 0; r < 8; ++r)
      if (tid < colofs) sfm[r][tid] = out[(rowbase + r) * ldout + tid];
    sfm[vloc][colofs + k] = res;
    __syncthreads();
    int cin = colofs + 32;
    float a1v = bn[k], a2v = bn[k + 32];
    for (int c = 0; c < cin; ++c) {
      float vv = sfm[vloc][c];
      a1v += vv * wn[c * 64 + k];
      a2v += vv * wn[c * 64 + k + 32];
    }
    fn[bvg * 64 + k] = a1v;
    fn[bvg * 64 + k + 32] = a2v;
  }
}

// ---------------------------------------------------------------------------
// conv_act_qbp: qbp fused in front of conv_act (+fused linear)
// ---------------------------------------------------------------------------
__global__ __launch_bounds__(256) void conv_act_qbp_kernel(
    const float* __restrict__ pts, int Nv, float rrq,
    const float* __restrict__ dd, int* __restrict__ ni_out,
    const float* __restrict__ f, float* __restrict__ out, int ldout,
    int colofs, const float* __restrict__ wn, const float* __restrict__ bn,
    float* __restrict__ fn) {
  __shared__ float spts[512 * 3];
  __shared__ float sdir[3][32];
  __shared__ float sdn[8][32][3];
  __shared__ int sni[8][32];
  __shared__ float sfm[8][256];
  int tid = threadIdx.x;
  int b = (blockIdx.x * 8) / Nv;
  int vbase = (blockIdx.x * 8) % Nv;
  const float* gp = pts + (size_t)b * Nv * 3;
  for (int i = tid; i < Nv * 3; i += 256) spts[i] = gp[i];
  if (tid < 32) {
    float x, y, z; norm_col(dd, tid, x, y, z);
    sdir[0][tid] = x; sdir[1][tid] = y; sdir[2][tid] = z;
  }
  __syncthreads();
  int lane = tid & 63, wv = tid >> 6;
  for (int rep = 0; rep < 2; ++rep) {
    int vl = wv * 2 + rep;
    int v = vbase + vl;
    float cx = spts[v * 3], cy = spts[v * 3 + 1], cz = spts[v * 3 + 2];
    int cnt = 0, idx0 = 0;
    for (int j0 = 0; j0 < Nv; j0 += 64) {
      int j = j0 + lane;
      float d2 = sqdist_f32(cx, cy, cz, spts + (size_t)j * 3);
      bool in = (d2 <= rrq);
      unsigned long long mask = __ballot(in);
      if (cnt == 0 && mask) idx0 = j0 + __builtin_ctzll(mask);
      if (in) {
        int rk = cnt + __popcll(mask & ((1ull << lane) - 1ull));
        if (rk < 32) sni[vl][rk] = j;
      }
      cnt += __popcll(mask);
      if (cnt >= 32) break;
    }
    for (int s = cnt + lane; s < 32; s += 64) sni[vl][s] = idx0;
  }
  __syncthreads();
  ni_out[(size_t)(blockIdx.x * 8) * 32 + tid] = sni[tid >> 5][tid & 31];
  int vloc = tid >> 5, k = tid & 31;
  size_t bvg = (size_t)blockIdx.x * 8 + vloc;
  int v = vbase + vloc;
  int nb = sni[vloc][k];
  float x, y, z; dirn(spts, v, nb, x, y, z);
  sdn[vloc][k][0] = x; sdn[vloc][k][1] = y; sdn[vloc][k][2] = z;
  __syncthreads();
  float m = -INFINITY;
  size_t fb = (size_t)b * Nv * 64;
  for (int n = 0; n < 32; ++n) {
    float th = fmaxf(sdn[vloc][n][0] * sdir[0][k] + sdn[vloc][n][1] * sdir[1][k] +
                     sdn[vloc][n][2] * sdir[2][k], 0.f);
    float sup = f[fb + (size_t)sni[vloc][n] * 64 + 32 + k];
    m = fmaxf(m, th * sup);
  }
  float center = f[bvg * 64 + k];
  float res = fmaxf(center + m, 0.f);
  out[bvg * ldout + colofs + k] = res;
  size_t rowbase = (size_t)blockIdx.x * 8;
#pragma unroll 1
  for (int r = 0; r < 8; ++r)
    if (tid < colofs) sfm[r][tid] = out[(rowbase + r) * ldout + tid];
  sfm[vloc][colofs + k] = res;
  __syncthreads();
  int cin = colofs + 32;
  float a1v = bn[k], a2v = bn[k + 32];
  for (int c = 0; c < cin; ++c) {
    float vv = sfm[vloc][c];
    a1v += vv * wn[c * 64 + k];
    a2v += vv * wn[c * 64 + k + 32];
  }
  fn[bvg * 64 + k] = a1v;
  fn[bvg * 64 + k + 32] = a2v;
}

// ---------------------------------------------------------------------------
// pool (+ fused next-linear)
// ---------------------------------------------------------------------------
__global__ __launch_bounds__(256) void pool_kernel(
    const float* __restrict__ pts_in, const float* __restrict__ fm_in,
    int ld_in, int C, int Nv_in, const int* __restrict__ perm, int Nv_out,
    float rr, float* __restrict__ pts_out, float* __restrict__ fm_out,
    int ld_out, const float* __restrict__ wn, const float* __restrict__ bn,
    float* __restrict__ fn) {
  __shared__ float spf[4][192];
  int wv = threadIdx.x >> 6;
  int lane = threadIdx.x & 63;
  int wid = blockIdx.x * 4 + wv;
  int b = wid / Nv_out, pp = wid - b * Nv_out;
  int v = perm[pp];
  const float* base = pts_in + (size_t)b * Nv_in * 3;
  float cx = base[v * 3], cy = base[v * 3 + 1], cz = base[v * 3 + 2];
  int nb[4]; int cnt = 0;
  for (int j0 = 0; j0 < Nv_in && cnt < 4; j0 += 64) {
    int j = j0 + lane;
    float d2 = sqdist_f32(cx, cy, cz, base + (size_t)j * 3);
    unsigned long long mask = __ballot(d2 <= rr);
    while (mask && cnt < 4) {
      int bp = __builtin_ctzll(mask);
      mask &= mask - 1;
      nb[cnt++] = j0 + bp;
    }
  }
  for (int q = cnt; q < 4; ++q) nb[q] = nb[0];
  if (lane < 3) pts_out[(size_t)wid * 3 + lane] = base[v * 3 + lane];
  size_t inrow = (size_t)b * Nv_in;
  size_t outrow = (size_t)wid * ld_out;
  for (int c = lane; c < C; c += 64) {
    float m = fm_in[(inrow + nb[0]) * ld_in + c];
    m = fmaxf(m, fm_in[(inrow + nb[1]) * ld_in + c]);
    m = fmaxf(m, fm_in[(inrow + nb[2]) * ld_in + c]);
    m = fmaxf(m, fm_in[(inrow + nb[3]) * ld_in + c]);
    fm_out[outrow + c] = m;
    spf[wv][c] = m;
  }
  __syncthreads();
  int o = threadIdx.x & 63, w_ = threadIdx.x >> 6;
  int wid0 = blockIdx.x * 4 + w_;
  float a = bn[o];
  for (int c = 0; c < C; ++c) a += spf[w_][c] * wn[c * 64 + o];
  fn[(size_t)wid0 * 64 + o] = a;
}

// ---------------------------------------------------------------------------
__global__ void gmax_kernel(const float* __restrict__ fm,
                            float* __restrict__ out) {
  int t = blockIdx.x * blockDim.x + threadIdx.x;
  if (t >= BS * 256) return;
  int b = t >> 8, c = t & 255;
  float m = -INFINITY;
  for (int v = 0; v < V2N; ++v)
    m = fmaxf(m, fm[((size_t)b * V2N + v) * 256 + c]);
  out[t] = m;
}

// ---------------------------------------------------------------------------
// fuse_row: inline argmin(n1,n2) + vectorized gather
// ---------------------------------------------------------------------------
__global__ __launch_bounds__(256) void fuse_row_kernel(
    const float* __restrict__ fm2, const float* __restrict__ fm5,
    const float* __restrict__ fm7, const float* __restrict__ fglob,
    const float* __restrict__ onehot, const float* __restrict__ verts,
    const float* __restrict__ v1, const float* __restrict__ v2,
    ushort_t* __restrict__ fuse_b) {
  __shared__ unsigned long long red[256];
  __shared__ int sn1, sn2;
  int bv = blockIdx.x;
  int b = bv >> 11;
  int tid = threadIdx.x;
  float cx = verts[(size_t)bv * 3 + 0];
  float cy = verts[(size_t)bv * 3 + 1];
  float cz = verts[(size_t)bv * 3 + 2];
  unsigned long long best = ~0ull;
  const float* sb = v1 + (size_t)b * V1N * 3;
  for (int j = tid; j < V1N; j += 256) {
    float d2 = sqdist_f32(cx, cy, cz, sb + (size_t)j * 3);
    unsigned long long key =
        (((unsigned long long)__float_as_uint(d2)) << 32) | (unsigned)j;
    best = best < key ? best : key;
  }
  red[tid] = best;
  __syncthreads();
  for (int s = 128; s > 0; s >>= 1) {
    if (tid < s) red[tid] = red[tid] < red[tid + s] ? red[tid] : red[tid + s];
    __syncthreads();
  }
  if (tid == 0) sn1 = (int)(red[0] & 0xffffffffu);
  __syncthreads();
  best = ~0ull;
  sb = v2 + (size_t)b * V2N * 3;
  for (int j = tid; j < V2N; j += 256) {
    float d2 = sqdist_f32(cx, cy, cz, sb + (size_t)j * 3);
    unsigned long long key =
        (((unsigned long long)__float_as_uint(d2)) << 32) | (unsigned)j;
    best = best < key ? best : key;
  }
  red[tid] = best;
  __syncthreads();
  for (int s = 128; s > 0; s >>= 1) {
    if (tid < s) red[tid] = red[tid] < red[tid + s] ? red[tid] : red[tid + s];
    __syncthreads();
  }
  if (tid == 0) sn2 = (int)(red[0] & 0xffffffffu);
  __syncthreads();
  const float* r2 = fm2 + (size_t)bv * 96;
  const float* r5 = fm5 + ((size_t)b * V1N + sn1) * 192;
  const float* r7 = fm7 + ((size_t)b * V2N + sn2) * 256;
  const float* rg = fglob + b * 256;
  const float* roh = onehot + b * 16;
  if (tid < KP1 / 8) {
    int c = tid * 8;
    const float* src = nullptr;
    if (c < 192) {
      int cc = (c < 32) ? c : (c < 96 ? c - 32 : c - 96);
      src = r2 + cc;
    } else if (c < 672) {
      int cc = (c < 320) ? c - 192 : (c < 480 ? c - 320 : c - 480);
      src = r5 + cc;
    } else if (c < 1152) {
      int cc = (c < 896) ? c - 672 : c - 896;
      src = r7 + cc;
    } else if (c < 1408) {
      src = rg + (c - 1152);
    } else if (c < 1424) {
      src = roh + (c - 1408);
    }
    float4 lo = make_float4(0.f, 0.f, 0.f, 0.f), hi = lo;
    if (src) { lo = *(const float4*)src; hi = *(const float4*)(src + 4); }
    bf16x8 o;
    o[0] = (short)f2bf(lo.x); o[1] = (short)f2bf(lo.y);
    o[2] = (short)f2bf(lo.z); o[3] = (short)f2bf(lo.w);
    o[4] = (short)f2bf(hi.x); o[5] = (short)f2bf(hi.y);
    o[6] = (short)f2bf(hi.z); o[7] = (short)f2bf(hi.w);
    *(bf16x8*)(fuse_b + (size_t)bv * KP1 + c) = o;
  }
}

// ---------------------------------------------------------------------------
// bf16 MFMA GEMM — BK=64 + XCD swizzle + XOR-8 chunk swizzle.
// LDS rows are 128 B (=32 banks): unswizzled, a quarter-wave's 16 rows all
// hit one 4-bank group (R10: conflicts 3×). Staging lane fetches global chunk
// (lane&7)^(lane>>3) of its row — 8-lane sub-group still covers the full
// 128 B row (coalescing + DMA lane*16B contract intact); readers use physical
// chunk (s*4+q)^(row&7) → 8 distinct chunks per 8 rows → 2 lanes/bank (free).
// Fragments get bit-identical data.
// ---------------------------------------------------------------------------
typedef const __attribute__((address_space(1))) unsigned int gas_u32;
typedef __attribute__((address_space(3))) unsigned int las_u32;

__global__ __launch_bounds__(256) void gemm_mfma_nt(
    const ushort_t* __restrict__ A, const ushort_t* __restrict__ B,
    const float* __restrict__ bias, ushort_t* __restrict__ Cb,
    float* __restrict__ Cf, int K, int ldc, int nvalid, int mode) {
  __shared__ ushort_t As[128 * 64];
  __shared__ ushort_t Bs[128 * 64];
  int tid = threadIdx.x;
  int lane = tid & 63, w = tid >> 6;
  int wm = (w >> 1) * 64, wn = (w & 1) * 64;
  int nb = gridDim.x;
  int flat = blockIdx.x + nb * blockIdx.y;
  int xcd = flat & 7, slot = flat >> 3;
  int nidx = slot % nb;
  int mband = xcd + 8 * (slot / nb);
  int bm = mband * 128, bn = nidx * 128;
  f32x4 acc[4][4];
#pragma unroll
  for (int i = 0; i < 4; ++i)
#pragma unroll
    for (int j = 0; j < 4; ++j) acc[i][j] = (f32x4){0.f, 0.f, 0.f, 0.f};

  // wave w stages rows [w*32, w*32+32) of A and B in 4 groups of 8 rows
  const ushort_t* gA[4];
  const ushort_t* gB[4];
  ushort_t* lA[4];
  ushort_t* lB[4];
  int rsub = lane >> 3;                      // row within 8-row DMA group
  int scol = ((lane & 7) ^ rsub) * 8;        // XOR-8 swizzled global chunk
#pragma unroll
  for (int g = 0; g < 4; ++g) {
    int r = w * 32 + g * 8 + rsub;
    gA[g] = A + (size_t)(bm + r) * K + scol;
    gB[g] = B + (size_t)(bn + r) * K + scol;
    lA[g] = As + (w * 32 + g * 8) * 64;
    lB[g] = Bs + (w * 32 + g * 8) * 64;
  }
  int rA = lane & 15, q = lane >> 4;
  int r7 = rA & 7;                            // row&7 for de-swizzle

  for (int k0 = 0; k0 < K; k0 += 64) {
#pragma unroll
    for (int g = 0; g < 4; ++g)
      __builtin_amdgcn_global_load_lds((gas_u32*)(gA[g] + k0), (las_u32*)lA[g],
                                       16, 0, 0);
#pragma unroll
    for (int g = 0; g < 4; ++g)
      __builtin_amdgcn_global_load_lds((gas_u32*)(gB[g] + k0), (las_u32*)lB[g],
                                       16, 0, 0);
    __syncthreads();
#pragma unroll
    for (int s = 0; s < 2; ++s) {
      int pc = ((s * 4 + q) ^ r7) * 8;        // physical chunk offset
      bf16x8 af[4], bfr[4];
#pragma unroll
      for (int i = 0; i < 4; ++i)
        af[i] = *(const bf16x8*)(As + (wm + i * 16 + rA) * 64 + pc);
#pragma unroll
      for (int j = 0; j < 4; ++j)
        bfr[j] = *(const bf16x8*)(Bs + (wn + j * 16 + rA) * 64 + pc);
#pragma unroll
      for (int i = 0; i < 4; ++i)
#pragma unroll
        for (int j = 0; j < 4; ++j)
          acc[i][j] = __builtin_amdgcn_mfma_f32_16x16x32_bf16(af[i], bfr[j],
                                                              acc[i][j], 0, 0, 0);
    }
    __syncthreads();
  }

  int rowq = (lane >> 4) * 4;
  int coll = lane & 15;
#pragma unroll
  for (int i = 0; i < 4; ++i) {
#pragma unroll
    for (int j = 0; j < 4; ++j) {
      int col = bn + wn + j * 16 + coll;
      float bi = bias[col];
#pragma unroll
      for (int r = 0; r < 4; ++r) {
        int row = bm + wm + i * 16 + rowq + r;
        float v = acc[i][j][r] + bi;
        if (mode == 0) {
          Cb[(size_t)row * ldc + col] = f2bf(fmaxf(v, 0.f));
        } else if (col < nvalid) {
          Cf[(size_t)row * ldc + col] = v;
        }
      }
    }
  }
}

// ---------------------------------------------------------------------------
extern "C" void kernel_launch(void* const* d_in, const int* in_sizes, int n_in,
                              void* d_out, int out_size, void* d_ws,
                              size_t ws_size, hipStream_t stream) {
  const float* vertices = (const float*)d_in[0];
  const float* onehot = (const float*)d_in[1];
  const float* d0 = (const float*)d_in[2];
  const float *w[8], *bb[8], *dd[8];
  for (int i = 1; i <= 7; ++i) {
    w[i] = (const float*)d_in[3 * i];
    bb[i] = (const float*)d_in[3 * i + 1];
    dd[i] = (const float*)d_in[3 * i + 2];
  }
  const float* cw1 = (const float*)d_in[24];
  const float* cb1 = (const float*)d_in[25];
  const float* cw2 = (const float*)d_in[26];
  const float* cb2 = (const float*)d_in[27];
  const float* cw3 = (const float*)d_in[28];
  const float* cb3 = (const float*)d_in[29];
  float* out = (float*)d_out;

  char* wsp = (char*)d_ws;
  size_t off = 0;
  auto alloc = [&](size_t bytes) -> void* {
    void* p = wsp + off;
    off += (bytes + 255) & ~(size_t)255;
    return p;
  };
  const int M = BS * V0;  // 16384
  int* rank = (int*)alloc(4608 * 4);
  int* perm1 = (int*)alloc(512 * 4);
  int* perm2 = (int*)alloc(128 * 4);
  int* ni1 = (int*)alloc((size_t)BS * V0 * 32 * 4);
  int* ni2 = (int*)alloc((size_t)BS * V1N * 32 * 4);
  int* ni3 = (int*)alloc((size_t)BS * V2N * 32 * 4);
  float* fm2buf = (float*)alloc((size_t)BS * V0 * 96 * 4);
  float* fm5buf = (float*)alloc((size_t)BS * V1N * 192 * 4);
  float* fm7buf = (float*)alloc((size_t)BS * V2N * 256 * 4);
  float* fbuf = (float*)alloc((size_t)BS * V0 * 64 * 4);
  float* v1 = (float*)alloc((size_t)BS * V1N * 3 * 4);
  float* v2 = (float*)alloc((size_t)BS * V2N * 3 * 4);
  float* fglob = (float*)alloc((size_t)BS * 256 * 4);
  ushort_t* fuse_b = (ushort_t*)alloc((size_t)M * KP1 * 2);
  ushort_t* h1b = (ushort_t*)alloc((size_t)M * 1024 * 2);
  ushort_t* h2b = (ushort_t*)alloc((size_t)M * 512 * 2);
  ushort_t* cw1b = (ushort_t*)alloc((size_t)1024 * KP1 * 2);
  ushort_t* cw2b = (ushort_t*)alloc((size_t)512 * 1024 * 2);
  ushort_t* cw3b = (ushort_t*)alloc((size_t)128 * 512 * 2);
  float* cb3p = (float*)alloc(128 * 4);

  float rr1 = 0.0625f;
  float rr2 = (float)(0.39 * 0.39);
  float rr3 = (float)(0.63 * 0.63);

  // 1: rank + weight-prep + qbp1
  misc1_kernel<<<18 + PREP_BLKS + 4096, 256, 0, stream>>>(
      rank, cw1, cw2, cw3, cb3, cw1b, cw2b, cw3b, cb3p, vertices, ni1);
  // 2: perm compose + conv_surface(+linear1)
  misc2_kernel<<<1 + BS * V0 / 8, 256, 0, stream>>>(
      rank, perm1, perm2, vertices, ni1, d0, w[1], bb[1], fm2buf, fbuf);
  // 3-4: level-1 convs
  conv_act_kernel<<<BS * V0 / 8, 256, 0, stream>>>(
      vertices, dd[1], ni1, fbuf, fm2buf, V0, 96, 32, w[2], bb[2], fbuf);
  conv_act_kernel<<<BS * V0 / 8, 256, 0, stream>>>(
      vertices, dd[2], ni1, fbuf, fm2buf, V0, 96, 64, nullptr, nullptr, nullptr);
  // 5: pool1 (+linear3)
  pool_kernel<<<BS * V1N / 4, 256, 0, stream>>>(
      vertices, fm2buf, 96, 96, V0, perm1, V1N, rr1, v1, fm5buf, 192,
      w[3], bb[3], fbuf);
  // 6-8: level-2 convs (first fuses qbp2 + linear4)
  conv_act_qbp_kernel<<<BS * V1N / 8, 256, 0, stream>>>(
      v1, V1N, rr2, dd[3], ni2, fbuf, fm5buf, 192, 96, w[4], bb[4], fbuf);
  conv_act_kernel<<<BS * V1N / 8, 256, 0, stream>>>(
      v1, dd[4], ni2, fbuf, fm5buf, V1N, 192, 128, w[5], bb[5], fbuf);
  conv_act_kernel<<<BS * V1N / 8, 256, 0, stream>>>(
      v1, dd[5], ni2, fbuf, fm5buf, V1N, 192, 160, nullptr, nullptr, nullptr);
  // 9: pool2 (+linear6)
  pool_kernel<<<BS * V2N / 4, 256, 0, stream>>>(
      v1, fm5buf, 192, 192, V1N, perm2, V2N, rr2, v2, fm7buf, 256,
      w[6], bb[6], fbuf);
  // 10-11: level-3 convs (first fuses qbp3 + linear7)
  conv_act_qbp_kernel<<<BS * V2N / 8, 256, 0, stream>>>(
      v2, V2N, rr3, dd[6], ni3, fbuf, fm7buf, 256, 192, w[7], bb[7], fbuf);
  conv_act_kernel<<<BS * V2N / 8, 256, 0, stream>>>(
      v2, dd[7], ni3, fbuf, fm7buf, V2N, 256, 224, nullptr, nullptr, nullptr);
  // 12: global max
  gmax_kernel<<<BS, 256, 0, stream>>>(fm7buf, fglob);
  // 13: fused nearest + gather + bf16 cast
  fuse_row_kernel<<<M, 256, 0, stream>>>(fm2buf, fm5buf, fm7buf, fglob, onehot,
                                         vertices, v1, v2, fuse_b);
  // 14-16: MLP head (bf16 MFMA, BK=64 + XOR-8 swizzle)
  gemm_mfma_nt<<<dim3(1024 / 128, M / 128), 256, 0, stream>>>(
      fuse_b, cw1b, cb1, h1b, nullptr, KP1, 1024, 1024, 0);
  gemm_mfma_nt<<<dim3(512 / 128, M / 128), 256, 0, stream>>>(
      h1b, cw2b, cb2, h2b, nullptr, 1024, 512, 512, 0);
  gemm_mfma_nt<<<dim3(1, M / 128), 256, 0, stream>>>(
      h2b, cw3b, cb3p, nullptr, out, 512, 50, 50, 1);
}